// Round 1
// baseline (1132.094 us; speedup 1.0000x reference)
//
#include <hip/hip_runtime.h>
#include <hip/hip_bf16.h>

// ---------------- problem constants ----------------
#define N_TOK 32768
#define DIMC  512
#define NH    8
#define DHD   64
#define NL    64
#define KSZ   33
#define QKVC  1536
#define NCHUNK 32   // attn3 n-chunks per head (1024 tokens each)

typedef _Float16 f16;
typedef _Float16 f16x8 __attribute__((ext_vector_type(8)));
typedef _Float16 f16x4 __attribute__((ext_vector_type(4)));
typedef float    f32x4 __attribute__((ext_vector_type(4)));

// ---------------- convert f32 -> f16 (vectorized) ----------------
__global__ void cvt4_k(const float4* __restrict__ in, f16x4* __restrict__ out, int n4) {
    int i = blockIdx.x * 256 + threadIdx.x;
    if (i < n4) {
        float4 v = in[i];
        f16x4 o = { (f16)v.x, (f16)v.y, (f16)v.z, (f16)v.w };
        out[i] = o;
    }
}

// ---------------- transpose f32 (R x C) -> f16 (C x R) ----------------
__global__ void transpose_k(const float* __restrict__ W, f16* __restrict__ WT, int R, int C) {
    __shared__ float tile[32][33];
    int bx = blockIdx.x * 32, by = blockIdx.y * 32;
    int tx = threadIdx.x, ty = threadIdx.y;
    #pragma unroll
    for (int i = 0; i < 32; i += 8)
        tile[ty + i][tx] = W[(size_t)(by + ty + i) * C + bx + tx];
    __syncthreads();
    #pragma unroll
    for (int i = 0; i < 32; i += 8)
        WT[(size_t)(bx + ty + i) * R + by + tx] = (f16)tile[tx][ty + i];
}

// ---------------- label histogram ----------------
__global__ void hist_k(const int* __restrict__ labels, int* __restrict__ counts) {
    __shared__ int hloc[NL];
    int t = threadIdx.x;
    if (t < NL) hloc[t] = 0;
    __syncthreads();
    int i = blockIdx.x * 256 + t;
    atomicAdd(&hloc[labels[i]], 1);
    __syncthreads();
    if (t < NL) atomicAdd(&counts[t], hloc[t]);
}

// ---------------- exclusive prefix over 64 counts ----------------
__global__ void scan_k(const int* __restrict__ counts, int* __restrict__ base) {
    if (threadIdx.x == 0) {
        int s = 0;
        for (int l = 0; l < NL; ++l) { base[l] = s; s += counts[l]; }
    }
}

// ---------------- stable compaction: one block per label ----------------
__global__ __launch_bounds__(256) void compact_k(const int* __restrict__ labels,
                                                 const int* __restrict__ base,
                                                 int* __restrict__ indexArr,
                                                 int* __restrict__ posArr) {
    const int l = blockIdx.x;
    __shared__ int wtot[4];
    __shared__ int s_run;
    int t = threadIdx.x, lane = t & 63, w = t >> 6;
    if (t == 0) s_run = base[l];
    __syncthreads();
    for (int c0 = 0; c0 < N_TOK; c0 += 256) {
        int ii = c0 + t;
        bool flag = (labels[ii] == l);
        unsigned long long mask = __ballot(flag);
        int before = __popcll(mask & ((1ull << lane) - 1ull));
        if (lane == 0) wtot[w] = __popcll(mask);
        __syncthreads();
        int off = 0;
        #pragma unroll
        for (int ww = 0; ww < 4; ++ww) off += (ww < w) ? wtot[ww] : 0;
        int tot = wtot[0] + wtot[1] + wtot[2] + wtot[3];
        int rb = s_run;
        if (flag) { int dest = rb + off + before; indexArr[dest] = ii; posArr[ii] = dest; }
        __syncthreads();
        if (t == 0) s_run = rb + tot;
    }
}

// ---------------- f16 MFMA GEMM: C[M x BNTOT] = A[M x 512] @ BT[BNTOT x 512]^T ----------------
// tile 128x256, BK=32, 4 waves (each: 128 rows x 64 cols), LDS row stride 40 halves (80B) for bank spread
template<int BNTOT, bool OUT_F32>
__global__ __launch_bounds__(256) void gemm_k512(const f16* __restrict__ A, const f16* __restrict__ BT,
                                                 void* __restrict__ Cout, const float* __restrict__ bias) {
    constexpr int K = 512;
    __shared__ f16 As[128][40];
    __shared__ f16 Bs[256][40];
    const int t = threadIdx.x;
    const int mBase = blockIdx.x * 128;
    const int nBase = blockIdx.y * 256;
    const int w = t >> 6, lane = t & 63;
    const int lr = lane & 15, lk = lane >> 4;
    f32x4 acc[8][4];
    #pragma unroll
    for (int m = 0; m < 8; ++m)
        #pragma unroll
        for (int n = 0; n < 4; ++n) acc[m][n] = (f32x4){0.f, 0.f, 0.f, 0.f};

    for (int kt = 0; kt < K / 32; ++kt) {
        __syncthreads();
        #pragma unroll
        for (int c = 0; c < 2; ++c) {  // A: 128 rows x 4 slots = 512 chunks of 16B
            int id = c * 256 + t, row = id >> 2, slot = id & 3;
            *(int4*)&As[row][slot * 8] = *(const int4*)&A[(size_t)(mBase + row) * K + kt * 32 + slot * 8];
        }
        #pragma unroll
        for (int c = 0; c < 4; ++c) {  // B: 256 rows x 4 slots = 1024 chunks
            int id = c * 256 + t, row = id >> 2, slot = id & 3;
            *(int4*)&Bs[row][slot * 8] = *(const int4*)&BT[(size_t)(nBase + row) * K + kt * 32 + slot * 8];
        }
        __syncthreads();
        f16x8 af[8], bf[4];
        #pragma unroll
        for (int m = 0; m < 8; ++m) af[m] = *(const f16x8*)&As[m * 16 + lr][lk * 8];
        #pragma unroll
        for (int n = 0; n < 4; ++n) bf[n] = *(const f16x8*)&Bs[w * 64 + n * 16 + lr][lk * 8];
        #pragma unroll
        for (int m = 0; m < 8; ++m)
            #pragma unroll
            for (int n = 0; n < 4; ++n)
                acc[m][n] = __builtin_amdgcn_mfma_f32_16x16x32_f16(af[m], bf[n], acc[m][n], 0, 0, 0);
    }
    #pragma unroll
    for (int m = 0; m < 8; ++m)
        #pragma unroll
        for (int n = 0; n < 4; ++n)
            #pragma unroll
            for (int j = 0; j < 4; ++j) {
                int row = mBase + m * 16 + lk * 4 + j;
                int col = nBase + w * 64 + n * 16 + lr;
                if constexpr (OUT_F32)
                    ((float*)Cout)[(size_t)row * BNTOT + col] = acc[m][n][j] + bias[col];
                else
                    ((f16*)Cout)[(size_t)row * BNTOT + col] = (f16)acc[m][n][j];
            }
}

// ---------------- segment-mean pooling of q,k -> ql,kl (f32) ----------------
__global__ void pool_k(const f16* __restrict__ qkvh, const int* __restrict__ indexArr,
                       const int* __restrict__ base, const int* __restrict__ counts,
                       float* __restrict__ ql, float* __restrict__ kl) {
    int l = blockIdx.x, h = blockIdx.y, d = threadIdx.x;  // 64 threads
    int b0 = base[l], cnt = counts[l];
    float sq = 0.f, sk = 0.f;
    for (int p = 0; p < cnt; ++p) {
        int j = indexArr[b0 + p];
        size_t ro = (size_t)j * QKVC + h * 64 + d;
        sq += (float)qkvh[ro];
        sk += (float)qkvh[ro + 512];
    }
    float inv = 1.0f / (float)(cnt > 0 ? cnt : 1);
    ql[(h * 64 + l) * 64 + d] = sq * inv;
    kl[(h * 64 + l) * 64 + d] = sk * inv;
}

// ---------------- attn2 = softmax(ql@kl^T) rows; per-head row/col abs-sum maxes ----------------
__global__ __launch_bounds__(256) void attn2_k(const float* __restrict__ ql, const float* __restrict__ kl,
                                               float* __restrict__ a_out, float* __restrict__ mrow,
                                               float* __restrict__ mcol) {
    int h = blockIdx.x;
    __shared__ float qs[64][65], ks[64][65], a[64][65];
    __shared__ float red[64][4];
    __shared__ float rowv[64], colv[64];
    int t = threadIdx.x;
    for (int idx = t; idx < 4096; idx += 256) {
        int r = idx >> 6, c = idx & 63;
        qs[r][c] = ql[h * 4096 + idx];
        ks[r][c] = kl[h * 4096 + idx];
    }
    __syncthreads();
    int i = t >> 2, q4 = t & 3, j0 = q4 * 16;
    float o[16];
    #pragma unroll
    for (int jj = 0; jj < 16; ++jj) o[jj] = 0.f;
    for (int d = 0; d < 64; ++d) {
        float qv = qs[i][d];
        #pragma unroll
        for (int jj = 0; jj < 16; ++jj) o[jj] += qv * ks[j0 + jj][d];
    }
    float pmx = o[0];
    #pragma unroll
    for (int jj = 1; jj < 16; ++jj) pmx = fmaxf(pmx, o[jj]);
    red[i][q4] = pmx;
    __syncthreads();
    float rm = fmaxf(fmaxf(red[i][0], red[i][1]), fmaxf(red[i][2], red[i][3]));
    float psum = 0.f;
    #pragma unroll
    for (int jj = 0; jj < 16; ++jj) { o[jj] = expf(o[jj] - rm); psum += o[jj]; }
    __syncthreads();
    red[i][q4] = psum;
    __syncthreads();
    float rs = red[i][0] + red[i][1] + red[i][2] + red[i][3];
    float inv = 1.0f / rs;
    #pragma unroll
    for (int jj = 0; jj < 16; ++jj) { o[jj] *= inv; a[i][j0 + jj] = o[jj]; }
    __syncthreads();
    for (int idx = t; idx < 4096; idx += 256) a_out[h * 4096 + idx] = a[idx >> 6][idx & 63];
    // row sums (positive matrix: abs == value)
    float rsum = 0.f;
    #pragma unroll
    for (int jj = 0; jj < 16; ++jj) rsum += o[jj];
    __syncthreads();
    red[i][q4] = rsum;
    __syncthreads();
    if (q4 == 0) rowv[i] = red[i][0] + red[i][1] + red[i][2] + red[i][3];
    // col sums: thread (i,q4) handles col i, rows j0..j0+15
    float csum = 0.f;
    #pragma unroll
    for (int jj = 0; jj < 16; ++jj) csum += a[j0 + jj][i];
    __syncthreads();
    red[i][q4] = csum;
    __syncthreads();
    if (q4 == 0) colv[i] = red[i][0] + red[i][1] + red[i][2] + red[i][3];
    __syncthreads();
    if (t == 0) {
        float mr = rowv[0], mc = colv[0];
        for (int j = 1; j < 64; ++j) { mr = fmaxf(mr, rowv[j]); mc = fmaxf(mc, colv[j]); }
        mrow[h] = mr; mcol[h] = mc;
    }
}

// 4x4-blocked 64x64 matmul helper (operands in LDS, stride 68)
__device__ __forceinline__ void mm_blk(const float (*X)[68], const float (*Y)[68],
                                       int i0, int j0, float o[4][4]) {
    #pragma unroll
    for (int ii = 0; ii < 4; ++ii)
        #pragma unroll
        for (int jj = 0; jj < 4; ++jj) o[ii][jj] = 0.f;
    for (int k = 0; k < 64; ++k) {
        float4 yv = *(const float4*)&Y[k][j0];
        float x0 = X[i0][k], x1 = X[i0 + 1][k], x2 = X[i0 + 2][k], x3 = X[i0 + 3][k];
        o[0][0] += x0 * yv.x; o[0][1] += x0 * yv.y; o[0][2] += x0 * yv.z; o[0][3] += x0 * yv.w;
        o[1][0] += x1 * yv.x; o[1][1] += x1 * yv.y; o[1][2] += x1 * yv.z; o[1][3] += x1 * yv.w;
        o[2][0] += x2 * yv.x; o[2][1] += x2 * yv.y; o[2][2] += x2 * yv.z; o[2][3] += x2 * yv.w;
        o[3][0] += x3 * yv.x; o[3][1] += x3 * yv.y; o[3][2] += x3 * yv.z; o[3][3] += x3 * yv.w;
    }
}

// ---------------- Newton-Schulz pinv (6 iters, f32, per head) ----------------
__global__ __launch_bounds__(256) void pinv_k(const float* __restrict__ a_g, const float* __restrict__ mrow,
                                              const float* __restrict__ mcol, float* __restrict__ z_g) {
    int h = blockIdx.x;
    __shared__ float a[64][68], z[64][68], C[64][68], D[64][68], E[64][68];
    int t = threadIdx.x;
    float mr = mrow[0], mc = mcol[0];
    #pragma unroll
    for (int k = 1; k < 8; ++k) { mr = fmaxf(mr, mrow[k]); mc = fmaxf(mc, mcol[k]); }
    float inv0 = 1.0f / (mr * mc);
    for (int idx = t; idx < 4096; idx += 256) {
        int r = idx >> 6, c = idx & 63;
        float av = a_g[h * 4096 + idx];
        a[r][c] = av;
        z[c][r] = av * inv0;   // z0 = a^T / (mr*mc)
    }
    __syncthreads();
    int i0 = (t >> 4) * 4, j0 = (t & 15) * 4;
    float o[4][4];
    for (int it = 0; it < 6; ++it) {
        mm_blk(a, z, i0, j0, o);                    // C = a@z
        #pragma unroll
        for (int ii = 0; ii < 4; ++ii)
            #pragma unroll
            for (int jj = 0; jj < 4; ++jj) C[i0 + ii][j0 + jj] = o[ii][jj];
        __syncthreads();
        mm_blk(C, C, i0, j0, o);                    // D = 7C - C@C
        #pragma unroll
        for (int ii = 0; ii < 4; ++ii)
            #pragma unroll
            for (int jj = 0; jj < 4; ++jj) D[i0 + ii][j0 + jj] = 7.f * C[i0 + ii][j0 + jj] - o[ii][jj];
        __syncthreads();
        mm_blk(C, D, i0, j0, o);                    // E = 15C - C@D
        #pragma unroll
        for (int ii = 0; ii < 4; ++ii)
            #pragma unroll
            for (int jj = 0; jj < 4; ++jj) E[i0 + ii][j0 + jj] = 15.f * C[i0 + ii][j0 + jj] - o[ii][jj];
        __syncthreads();
        mm_blk(z, E, i0, j0, o);                    // D = 0.25*(13z - z@E)
        #pragma unroll
        for (int ii = 0; ii < 4; ++ii)
            #pragma unroll
            for (int jj = 0; jj < 4; ++jj) D[i0 + ii][j0 + jj] = 0.25f * (13.f * z[i0 + ii][j0 + jj] - o[ii][jj]);
        __syncthreads();
        #pragma unroll
        for (int ii = 0; ii < 4; ++ii)
            #pragma unroll
            for (int jj = 0; jj < 4; ++jj) z[i0 + ii][j0 + jj] = D[i0 + ii][j0 + jj];
        __syncthreads();
    }
    for (int idx = t; idx < 4096; idx += 256) z_g[h * 4096 + idx] = z[idx >> 6][idx & 63];
}

// ---------------- attn3 @ v: chunked online-softmax partials ----------------
__global__ __launch_bounds__(256) void attn3_k(const f16* __restrict__ qkvh, const float* __restrict__ ql,
                                               float* __restrict__ pm, float* __restrict__ ps,
                                               float* __restrict__ pacc) {
    int cx = blockIdx.x, h = blockIdx.y;
    __shared__ float qls[64][68];
    __shared__ float kts[64][68];  // transposed: kts[d][n]
    __shared__ float vs[64][68];   // vs[n][d]
    __shared__ float S[64][68];
    __shared__ float red[64][4];
    __shared__ float ml[64], sl[64];
    int t = threadIdx.x;
    for (int idx = t; idx < 4096; idx += 256) qls[idx >> 6][idx & 63] = ql[h * 4096 + idx];
    if (t < 64) { ml[t] = -1e30f; sl[t] = 0.f; }
    int i = t >> 2, q4 = t & 3, j0 = q4 * 16;
    float acc[16];
    #pragma unroll
    for (int jj = 0; jj < 16; ++jj) acc[jj] = 0.f;
    __syncthreads();
    for (int sub = 0; sub < 16; ++sub) {
        int n0 = cx * 1024 + sub * 64;
        for (int idx = t; idx < 4096; idx += 256) {
            int r = idx >> 6, c = idx & 63;
            size_t ro = (size_t)(n0 + r) * QKVC + 512 + h * 64 + c;
            kts[c][r] = (float)qkvh[ro];
            vs[r][c] = (float)qkvh[ro + 512];
        }
        __syncthreads();
        float o[16];
        #pragma unroll
        for (int jj = 0; jj < 16; ++jj) o[jj] = 0.f;
        for (int d = 0; d < 64; ++d) {
            float qv = qls[i][d];
            #pragma unroll
            for (int w = 0; w < 4; ++w) {
                float4 kv = *(const float4*)&kts[d][j0 + w * 4];
                o[w * 4 + 0] += qv * kv.x; o[w * 4 + 1] += qv * kv.y;
                o[w * 4 + 2] += qv * kv.z; o[w * 4 + 3] += qv * kv.w;
            }
        }
        float tm = o[0];
        #pragma unroll
        for (int jj = 1; jj < 16; ++jj) tm = fmaxf(tm, o[jj]);
        red[i][q4] = tm;
        __syncthreads();
        float rowm = fmaxf(fmaxf(red[i][0], red[i][1]), fmaxf(red[i][2], red[i][3]));
        float oldm = ml[i];
        float newm = fmaxf(oldm, rowm);
        float f = __expf(oldm - newm);
        float psum = 0.f;
        #pragma unroll
        for (int jj = 0; jj < 16; ++jj) { o[jj] = __expf(o[jj] - newm); psum += o[jj]; }
        #pragma unroll
        for (int w = 0; w < 4; ++w)
            *(float4*)&S[i][j0 + w * 4] = make_float4(o[w * 4], o[w * 4 + 1], o[w * 4 + 2], o[w * 4 + 3]);
        __syncthreads();
        red[i][q4] = psum;
        __syncthreads();
        float tsum = red[i][0] + red[i][1] + red[i][2] + red[i][3];
        if (q4 == 0) { sl[i] = sl[i] * f + tsum; ml[i] = newm; }
        #pragma unroll
        for (int jj = 0; jj < 16; ++jj) acc[jj] *= f;
        for (int k = 0; k < 64; ++k) {
            float pv = S[i][k];
            #pragma unroll
            for (int w = 0; w < 4; ++w) {
                float4 vv = *(const float4*)&vs[k][j0 + w * 4];
                acc[w * 4 + 0] += pv * vv.x; acc[w * 4 + 1] += pv * vv.y;
                acc[w * 4 + 2] += pv * vv.z; acc[w * 4 + 3] += pv * vv.w;
            }
        }
        __syncthreads();
    }
    if (q4 == 0) {
        pm[(h * NCHUNK + cx) * 64 + i] = ml[i];
        ps[(h * NCHUNK + cx) * 64 + i] = sl[i];
    }
    size_t po = ((size_t)(h * NCHUNK + cx) * 64 + i) * 64 + j0;
    #pragma unroll
    for (int w = 0; w < 4; ++w)
        *(float4*)&pacc[po + w * 4] = make_float4(acc[w * 4], acc[w * 4 + 1], acc[w * 4 + 2], acc[w * 4 + 3]);
}

// ---------------- merge attn3 partials -> T[h][l][d] ----------------
__global__ void attn3_merge_k(const float* __restrict__ pm, const float* __restrict__ ps,
                              const float* __restrict__ pacc, float* __restrict__ T) {
    int l = blockIdx.x, h = blockIdx.y, d = threadIdx.x;  // 64 threads
    float m = -1e30f;
    for (int c = 0; c < NCHUNK; ++c) m = fmaxf(m, pm[(h * NCHUNK + c) * 64 + l]);
    float s = 0.f, a = 0.f;
    for (int c = 0; c < NCHUNK; ++c) {
        float wgt = __expf(pm[(h * NCHUNK + c) * 64 + l] - m);
        s += ps[(h * NCHUNK + c) * 64 + l] * wgt;
        a += pacc[((size_t)(h * NCHUNK + c) * 64 + l) * 64 + d] * wgt;
    }
    T[(h * 64 + l) * 64 + d] = a / s;
}

// ---------------- M = z @ T per head ----------------
__global__ __launch_bounds__(256) void zmatT_k(const float* __restrict__ z_g, const float* __restrict__ T,
                                               float* __restrict__ M) {
    int h = blockIdx.x;
    __shared__ float zs[64][68], Ts[64][68];
    int t = threadIdx.x;
    for (int idx = t; idx < 4096; idx += 256) {
        int r = idx >> 6, c = idx & 63;
        zs[r][c] = z_g[h * 4096 + idx];
        Ts[r][c] = T[h * 4096 + idx];
    }
    __syncthreads();
    int i0 = (t >> 4) * 4, j0 = (t & 15) * 4;
    float o[4][4];
    mm_blk(zs, Ts, i0, j0, o);
    #pragma unroll
    for (int ii = 0; ii < 4; ++ii)
        #pragma unroll
        for (int jj = 0; jj < 4; ++jj)
            M[h * 4096 + (i0 + ii) * 64 + j0 + jj] = o[ii][jj];
}

// ---------------- depthwise conv over sorted v -> resS (f32, in d_out scratch) ----------------
__global__ __launch_bounds__(256) void conv_k(const f16* __restrict__ qkvh, const int* __restrict__ indexArr,
                                              const float* __restrict__ resk, float* __restrict__ resS) {
    int h = blockIdx.y;
    int p0 = blockIdx.x * 256;
    __shared__ f16 vt[288][64];
    __shared__ float wsm[KSZ];
    int t = threadIdx.x;
    if (t < KSZ) wsm[t] = resk[h * KSZ + t];
    for (int id = t; id < 288 * 8; id += 256) {
        int rr = id >> 3, c = id & 7;
        int pg = p0 - 16 + rr;
        int4 v = {0, 0, 0, 0};
        if (pg >= 0 && pg < N_TOK) {
            int j = indexArr[pg];
            v = *(const int4*)&qkvh[(size_t)j * QKVC + 1024 + h * 64 + c * 8];
        }
        *(int4*)&vt[rr][c * 8] = v;
    }
    __syncthreads();
    int d = t & 63, pg4 = t >> 6;  // 4 groups of 64 positions
    float col[96];
    #pragma unroll
    for (int i2 = 0; i2 < 96; ++i2) col[i2] = (float)vt[pg4 * 64 + i2][d];
    for (int pp = 0; pp < 64; ++pp) {
        float acc = 0.f;
        #pragma unroll
        for (int k = 0; k < KSZ; ++k) acc += wsm[k] * col[pp + k];
        resS[(size_t)(p0 + pg4 * 64 + pp) * 512 + h * 64 + d] = acc;
    }
}

// ---------------- attn1 softmax + @M + residual -> Yh (f16) ----------------
__global__ __launch_bounds__(256) void attn1_k(const f16* __restrict__ qkvh, const float* __restrict__ kl,
                                               const float* __restrict__ M, const int* __restrict__ pos,
                                               const float* __restrict__ resS, f16* __restrict__ Yh) {
    int h = blockIdx.y;
    int n0 = blockIdx.x * 256;
    int t = threadIdx.x;
    int n = n0 + t;
    __shared__ float kls[64][68];
    __shared__ float Ms[64][68];
    __shared__ f16 Yt[256][72];
    for (int idx = t; idx < 4096; idx += 256) {
        int r = idx >> 6, c = idx & 63;
        kls[r][c] = kl[h * 4096 + idx];
        Ms[r][c] = M[h * 4096 + idx];
    }
    __syncthreads();
    float qf[64];
    {
        const f16x8* qp = (const f16x8*)&qkvh[(size_t)n * QKVC + h * 64];
        #pragma unroll
        for (int c = 0; c < 8; ++c) {
            f16x8 hv = qp[c];
            #pragma unroll
            for (int e = 0; e < 8; ++e) qf[c * 8 + e] = (float)hv[e];
        }
    }
    float p[64];
    #pragma unroll
    for (int l = 0; l < 64; ++l) {
        float s = 0.f;
        #pragma unroll
        for (int c4 = 0; c4 < 16; ++c4) {
            float4 kv = *(const float4*)&kls[l][c4 * 4];
            s += qf[c4 * 4] * kv.x + qf[c4 * 4 + 1] * kv.y + qf[c4 * 4 + 2] * kv.z + qf[c4 * 4 + 3] * kv.w;
        }
        p[l] = s;
    }
    float m = p[0];
    #pragma unroll
    for (int l = 1; l < 64; ++l) m = fmaxf(m, p[l]);
    float sum = 0.f;
    #pragma unroll
    for (int l = 0; l < 64; ++l) { p[l] = __expf(p[l] - m); sum += p[l]; }
    float inv = 1.0f / sum;
    float acc[64];
    #pragma unroll
    for (int d = 0; d < 64; ++d) acc[d] = 0.f;
    #pragma unroll
    for (int l = 0; l < 64; ++l) {
        float wgt = p[l] * inv;
        #pragma unroll
        for (int d4 = 0; d4 < 16; ++d4) {
            float4 mv = *(const float4*)&Ms[l][d4 * 4];
            acc[d4 * 4 + 0] += wgt * mv.x; acc[d4 * 4 + 1] += wgt * mv.y;
            acc[d4 * 4 + 2] += wgt * mv.z; acc[d4 * 4 + 3] += wgt * mv.w;
        }
    }
    int pn = pos[n];
    const float* rr = &resS[(size_t)pn * 512 + h * 64];
    #pragma unroll
    for (int d4 = 0; d4 < 16; ++d4) {
        float4 rv = *(const float4*)&rr[d4 * 4];
        Yt[t][d4 * 4 + 0] = (f16)(acc[d4 * 4 + 0] + rv.x);
        Yt[t][d4 * 4 + 1] = (f16)(acc[d4 * 4 + 1] + rv.y);
        Yt[t][d4 * 4 + 2] = (f16)(acc[d4 * 4 + 2] + rv.z);
        Yt[t][d4 * 4 + 3] = (f16)(acc[d4 * 4 + 3] + rv.w);
    }
    __syncthreads();
    for (int id = t; id < 4096; id += 256) {  // coalesced f16 write-out, 8B chunks
        int row = id >> 4, c = id & 15;
        *(int2*)&Yh[(size_t)(n0 + row) * 512 + h * 64 + c * 4] = *(const int2*)&Yt[row][c * 4];
    }
}

// ---------------- host launch ----------------
extern "C" void kernel_launch(void* const* d_in, const int* in_sizes, int n_in,
                              void* d_out, int out_size, void* d_ws, size_t ws_size,
                              hipStream_t stream) {
    const float* x    = (const float*)d_in[0];
    const float* Wqkv = (const float*)d_in[1];
    const float* Wout = (const float*)d_in[2];
    const float* bout = (const float*)d_in[3];
    const float* resk = (const float*)d_in[4];
    const int*   labels = (const int*)d_in[5];
    float* out = (float*)d_out;

    char* w = (char*)d_ws;
    size_t off = 0;
    auto alloc = [&](size_t bytes) {
        void* p = w + off;
        off += (bytes + 255) & ~(size_t)255;
        return p;
    };
    f16* xh     = (f16*)alloc((size_t)N_TOK * DIMC * 2);       // 32 MB
    f16* qkvh   = (f16*)alloc((size_t)N_TOK * QKVC * 2);       // 96 MB
    f16* WqkvT  = (f16*)alloc((size_t)QKVC * DIMC * 2);
    f16* WoutT  = (f16*)alloc((size_t)DIMC * DIMC * 2);
    f16* Yh     = (f16*)alloc((size_t)N_TOK * DIMC * 2);       // 32 MB
    int* counts = (int*)alloc(NL * 4);
    int* baseA  = (int*)alloc(NL * 4);
    int* indexA = (int*)alloc((size_t)N_TOK * 4);
    int* posA   = (int*)alloc((size_t)N_TOK * 4);
    float* ql   = (float*)alloc((size_t)NH * 64 * 64 * 4);
    float* kl   = (float*)alloc((size_t)NH * 64 * 64 * 4);
    float* a2   = (float*)alloc((size_t)NH * 64 * 64 * 4);
    float* mrow = (float*)alloc(NH * 4);
    float* mcol = (float*)alloc(NH * 4);
    float* zb   = (float*)alloc((size_t)NH * 64 * 64 * 4);
    float* Tb   = (float*)alloc((size_t)NH * 64 * 64 * 4);
    float* Mb   = (float*)alloc((size_t)NH * 64 * 64 * 4);
    float* pm   = (float*)alloc((size_t)NH * NCHUNK * 64 * 4);
    float* ps   = (float*)alloc((size_t)NH * NCHUNK * 64 * 4);
    float* pacc = (float*)alloc((size_t)NH * NCHUNK * 64 * 64 * 4);  // 4 MB
    float* resS = out;  // reuse d_out as f32 conv scratch (fully overwritten by final GEMM)

    hipMemsetAsync(counts, 0, NL * 4, stream);

    // convert x -> f16
    cvt4_k<<<(N_TOK * DIMC / 4 + 255) / 256, 256, 0, stream>>>((const float4*)x, (f16x4*)xh, N_TOK * DIMC / 4);
    // transpose weights to (N,K) f16
    transpose_k<<<dim3(QKVC / 32, DIMC / 32), dim3(32, 8), 0, stream>>>(Wqkv, WqkvT, DIMC, QKVC);
    transpose_k<<<dim3(DIMC / 32, DIMC / 32), dim3(32, 8), 0, stream>>>(Wout, WoutT, DIMC, DIMC);
    // stable counting sort
    hist_k<<<N_TOK / 256, 256, 0, stream>>>(labels, counts);
    scan_k<<<1, 64, 0, stream>>>(counts, baseA);
    compact_k<<<NL, 256, 0, stream>>>(labels, baseA, indexA, posA);
    // qkv = x @ Wqkv (unsorted)
    gemm_k512<QKVC, false><<<dim3(N_TOK / 128, QKVC / 256), 256, 0, stream>>>(xh, WqkvT, qkvh, nullptr);
    // segment pooling
    pool_k<<<dim3(NL, NH), 64, 0, stream>>>(qkvh, indexA, baseA, counts, ql, kl);
    // attn2 + pinv chain (f32)
    attn2_k<<<NH, 256, 0, stream>>>(ql, kl, a2, mrow, mcol);
    pinv_k<<<NH, 256, 0, stream>>>(a2, mrow, mcol, zb);
    // T = softmax(ql@k^T) @ v  (chunked online softmax)
    attn3_k<<<dim3(NCHUNK, NH), 256, 0, stream>>>(qkvh, ql, pm, ps, pacc);
    attn3_merge_k<<<dim3(NL, NH), 64, 0, stream>>>(pm, ps, pacc, Tb);
    // M = z @ T
    zmatT_k<<<NH, 256, 0, stream>>>(zb, Tb, Mb);
    // depthwise conv over sorted v (writes resS == d_out scratch)
    conv_k<<<dim3(N_TOK / 256, NH), 256, 0, stream>>>(qkvh, indexA, resk, resS);
    // attn1 + combine -> Yh
    attn1_k<<<dim3(N_TOK / 256, NH), 256, 0, stream>>>(qkvh, kl, Mb, posA, resS, Yh);
    // final projection + bias -> d_out
    gemm_k512<DIMC, true><<<dim3(N_TOK / 128, DIMC / 256), 256, 0, stream>>>(Yh, WoutT, out, bout);
}

// Round 2
// 740.234 us; speedup vs baseline: 1.5294x; 1.5294x over previous
//
#include <hip/hip_runtime.h>
#include <hip/hip_bf16.h>

// ---------------- problem constants ----------------
#define N_TOK 32768
#define DIMC  512
#define NH    8
#define DHD   64
#define NL    64
#define KSZ   33
#define QKVC  1536
#define NCHUNK 32   // attn3 n-chunks per head (1024 tokens each)

typedef _Float16 f16;
typedef _Float16 f16x8 __attribute__((ext_vector_type(8)));
typedef _Float16 f16x4 __attribute__((ext_vector_type(4)));
typedef float    f32x4 __attribute__((ext_vector_type(4)));

// ---------------- transpose f32 (R x C) -> f16 (C x R) ----------------
__global__ void transpose_k(const float* __restrict__ W, f16* __restrict__ WT, int R, int C) {
    __shared__ float tile[32][33];
    int bx = blockIdx.x * 32, by = blockIdx.y * 32;
    int tx = threadIdx.x, ty = threadIdx.y;
    #pragma unroll
    for (int i = 0; i < 32; i += 8)
        tile[ty + i][tx] = W[(size_t)(by + ty + i) * C + bx + tx];
    __syncthreads();
    #pragma unroll
    for (int i = 0; i < 32; i += 8)
        WT[(size_t)(bx + ty + i) * R + by + tx] = (f16)tile[tx][ty + i];
}

// ---------------- label histogram ----------------
__global__ void hist_k(const int* __restrict__ labels, int* __restrict__ counts) {
    __shared__ int hloc[NL];
    int t = threadIdx.x;
    if (t < NL) hloc[t] = 0;
    __syncthreads();
    int i = blockIdx.x * 256 + t;
    atomicAdd(&hloc[labels[i]], 1);
    __syncthreads();
    if (t < NL) atomicAdd(&counts[t], hloc[t]);
}

// ---------------- exclusive prefix over 64 counts ----------------
__global__ void scan_k(const int* __restrict__ counts, int* __restrict__ base) {
    if (threadIdx.x == 0) {
        int s = 0;
        for (int l = 0; l < NL; ++l) { base[l] = s; s += counts[l]; }
    }
}

// ---------------- stable compaction: one block per label ----------------
__global__ __launch_bounds__(256) void compact_k(const int* __restrict__ labels,
                                                 const int* __restrict__ base,
                                                 int* __restrict__ indexArr) {
    const int l = blockIdx.x;
    __shared__ int wtot[4];
    __shared__ int s_run;
    int t = threadIdx.x, lane = t & 63, w = t >> 6;
    if (t == 0) s_run = base[l];
    __syncthreads();
    for (int c0 = 0; c0 < N_TOK; c0 += 256) {
        int ii = c0 + t;
        bool flag = (labels[ii] == l);
        unsigned long long mask = __ballot(flag);
        int before = __popcll(mask & ((1ull << lane) - 1ull));
        if (lane == 0) wtot[w] = __popcll(mask);
        __syncthreads();
        int off = 0;
        #pragma unroll
        for (int ww = 0; ww < 4; ++ww) off += (ww < w) ? wtot[ww] : 0;
        int tot = wtot[0] + wtot[1] + wtot[2] + wtot[3];
        int rb = s_run;
        if (flag) indexArr[rb + off + before] = ii;
        __syncthreads();
        if (t == 0) s_run = rb + tot;
    }
}

// ---------------- gather rows of x via index, convert to f16 (sorted domain) ----------------
__global__ __launch_bounds__(256) void gather_cvt_k(const float4* __restrict__ x4,
                                                    const int* __restrict__ indexArr,
                                                    f16x4* __restrict__ xh4) {
    int t = threadIdx.x;
    int row = blockIdx.x * 2 + (t >> 7);
    int c4 = t & 127;
    int j = indexArr[row];
    float4 v = x4[(size_t)j * 128 + c4];
    f16x4 o = { (f16)v.x, (f16)v.y, (f16)v.z, (f16)v.w };
    xh4[(size_t)row * 128 + c4] = o;
}

// ---------------- f16 MFMA GEMM: C[M x BNTOT] = A[M x 512] @ BT[BNTOT x 512]^T ----------------
template<int BNTOT, bool OUT_F32>
__global__ __launch_bounds__(256) void gemm_k512(const f16* __restrict__ A, const f16* __restrict__ BT,
                                                 void* __restrict__ Cout, const float* __restrict__ bias,
                                                 const int* __restrict__ scatterIdx) {
    constexpr int K = 512;
    __shared__ f16 As[128][40];
    __shared__ f16 Bs[256][40];
    const int t = threadIdx.x;
    const int mBase = blockIdx.x * 128;
    const int nBase = blockIdx.y * 256;
    const int w = t >> 6, lane = t & 63;
    const int lr = lane & 15, lk = lane >> 4;
    f32x4 acc[8][4];
    #pragma unroll
    for (int m = 0; m < 8; ++m)
        #pragma unroll
        for (int n = 0; n < 4; ++n) acc[m][n] = (f32x4){0.f, 0.f, 0.f, 0.f};

    for (int kt = 0; kt < K / 32; ++kt) {
        __syncthreads();
        #pragma unroll
        for (int c = 0; c < 2; ++c) {
            int id = c * 256 + t, row = id >> 2, slot = id & 3;
            *(int4*)&As[row][slot * 8] = *(const int4*)&A[(size_t)(mBase + row) * K + kt * 32 + slot * 8];
        }
        #pragma unroll
        for (int c = 0; c < 4; ++c) {
            int id = c * 256 + t, row = id >> 2, slot = id & 3;
            *(int4*)&Bs[row][slot * 8] = *(const int4*)&BT[(size_t)(nBase + row) * K + kt * 32 + slot * 8];
        }
        __syncthreads();
        f16x8 af[8], bf[4];
        #pragma unroll
        for (int m = 0; m < 8; ++m) af[m] = *(const f16x8*)&As[m * 16 + lr][lk * 8];
        #pragma unroll
        for (int n = 0; n < 4; ++n) bf[n] = *(const f16x8*)&Bs[w * 64 + n * 16 + lr][lk * 8];
        #pragma unroll
        for (int m = 0; m < 8; ++m)
            #pragma unroll
            for (int n = 0; n < 4; ++n)
                acc[m][n] = __builtin_amdgcn_mfma_f32_16x16x32_f16(af[m], bf[n], acc[m][n], 0, 0, 0);
    }
    #pragma unroll
    for (int m = 0; m < 8; ++m) {
        #pragma unroll
        for (int j = 0; j < 4; ++j) {
            int row = mBase + m * 16 + lk * 4 + j;
            int srow = OUT_F32 ? scatterIdx[row] : row;
            #pragma unroll
            for (int n = 0; n < 4; ++n) {
                int col = nBase + w * 64 + n * 16 + lr;
                if constexpr (OUT_F32)
                    ((float*)Cout)[(size_t)srow * BNTOT + col] = acc[m][n][j] + bias[col];
                else
                    ((f16*)Cout)[(size_t)srow * BNTOT + col] = (f16)acc[m][n][j];
            }
        }
    }
}

// ---------------- segment-mean pooling of sorted q,k -> ql,kl (f32) ----------------
__global__ __launch_bounds__(256) void pool_k(const f16* __restrict__ qkvh,
                                              const int* __restrict__ base, const int* __restrict__ counts,
                                              float* __restrict__ ql, float* __restrict__ kl) {
    int l = blockIdx.x, h = blockIdx.y;
    int t = threadIdx.x, d = t & 63, g = t >> 6;
    int b0 = base[l], cnt = counts[l];
    float sq = 0.f, sk = 0.f;
    for (int p = g; p < cnt; p += 4) {
        size_t ro = (size_t)(b0 + p) * QKVC + h * 64 + d;
        sq += (float)qkvh[ro];
        sk += (float)qkvh[ro + 512];
    }
    __shared__ float rq[4][64], rk[4][64];
    rq[g][d] = sq; rk[g][d] = sk;
    __syncthreads();
    if (t < 64) {
        float inv = 1.0f / (float)(cnt > 0 ? cnt : 1);
        ql[(h * 64 + l) * 64 + t] = (rq[0][t] + rq[1][t] + rq[2][t] + rq[3][t]) * inv;
        kl[(h * 64 + l) * 64 + t] = (rk[0][t] + rk[1][t] + rk[2][t] + rk[3][t]) * inv;
    }
}

// ---------------- attn2 = softmax(ql@kl^T) rows; per-head row/col abs-sum maxes ----------------
__global__ __launch_bounds__(256) void attn2_k(const float* __restrict__ ql, const float* __restrict__ kl,
                                               float* __restrict__ a_out, float* __restrict__ mrow,
                                               float* __restrict__ mcol) {
    int h = blockIdx.x;
    __shared__ float qs[64][65], ks[64][65], a[64][65];
    __shared__ float red[64][4];
    __shared__ float rowv[64], colv[64];
    int t = threadIdx.x;
    for (int idx = t; idx < 4096; idx += 256) {
        int r = idx >> 6, c = idx & 63;
        qs[r][c] = ql[h * 4096 + idx];
        ks[r][c] = kl[h * 4096 + idx];
    }
    __syncthreads();
    int i = t >> 2, q4 = t & 3, j0 = q4 * 16;
    float o[16];
    #pragma unroll
    for (int jj = 0; jj < 16; ++jj) o[jj] = 0.f;
    for (int d = 0; d < 64; ++d) {
        float qv = qs[i][d];
        #pragma unroll
        for (int jj = 0; jj < 16; ++jj) o[jj] += qv * ks[j0 + jj][d];
    }
    float pmx = o[0];
    #pragma unroll
    for (int jj = 1; jj < 16; ++jj) pmx = fmaxf(pmx, o[jj]);
    red[i][q4] = pmx;
    __syncthreads();
    float rm = fmaxf(fmaxf(red[i][0], red[i][1]), fmaxf(red[i][2], red[i][3]));
    float psum = 0.f;
    #pragma unroll
    for (int jj = 0; jj < 16; ++jj) { o[jj] = expf(o[jj] - rm); psum += o[jj]; }
    __syncthreads();
    red[i][q4] = psum;
    __syncthreads();
    float rs = red[i][0] + red[i][1] + red[i][2] + red[i][3];
    float inv = 1.0f / rs;
    #pragma unroll
    for (int jj = 0; jj < 16; ++jj) { o[jj] *= inv; a[i][j0 + jj] = o[jj]; }
    __syncthreads();
    for (int idx = t; idx < 4096; idx += 256) a_out[h * 4096 + idx] = a[idx >> 6][idx & 63];
    float rsum = 0.f;
    #pragma unroll
    for (int jj = 0; jj < 16; ++jj) rsum += o[jj];
    __syncthreads();
    red[i][q4] = rsum;
    __syncthreads();
    if (q4 == 0) rowv[i] = red[i][0] + red[i][1] + red[i][2] + red[i][3];
    float csum = 0.f;
    #pragma unroll
    for (int jj = 0; jj < 16; ++jj) csum += a[j0 + jj][i];
    __syncthreads();
    red[i][q4] = csum;
    __syncthreads();
    if (q4 == 0) colv[i] = red[i][0] + red[i][1] + red[i][2] + red[i][3];
    __syncthreads();
    if (t == 0) {
        float mr = rowv[0], mc = colv[0];
        for (int j = 1; j < 64; ++j) { mr = fmaxf(mr, rowv[j]); mc = fmaxf(mc, colv[j]); }
        mrow[h] = mr; mcol[h] = mc;
    }
}

// 4x4-blocked 64x64 matmul helper (operands in LDS, stride 68)
__device__ __forceinline__ void mm_blk(const float (*X)[68], const float (*Y)[68],
                                       int i0, int j0, float o[4][4]) {
    #pragma unroll
    for (int ii = 0; ii < 4; ++ii)
        #pragma unroll
        for (int jj = 0; jj < 4; ++jj) o[ii][jj] = 0.f;
    for (int k = 0; k < 64; ++k) {
        float4 yv = *(const float4*)&Y[k][j0];
        float x0 = X[i0][k], x1 = X[i0 + 1][k], x2 = X[i0 + 2][k], x3 = X[i0 + 3][k];
        o[0][0] += x0 * yv.x; o[0][1] += x0 * yv.y; o[0][2] += x0 * yv.z; o[0][3] += x0 * yv.w;
        o[1][0] += x1 * yv.x; o[1][1] += x1 * yv.y; o[1][2] += x1 * yv.z; o[1][3] += x1 * yv.w;
        o[2][0] += x2 * yv.x; o[2][1] += x2 * yv.y; o[2][2] += x2 * yv.z; o[2][3] += x2 * yv.w;
        o[3][0] += x3 * yv.x; o[3][1] += x3 * yv.y; o[3][2] += x3 * yv.z; o[3][3] += x3 * yv.w;
    }
}

// ---------------- Newton-Schulz pinv (6 iters, f32, per head) ----------------
__global__ __launch_bounds__(256) void pinv_k(const float* __restrict__ a_g, const float* __restrict__ mrow,
                                              const float* __restrict__ mcol, float* __restrict__ z_g) {
    int h = blockIdx.x;
    __shared__ float a[64][68], z[64][68], C[64][68], D[64][68], E[64][68];
    int t = threadIdx.x;
    float mr = mrow[0], mc = mcol[0];
    #pragma unroll
    for (int k = 1; k < 8; ++k) { mr = fmaxf(mr, mrow[k]); mc = fmaxf(mc, mcol[k]); }
    float inv0 = 1.0f / (mr * mc);
    for (int idx = t; idx < 4096; idx += 256) {
        int r = idx >> 6, c = idx & 63;
        float av = a_g[h * 4096 + idx];
        a[r][c] = av;
        z[c][r] = av * inv0;
    }
    __syncthreads();
    int i0 = (t >> 4) * 4, j0 = (t & 15) * 4;
    float o[4][4];
    for (int it = 0; it < 6; ++it) {
        mm_blk(a, z, i0, j0, o);
        #pragma unroll
        for (int ii = 0; ii < 4; ++ii)
            #pragma unroll
            for (int jj = 0; jj < 4; ++jj) C[i0 + ii][j0 + jj] = o[ii][jj];
        __syncthreads();
        mm_blk(C, C, i0, j0, o);
        #pragma unroll
        for (int ii = 0; ii < 4; ++ii)
            #pragma unroll
            for (int jj = 0; jj < 4; ++jj) D[i0 + ii][j0 + jj] = 7.f * C[i0 + ii][j0 + jj] - o[ii][jj];
        __syncthreads();
        mm_blk(C, D, i0, j0, o);
        #pragma unroll
        for (int ii = 0; ii < 4; ++ii)
            #pragma unroll
            for (int jj = 0; jj < 4; ++jj) E[i0 + ii][j0 + jj] = 15.f * C[i0 + ii][j0 + jj] - o[ii][jj];
        __syncthreads();
        mm_blk(z, E, i0, j0, o);
        #pragma unroll
        for (int ii = 0; ii < 4; ++ii)
            #pragma unroll
            for (int jj = 0; jj < 4; ++jj) D[i0 + ii][j0 + jj] = 0.25f * (13.f * z[i0 + ii][j0 + jj] - o[ii][jj]);
        __syncthreads();
        #pragma unroll
        for (int ii = 0; ii < 4; ++ii)
            #pragma unroll
            for (int jj = 0; jj < 4; ++jj) z[i0 + ii][j0 + jj] = D[i0 + ii][j0 + jj];
        __syncthreads();
    }
    for (int idx = t; idx < 4096; idx += 256) z_g[h * 4096 + idx] = z[idx >> 6][idx & 63];
}

// ---------------- attn3 @ v: chunked online-softmax partials ----------------
__global__ __launch_bounds__(256) void attn3_k(const f16* __restrict__ qkvh, const float* __restrict__ ql,
                                               float* __restrict__ pm, float* __restrict__ ps,
                                               float* __restrict__ pacc) {
    int cx = blockIdx.x, h = blockIdx.y;
    __shared__ float qls[64][68];
    __shared__ float kts[64][68];
    __shared__ float vs[64][68];
    __shared__ float S[64][68];
    __shared__ float red[64][4];
    __shared__ float ml[64], sl[64];
    int t = threadIdx.x;
    for (int idx = t; idx < 4096; idx += 256) qls[idx >> 6][idx & 63] = ql[h * 4096 + idx];
    if (t < 64) { ml[t] = -1e30f; sl[t] = 0.f; }
    int i = t >> 2, q4 = t & 3, j0 = q4 * 16;
    float acc[16];
    #pragma unroll
    for (int jj = 0; jj < 16; ++jj) acc[jj] = 0.f;
    __syncthreads();
    for (int sub = 0; sub < 16; ++sub) {
        int n0 = cx * 1024 + sub * 64;
        for (int idx = t; idx < 4096; idx += 256) {
            int r = idx >> 6, c = idx & 63;
            size_t ro = (size_t)(n0 + r) * QKVC + 512 + h * 64 + c;
            kts[c][r] = (float)qkvh[ro];
            vs[r][c] = (float)qkvh[ro + 512];
        }
        __syncthreads();
        float o[16];
        #pragma unroll
        for (int jj = 0; jj < 16; ++jj) o[jj] = 0.f;
        for (int d = 0; d < 64; ++d) {
            float qv = qls[i][d];
            #pragma unroll
            for (int w = 0; w < 4; ++w) {
                float4 kv = *(const float4*)&kts[d][j0 + w * 4];
                o[w * 4 + 0] += qv * kv.x; o[w * 4 + 1] += qv * kv.y;
                o[w * 4 + 2] += qv * kv.z; o[w * 4 + 3] += qv * kv.w;
            }
        }
        float tm = o[0];
        #pragma unroll
        for (int jj = 1; jj < 16; ++jj) tm = fmaxf(tm, o[jj]);
        red[i][q4] = tm;
        __syncthreads();
        float rowm = fmaxf(fmaxf(red[i][0], red[i][1]), fmaxf(red[i][2], red[i][3]));
        float oldm = ml[i];
        float newm = fmaxf(oldm, rowm);
        float f = __expf(oldm - newm);
        float psum = 0.f;
        #pragma unroll
        for (int jj = 0; jj < 16; ++jj) { o[jj] = __expf(o[jj] - newm); psum += o[jj]; }
        #pragma unroll
        for (int w = 0; w < 4; ++w)
            *(float4*)&S[i][j0 + w * 4] = make_float4(o[w * 4], o[w * 4 + 1], o[w * 4 + 2], o[w * 4 + 3]);
        __syncthreads();
        red[i][q4] = psum;
        __syncthreads();
        float tsum = red[i][0] + red[i][1] + red[i][2] + red[i][3];
        if (q4 == 0) { sl[i] = sl[i] * f + tsum; ml[i] = newm; }
        #pragma unroll
        for (int jj = 0; jj < 16; ++jj) acc[jj] *= f;
        for (int k = 0; k < 64; ++k) {
            float pv = S[i][k];
            #pragma unroll
            for (int w = 0; w < 4; ++w) {
                float4 vv = *(const float4*)&vs[k][j0 + w * 4];
                acc[w * 4 + 0] += pv * vv.x; acc[w * 4 + 1] += pv * vv.y;
                acc[w * 4 + 2] += pv * vv.z; acc[w * 4 + 3] += pv * vv.w;
            }
        }
        __syncthreads();
    }
    if (q4 == 0) {
        pm[(h * NCHUNK + cx) * 64 + i] = ml[i];
        ps[(h * NCHUNK + cx) * 64 + i] = sl[i];
    }
    size_t po = ((size_t)(h * NCHUNK + cx) * 64 + i) * 64 + j0;
    #pragma unroll
    for (int w = 0; w < 4; ++w)
        *(float4*)&pacc[po + w * 4] = make_float4(acc[w * 4], acc[w * 4 + 1], acc[w * 4 + 2], acc[w * 4 + 3]);
}

// ---------------- merge attn3 partials -> T[h][l][d] ----------------
__global__ void attn3_merge_k(const float* __restrict__ pm, const float* __restrict__ ps,
                              const float* __restrict__ pacc, float* __restrict__ T) {
    int l = blockIdx.x, h = blockIdx.y, d = threadIdx.x;
    float m = -1e30f;
    for (int c = 0; c < NCHUNK; ++c) m = fmaxf(m, pm[(h * NCHUNK + c) * 64 + l]);
    float s = 0.f, a = 0.f;
    for (int c = 0; c < NCHUNK; ++c) {
        float wgt = __expf(pm[(h * NCHUNK + c) * 64 + l] - m);
        s += ps[(h * NCHUNK + c) * 64 + l] * wgt;
        a += pacc[((size_t)(h * NCHUNK + c) * 64 + l) * 64 + d] * wgt;
    }
    T[(h * 64 + l) * 64 + d] = a / s;
}

// ---------------- M = z @ T per head ----------------
__global__ __launch_bounds__(256) void zmatT_k(const float* __restrict__ z_g, const float* __restrict__ T,
                                               float* __restrict__ M) {
    int h = blockIdx.x;
    __shared__ float zs[64][68], Ts[64][68];
    int t = threadIdx.x;
    for (int idx = t; idx < 4096; idx += 256) {
        int r = idx >> 6, c = idx & 63;
        zs[r][c] = z_g[h * 4096 + idx];
        Ts[r][c] = T[h * 4096 + idx];
    }
    __syncthreads();
    int i0 = (t >> 4) * 4, j0 = (t & 15) * 4;
    float o[4][4];
    mm_blk(zs, Ts, i0, j0, o);
    #pragma unroll
    for (int ii = 0; ii < 4; ++ii)
        #pragma unroll
        for (int jj = 0; jj < 4; ++jj)
            M[h * 4096 + (i0 + ii) * 64 + j0 + jj] = o[ii][jj];
}

// ---------------- depthwise conv over sorted v (streaming) -> resH (f16) ----------------
__global__ __launch_bounds__(256) void conv_k(const f16* __restrict__ qkvh,
                                              const float* __restrict__ resk, f16* __restrict__ resH) {
    int h = blockIdx.y;
    int p0 = blockIdx.x * 256;
    __shared__ f16 vt[288][72];
    int t = threadIdx.x;
    for (int id = t; id < 288 * 8; id += 256) {
        int rr = id >> 3, c = id & 7;
        int pg = p0 - 16 + rr;
        int4 v = {0, 0, 0, 0};
        if (pg >= 0 && pg < N_TOK)
            v = *(const int4*)&qkvh[(size_t)pg * QKVC + 1024 + h * 64 + c * 8];
        *(int4*)&vt[rr][c * 8] = v;
    }
    float wk[KSZ];
    #pragma unroll
    for (int k = 0; k < KSZ; ++k) wk[k] = resk[h * KSZ + k];
    __syncthreads();
    int d = t & 63, pg4 = t >> 6;
    float col[96];
    #pragma unroll
    for (int i2 = 0; i2 < 96; ++i2) col[i2] = (float)vt[pg4 * 64 + i2][d];
    #pragma unroll
    for (int pp = 0; pp < 64; ++pp) {
        float acc = 0.f;
        #pragma unroll
        for (int k = 0; k < KSZ; ++k) acc += wk[k] * col[pp + k];
        resH[(size_t)(p0 + pg4 * 64 + pp) * 512 + h * 64 + d] = (f16)acc;
    }
}

// ---------------- attn1 softmax + @M + residual -> Yh (f16, sorted domain) ----------------
__global__ __launch_bounds__(256) void attn1_k(const f16* __restrict__ qkvh, const float* __restrict__ kl,
                                               const float* __restrict__ M, const f16* __restrict__ resH,
                                               f16* __restrict__ Yh) {
    int h = blockIdx.y;
    int p0 = blockIdx.x * 64;
    int t = threadIdx.x;
    __shared__ float qs[64][68];
    __shared__ float kls[64][68];
    __shared__ float Ms[64][68];
    __shared__ float S[64][68];
    __shared__ float red[64][4];
    for (int idx = t; idx < 4096; idx += 256) {
        int r = idx >> 6, c = idx & 63;
        kls[r][c] = kl[h * 4096 + idx];
        Ms[r][c] = M[h * 4096 + idx];
        qs[r][c] = (float)qkvh[(size_t)(p0 + r) * QKVC + h * 64 + c];
    }
    __syncthreads();
    int i = t >> 2, q4 = t & 3, j0 = q4 * 16;
    float p[16];
    #pragma unroll
    for (int jj = 0; jj < 16; ++jj) p[jj] = 0.f;
    for (int d = 0; d < 64; ++d) {
        float qv = qs[i][d];
        #pragma unroll
        for (int jj = 0; jj < 16; ++jj) p[jj] += qv * kls[j0 + jj][d];
    }
    float pmx = p[0];
    #pragma unroll
    for (int jj = 1; jj < 16; ++jj) pmx = fmaxf(pmx, p[jj]);
    red[i][q4] = pmx;
    __syncthreads();
    float rm = fmaxf(fmaxf(red[i][0], red[i][1]), fmaxf(red[i][2], red[i][3]));
    float psum = 0.f;
    #pragma unroll
    for (int jj = 0; jj < 16; ++jj) { p[jj] = __expf(p[jj] - rm); psum += p[jj]; }
    __syncthreads();
    red[i][q4] = psum;
    __syncthreads();
    float rs = red[i][0] + red[i][1] + red[i][2] + red[i][3];
    float inv = 1.0f / rs;
    #pragma unroll
    for (int w = 0; w < 4; ++w) {
        float4 sv = make_float4(p[w * 4] * inv, p[w * 4 + 1] * inv, p[w * 4 + 2] * inv, p[w * 4 + 3] * inv);
        *(float4*)&S[i][j0 + w * 4] = sv;
    }
    __syncthreads();
    float acc[16];
    #pragma unroll
    for (int dd = 0; dd < 16; ++dd) acc[dd] = 0.f;
    for (int l = 0; l < 64; ++l) {
        float sv = S[i][l];
        #pragma unroll
        for (int w = 0; w < 4; ++w) {
            float4 mv = *(const float4*)&Ms[l][j0 + w * 4];
            acc[w * 4 + 0] += sv * mv.x; acc[w * 4 + 1] += sv * mv.y;
            acc[w * 4 + 2] += sv * mv.z; acc[w * 4 + 3] += sv * mv.w;
        }
    }
    size_t ro = (size_t)(p0 + i) * 512 + h * 64 + j0;
    f16x8 r0 = *(const f16x8*)&resH[ro];
    f16x8 r1 = *(const f16x8*)&resH[ro + 8];
    f16x8 y0, y1;
    #pragma unroll
    for (int e = 0; e < 8; ++e) {
        y0[e] = (f16)(acc[e] + (float)r0[e]);
        y1[e] = (f16)(acc[8 + e] + (float)r1[e]);
    }
    *(f16x8*)&Yh[ro] = y0;
    *(f16x8*)&Yh[ro + 8] = y1;
}

// ---------------- host launch ----------------
extern "C" void kernel_launch(void* const* d_in, const int* in_sizes, int n_in,
                              void* d_out, int out_size, void* d_ws, size_t ws_size,
                              hipStream_t stream) {
    const float* x    = (const float*)d_in[0];
    const float* Wqkv = (const float*)d_in[1];
    const float* Wout = (const float*)d_in[2];
    const float* bout = (const float*)d_in[3];
    const float* resk = (const float*)d_in[4];
    const int*   labels = (const int*)d_in[5];
    float* out = (float*)d_out;

    char* w = (char*)d_ws;
    size_t off = 0;
    auto alloc = [&](size_t bytes) {
        void* p = w + off;
        off += (bytes + 255) & ~(size_t)255;
        return p;
    };
    f16* xh     = (f16*)alloc((size_t)N_TOK * DIMC * 2);       // sorted
    f16* qkvh   = (f16*)alloc((size_t)N_TOK * QKVC * 2);       // sorted
    f16* WqkvT  = (f16*)alloc((size_t)QKVC * DIMC * 2);
    f16* WoutT  = (f16*)alloc((size_t)DIMC * DIMC * 2);
    f16* Yh     = (f16*)alloc((size_t)N_TOK * DIMC * 2);       // sorted
    int* counts = (int*)alloc(NL * 4);
    int* baseA  = (int*)alloc(NL * 4);
    int* indexA = (int*)alloc((size_t)N_TOK * 4);
    float* ql   = (float*)alloc((size_t)NH * 64 * 64 * 4);
    float* kl   = (float*)alloc((size_t)NH * 64 * 64 * 4);
    float* a2   = (float*)alloc((size_t)NH * 64 * 64 * 4);
    float* mrow = (float*)alloc(NH * 4);
    float* mcol = (float*)alloc(NH * 4);
    float* zb   = (float*)alloc((size_t)NH * 64 * 64 * 4);
    float* Tb   = (float*)alloc((size_t)NH * 64 * 64 * 4);
    float* Mb   = (float*)alloc((size_t)NH * 64 * 64 * 4);
    float* pm   = (float*)alloc((size_t)NH * NCHUNK * 64 * 4);
    float* ps   = (float*)alloc((size_t)NH * NCHUNK * 64 * 4);
    float* pacc = (float*)alloc((size_t)NH * NCHUNK * 64 * 64 * 4);
    f16* resH = (f16*)d_out;  // reuse d_out (64MB) as f16 conv output (32MB); overwritten by final GEMM

    hipMemsetAsync(counts, 0, NL * 4, stream);

    // stable counting sort
    hist_k<<<N_TOK / 256, 256, 0, stream>>>(labels, counts);
    scan_k<<<1, 64, 0, stream>>>(counts, baseA);
    compact_k<<<NL, 256, 0, stream>>>(labels, baseA, indexA);
    // gather+convert x rows into sorted order
    gather_cvt_k<<<N_TOK / 2, 256, 0, stream>>>((const float4*)x, indexA, (f16x4*)xh);
    // weight transposes
    transpose_k<<<dim3(QKVC / 32, DIMC / 32), dim3(32, 8), 0, stream>>>(Wqkv, WqkvT, DIMC, QKVC);
    transpose_k<<<dim3(DIMC / 32, DIMC / 32), dim3(32, 8), 0, stream>>>(Wout, WoutT, DIMC, DIMC);
    // qkv = x_sorted @ Wqkv  (sorted domain)
    gemm_k512<QKVC, false><<<dim3(N_TOK / 128, QKVC / 256), 256, 0, stream>>>(xh, WqkvT, qkvh, nullptr, nullptr);
    // segment pooling (contiguous segments now)
    pool_k<<<dim3(NL, NH), 256, 0, stream>>>(qkvh, baseA, counts, ql, kl);
    // attn2 + pinv chain (f32)
    attn2_k<<<NH, 256, 0, stream>>>(ql, kl, a2, mrow, mcol);
    pinv_k<<<NH, 256, 0, stream>>>(a2, mrow, mcol, zb);
    // T = softmax(ql@k^T) @ v  (chunked online softmax)
    attn3_k<<<dim3(NCHUNK, NH), 256, 0, stream>>>(qkvh, ql, pm, ps, pacc);
    attn3_merge_k<<<dim3(NL, NH), 64, 0, stream>>>(pm, ps, pacc, Tb);
    // M = z @ T
    zmatT_k<<<NH, 256, 0, stream>>>(zb, Tb, Mb);
    // depthwise conv over sorted v (streaming)
    conv_k<<<dim3(N_TOK / 256, NH), 256, 0, stream>>>(qkvh, resk, resH);
    // attn1 + combine -> Yh (sorted)
    attn1_k<<<dim3(N_TOK / 64, NH), 256, 0, stream>>>(qkvh, kl, Mb, resH, Yh);
    // final projection + bias, scatter rows back to original order
    gemm_k512<DIMC, true><<<dim3(N_TOK / 128, DIMC / 256), 256, 0, stream>>>(Yh, WoutT, out, bout, indexA);
}

// Round 3
// 577.215 us; speedup vs baseline: 1.9613x; 1.2824x over previous
//
#include <hip/hip_runtime.h>
#include <hip/hip_bf16.h>

// ---------------- problem constants ----------------
#define N_TOK 32768
#define DIMC  512
#define NH    8
#define DHD   64
#define NL    64
#define KSZ   33
#define QKVC  1536
#define NCHUNK 32   // attn3 n-chunks per head (1024 tokens each)

typedef _Float16 f16;
typedef _Float16 f16x8 __attribute__((ext_vector_type(8)));
typedef _Float16 f16x4 __attribute__((ext_vector_type(4)));
typedef float    f32x4 __attribute__((ext_vector_type(4)));

#define GLOAD_LDS16(gp, lp) \
    __builtin_amdgcn_global_load_lds((const __attribute__((address_space(1))) void*)(gp), \
                                     (__attribute__((address_space(3))) void*)(lp), 16, 0, 0)

// ---------------- transpose f32 (R x C) -> f16 (C x R) ----------------
__global__ void transpose_k(const float* __restrict__ W, f16* __restrict__ WT, int R, int C) {
    __shared__ float tile[32][33];
    int bx = blockIdx.x * 32, by = blockIdx.y * 32;
    int tx = threadIdx.x, ty = threadIdx.y;
    #pragma unroll
    for (int i = 0; i < 32; i += 8)
        tile[ty + i][tx] = W[(size_t)(by + ty + i) * C + bx + tx];
    __syncthreads();
    #pragma unroll
    for (int i = 0; i < 32; i += 8)
        WT[(size_t)(bx + ty + i) * R + by + tx] = (f16)tile[tx][ty + i];
}

// ---------------- label histogram ----------------
__global__ void hist_k(const int* __restrict__ labels, int* __restrict__ counts) {
    __shared__ int hloc[NL];
    int t = threadIdx.x;
    if (t < NL) hloc[t] = 0;
    __syncthreads();
    int i = blockIdx.x * 256 + t;
    atomicAdd(&hloc[labels[i]], 1);
    __syncthreads();
    if (t < NL) atomicAdd(&counts[t], hloc[t]);
}

// ---------------- exclusive prefix over 64 counts ----------------
__global__ void scan_k(const int* __restrict__ counts, int* __restrict__ base) {
    if (threadIdx.x == 0) {
        int s = 0;
        for (int l = 0; l < NL; ++l) { base[l] = s; s += counts[l]; }
    }
}

// ---------------- stable compaction: one block per label ----------------
__global__ __launch_bounds__(256) void compact_k(const int* __restrict__ labels,
                                                 const int* __restrict__ base,
                                                 int* __restrict__ indexArr) {
    const int l = blockIdx.x;
    __shared__ int wtot[4];
    __shared__ int s_run;
    int t = threadIdx.x, lane = t & 63, w = t >> 6;
    if (t == 0) s_run = base[l];
    __syncthreads();
    for (int c0 = 0; c0 < N_TOK; c0 += 256) {
        int ii = c0 + t;
        bool flag = (labels[ii] == l);
        unsigned long long mask = __ballot(flag);
        int before = __popcll(mask & ((1ull << lane) - 1ull));
        if (lane == 0) wtot[w] = __popcll(mask);
        __syncthreads();
        int off = 0;
        #pragma unroll
        for (int ww = 0; ww < 4; ++ww) off += (ww < w) ? wtot[ww] : 0;
        int tot = wtot[0] + wtot[1] + wtot[2] + wtot[3];
        int rb = s_run;
        if (flag) indexArr[rb + off + before] = ii;
        __syncthreads();
        if (t == 0) s_run = rb + tot;
    }
}

// ---------------- gather rows of x via index, convert to f16 (sorted domain) ----------------
__global__ __launch_bounds__(256) void gather_cvt_k(const float4* __restrict__ x4,
                                                    const int* __restrict__ indexArr,
                                                    f16x4* __restrict__ xh4) {
    int t = threadIdx.x;
    int row = blockIdx.x * 2 + (t >> 7);
    int c4 = t & 127;
    int j = indexArr[row];
    float4 v = x4[(size_t)j * 128 + c4];
    f16x4 o = { (f16)v.x, (f16)v.y, (f16)v.z, (f16)v.w };
    xh4[(size_t)row * 128 + c4] = o;
}

// ---------------- f16 MFMA GEMM: C[M x BNTOT] = A[M x 512] @ BT[BNTOT x 512]^T ----------------
// tile 128x256, BK=32, 4 waves; global_load_lds width-16 staging into linear LDS (m97 pattern)
template<int BNTOT, bool OUT_F32>
__global__ __launch_bounds__(256) void gemm_k512(const f16* __restrict__ A, const f16* __restrict__ BT,
                                                 void* __restrict__ Cout, const float* __restrict__ bias,
                                                 const int* __restrict__ scatterIdx) {
    constexpr int K = 512;
    __shared__ f16 As[128][32];
    __shared__ f16 Bs[256][32];
    const int t = threadIdx.x;
    const int mBase = blockIdx.x * 128;
    const int nBase = blockIdx.y * 256;
    const int w = t >> 6, lane = t & 63;
    const int lr = lane & 15, lk = lane >> 4;
    f32x4 acc[8][4];
    #pragma unroll
    for (int m = 0; m < 8; ++m)
        #pragma unroll
        for (int n = 0; n < 4; ++n) acc[m][n] = (f32x4){0.f, 0.f, 0.f, 0.f};

    for (int kt = 0; kt < K / 32; ++kt) {
        __syncthreads();
        // A: 512 chunks of 16B (128 rows x 4 slots); 2 rounds x 4 waves x 64 lanes
        #pragma unroll
        for (int r = 0; r < 2; ++r) {
            int c = r * 256 + w * 64 + lane;
            int row = c >> 2, slot = c & 3;
            const f16* gp = &A[(size_t)(mBase + row) * K + kt * 32 + slot * 8];
            f16* lp = &As[0][0] + (size_t)(r * 256 + w * 64) * 8;
            GLOAD_LDS16(gp, lp);
        }
        // B: 1024 chunks; 4 rounds
        #pragma unroll
        for (int r = 0; r < 4; ++r) {
            int c = r * 256 + w * 64 + lane;
            int row = c >> 2, slot = c & 3;
            const f16* gp = &BT[(size_t)(nBase + row) * K + kt * 32 + slot * 8];
            f16* lp = &Bs[0][0] + (size_t)(r * 256 + w * 64) * 8;
            GLOAD_LDS16(gp, lp);
        }
        __syncthreads();
        f16x8 af[8], bf[4];
        #pragma unroll
        for (int m = 0; m < 8; ++m) af[m] = *(const f16x8*)&As[m * 16 + lr][lk * 8];
        #pragma unroll
        for (int n = 0; n < 4; ++n) bf[n] = *(const f16x8*)&Bs[w * 64 + n * 16 + lr][lk * 8];
        #pragma unroll
        for (int m = 0; m < 8; ++m)
            #pragma unroll
            for (int n = 0; n < 4; ++n)
                acc[m][n] = __builtin_amdgcn_mfma_f32_16x16x32_f16(af[m], bf[n], acc[m][n], 0, 0, 0);
    }
    #pragma unroll
    for (int m = 0; m < 8; ++m) {
        #pragma unroll
        for (int j = 0; j < 4; ++j) {
            int row = mBase + m * 16 + lk * 4 + j;
            int srow = OUT_F32 ? scatterIdx[row] : row;
            #pragma unroll
            for (int n = 0; n < 4; ++n) {
                int col = nBase + w * 64 + n * 16 + lr;
                if constexpr (OUT_F32)
                    ((float*)Cout)[(size_t)srow * BNTOT + col] = acc[m][n][j] + bias[col];
                else
                    ((f16*)Cout)[(size_t)srow * BNTOT + col] = (f16)acc[m][n][j];
            }
        }
    }
}

// ---------------- segment-mean pooling of sorted q,k -> ql,kl (f32) + klh (f16) ----------------
__global__ __launch_bounds__(256) void pool_k(const f16* __restrict__ qkvh,
                                              const int* __restrict__ base, const int* __restrict__ counts,
                                              float* __restrict__ ql, float* __restrict__ kl,
                                              f16* __restrict__ klh) {
    int l = blockIdx.x, h = blockIdx.y;
    int t = threadIdx.x, d = t & 63, g = t >> 6;
    int b0 = base[l], cnt = counts[l];
    float sq = 0.f, sk = 0.f;
    for (int p = g; p < cnt; p += 4) {
        size_t ro = (size_t)(b0 + p) * QKVC + h * 64 + d;
        sq += (float)qkvh[ro];
        sk += (float)qkvh[ro + 512];
    }
    __shared__ float rq[4][64], rk[4][64];
    rq[g][d] = sq; rk[g][d] = sk;
    __syncthreads();
    if (t < 64) {
        float inv = 1.0f / (float)(cnt > 0 ? cnt : 1);
        float qv = (rq[0][t] + rq[1][t] + rq[2][t] + rq[3][t]) * inv;
        float kv = (rk[0][t] + rk[1][t] + rk[2][t] + rk[3][t]) * inv;
        ql[(h * 64 + l) * 64 + t] = qv;
        kl[(h * 64 + l) * 64 + t] = kv;
        klh[(h * 64 + l) * 64 + t] = (f16)kv;
    }
}

// ---------------- attn2 = softmax(ql@kl^T) rows; per-head row/col abs-sum maxes ----------------
__global__ __launch_bounds__(256) void attn2_k(const float* __restrict__ ql, const float* __restrict__ kl,
                                               float* __restrict__ a_out, float* __restrict__ mrow,
                                               float* __restrict__ mcol) {
    int h = blockIdx.x;
    __shared__ float qs[64][65], ks[64][65], a[64][65];
    __shared__ float red[64][4];
    __shared__ float rowv[64], colv[64];
    int t = threadIdx.x;
    for (int idx = t; idx < 4096; idx += 256) {
        int r = idx >> 6, c = idx & 63;
        qs[r][c] = ql[h * 4096 + idx];
        ks[r][c] = kl[h * 4096 + idx];
    }
    __syncthreads();
    int i = t >> 2, q4 = t & 3, j0 = q4 * 16;
    float o[16];
    #pragma unroll
    for (int jj = 0; jj < 16; ++jj) o[jj] = 0.f;
    for (int d = 0; d < 64; ++d) {
        float qv = qs[i][d];
        #pragma unroll
        for (int jj = 0; jj < 16; ++jj) o[jj] += qv * ks[j0 + jj][d];
    }
    float pmx = o[0];
    #pragma unroll
    for (int jj = 1; jj < 16; ++jj) pmx = fmaxf(pmx, o[jj]);
    red[i][q4] = pmx;
    __syncthreads();
    float rm = fmaxf(fmaxf(red[i][0], red[i][1]), fmaxf(red[i][2], red[i][3]));
    float psum = 0.f;
    #pragma unroll
    for (int jj = 0; jj < 16; ++jj) { o[jj] = expf(o[jj] - rm); psum += o[jj]; }
    __syncthreads();
    red[i][q4] = psum;
    __syncthreads();
    float rs = red[i][0] + red[i][1] + red[i][2] + red[i][3];
    float inv = 1.0f / rs;
    #pragma unroll
    for (int jj = 0; jj < 16; ++jj) { o[jj] *= inv; a[i][j0 + jj] = o[jj]; }
    __syncthreads();
    for (int idx = t; idx < 4096; idx += 256) a_out[h * 4096 + idx] = a[idx >> 6][idx & 63];
    float rsum = 0.f;
    #pragma unroll
    for (int jj = 0; jj < 16; ++jj) rsum += o[jj];
    __syncthreads();
    red[i][q4] = rsum;
    __syncthreads();
    if (q4 == 0) rowv[i] = red[i][0] + red[i][1] + red[i][2] + red[i][3];
    float csum = 0.f;
    #pragma unroll
    for (int jj = 0; jj < 16; ++jj) csum += a[j0 + jj][i];
    __syncthreads();
    red[i][q4] = csum;
    __syncthreads();
    if (q4 == 0) colv[i] = red[i][0] + red[i][1] + red[i][2] + red[i][3];
    __syncthreads();
    if (t == 0) {
        float mr = rowv[0], mc = colv[0];
        for (int j = 1; j < 64; ++j) { mr = fmaxf(mr, rowv[j]); mc = fmaxf(mc, colv[j]); }
        mrow[h] = mr; mcol[h] = mc;
    }
}

// 4x4-blocked 64x64 matmul helper (operands in LDS, stride 68)
__device__ __forceinline__ void mm_blk(const float (*X)[68], const float (*Y)[68],
                                       int i0, int j0, float o[4][4]) {
    #pragma unroll
    for (int ii = 0; ii < 4; ++ii)
        #pragma unroll
        for (int jj = 0; jj < 4; ++jj) o[ii][jj] = 0.f;
    for (int k = 0; k < 64; ++k) {
        float4 yv = *(const float4*)&Y[k][j0];
        float x0 = X[i0][k], x1 = X[i0 + 1][k], x2 = X[i0 + 2][k], x3 = X[i0 + 3][k];
        o[0][0] += x0 * yv.x; o[0][1] += x0 * yv.y; o[0][2] += x0 * yv.z; o[0][3] += x0 * yv.w;
        o[1][0] += x1 * yv.x; o[1][1] += x1 * yv.y; o[1][2] += x1 * yv.z; o[1][3] += x1 * yv.w;
        o[2][0] += x2 * yv.x; o[2][1] += x2 * yv.y; o[2][2] += x2 * yv.z; o[2][3] += x2 * yv.w;
        o[3][0] += x3 * yv.x; o[3][1] += x3 * yv.y; o[3][2] += x3 * yv.z; o[3][3] += x3 * yv.w;
    }
}

// ---------------- Newton-Schulz pinv (6 iters, f32, per head) ----------------
__global__ __launch_bounds__(256) void pinv_k(const float* __restrict__ a_g, const float* __restrict__ mrow,
                                              const float* __restrict__ mcol, float* __restrict__ z_g) {
    int h = blockIdx.x;
    __shared__ float a[64][68], z[64][68], C[64][68], D[64][68], E[64][68];
    int t = threadIdx.x;
    float mr = mrow[0], mc = mcol[0];
    #pragma unroll
    for (int k = 1; k < 8; ++k) { mr = fmaxf(mr, mrow[k]); mc = fmaxf(mc, mcol[k]); }
    float inv0 = 1.0f / (mr * mc);
    for (int idx = t; idx < 4096; idx += 256) {
        int r = idx >> 6, c = idx & 63;
        float av = a_g[h * 4096 + idx];
        a[r][c] = av;
        z[c][r] = av * inv0;
    }
    __syncthreads();
    int i0 = (t >> 4) * 4, j0 = (t & 15) * 4;
    float o[4][4];
    for (int it = 0; it < 6; ++it) {
        mm_blk(a, z, i0, j0, o);
        #pragma unroll
        for (int ii = 0; ii < 4; ++ii)
            #pragma unroll
            for (int jj = 0; jj < 4; ++jj) C[i0 + ii][j0 + jj] = o[ii][jj];
        __syncthreads();
        mm_blk(C, C, i0, j0, o);
        #pragma unroll
        for (int ii = 0; ii < 4; ++ii)
            #pragma unroll
            for (int jj = 0; jj < 4; ++jj) D[i0 + ii][j0 + jj] = 7.f * C[i0 + ii][j0 + jj] - o[ii][jj];
        __syncthreads();
        mm_blk(C, D, i0, j0, o);
        #pragma unroll
        for (int ii = 0; ii < 4; ++ii)
            #pragma unroll
            for (int jj = 0; jj < 4; ++jj) E[i0 + ii][j0 + jj] = 15.f * C[i0 + ii][j0 + jj] - o[ii][jj];
        __syncthreads();
        mm_blk(z, E, i0, j0, o);
        #pragma unroll
        for (int ii = 0; ii < 4; ++ii)
            #pragma unroll
            for (int jj = 0; jj < 4; ++jj) D[i0 + ii][j0 + jj] = 0.25f * (13.f * z[i0 + ii][j0 + jj] - o[ii][jj]);
        __syncthreads();
        #pragma unroll
        for (int ii = 0; ii < 4; ++ii)
            #pragma unroll
            for (int jj = 0; jj < 4; ++jj) z[i0 + ii][j0 + jj] = D[i0 + ii][j0 + jj];
        __syncthreads();
    }
    for (int idx = t; idx < 4096; idx += 256) z_g[h * 4096 + idx] = z[idx >> 6][idx & 63];
}

// ---------------- attn3 @ v: chunked online-softmax partials ----------------
__global__ __launch_bounds__(256) void attn3_k(const f16* __restrict__ qkvh, const float* __restrict__ ql,
                                               float* __restrict__ pm, float* __restrict__ ps,
                                               float* __restrict__ pacc) {
    int cx = blockIdx.x, h = blockIdx.y;
    __shared__ float qls[64][68];
    __shared__ float kts[64][68];
    __shared__ float vs[64][68];
    __shared__ float S[64][68];
    __shared__ float red[64][4];
    __shared__ float ml[64], sl[64];
    int t = threadIdx.x;
    for (int idx = t; idx < 4096; idx += 256) qls[idx >> 6][idx & 63] = ql[h * 4096 + idx];
    if (t < 64) { ml[t] = -1e30f; sl[t] = 0.f; }
    int i = t >> 2, q4 = t & 3, j0 = q4 * 16;
    float acc[16];
    #pragma unroll
    for (int jj = 0; jj < 16; ++jj) acc[jj] = 0.f;
    __syncthreads();
    for (int sub = 0; sub < 16; ++sub) {
        int n0 = cx * 1024 + sub * 64;
        for (int idx = t; idx < 4096; idx += 256) {
            int r = idx >> 6, c = idx & 63;
            size_t ro = (size_t)(n0 + r) * QKVC + 512 + h * 64 + c;
            kts[c][r] = (float)qkvh[ro];
            vs[r][c] = (float)qkvh[ro + 512];
        }
        __syncthreads();
        float o[16];
        #pragma unroll
        for (int jj = 0; jj < 16; ++jj) o[jj] = 0.f;
        for (int d = 0; d < 64; ++d) {
            float qv = qls[i][d];
            #pragma unroll
            for (int w = 0; w < 4; ++w) {
                float4 kv = *(const float4*)&kts[d][j0 + w * 4];
                o[w * 4 + 0] += qv * kv.x; o[w * 4 + 1] += qv * kv.y;
                o[w * 4 + 2] += qv * kv.z; o[w * 4 + 3] += qv * kv.w;
            }
        }
        float tm = o[0];
        #pragma unroll
        for (int jj = 1; jj < 16; ++jj) tm = fmaxf(tm, o[jj]);
        red[i][q4] = tm;
        __syncthreads();
        float rowm = fmaxf(fmaxf(red[i][0], red[i][1]), fmaxf(red[i][2], red[i][3]));
        float oldm = ml[i];
        float newm = fmaxf(oldm, rowm);
        float f = __expf(oldm - newm);
        float psum = 0.f;
        #pragma unroll
        for (int jj = 0; jj < 16; ++jj) { o[jj] = __expf(o[jj] - newm); psum += o[jj]; }
        #pragma unroll
        for (int w = 0; w < 4; ++w)
            *(float4*)&S[i][j0 + w * 4] = make_float4(o[w * 4], o[w * 4 + 1], o[w * 4 + 2], o[w * 4 + 3]);
        __syncthreads();
        red[i][q4] = psum;
        __syncthreads();
        float tsum = red[i][0] + red[i][1] + red[i][2] + red[i][3];
        if (q4 == 0) { sl[i] = sl[i] * f + tsum; ml[i] = newm; }
        #pragma unroll
        for (int jj = 0; jj < 16; ++jj) acc[jj] *= f;
        for (int k = 0; k < 64; ++k) {
            float pv = S[i][k];
            #pragma unroll
            for (int w = 0; w < 4; ++w) {
                float4 vv = *(const float4*)&vs[k][j0 + w * 4];
                acc[w * 4 + 0] += pv * vv.x; acc[w * 4 + 1] += pv * vv.y;
                acc[w * 4 + 2] += pv * vv.z; acc[w * 4 + 3] += pv * vv.w;
            }
        }
        __syncthreads();
    }
    if (q4 == 0) {
        pm[(h * NCHUNK + cx) * 64 + i] = ml[i];
        ps[(h * NCHUNK + cx) * 64 + i] = sl[i];
    }
    size_t po = ((size_t)(h * NCHUNK + cx) * 64 + i) * 64 + j0;
    #pragma unroll
    for (int w = 0; w < 4; ++w)
        *(float4*)&pacc[po + w * 4] = make_float4(acc[w * 4], acc[w * 4 + 1], acc[w * 4 + 2], acc[w * 4 + 3]);
}

// ---------------- merge attn3 partials -> T[h][l][d] ----------------
__global__ void attn3_merge_k(const float* __restrict__ pm, const float* __restrict__ ps,
                              const float* __restrict__ pacc, float* __restrict__ T) {
    int l = blockIdx.x, h = blockIdx.y, d = threadIdx.x;
    float m = -1e30f;
    for (int c = 0; c < NCHUNK; ++c) m = fmaxf(m, pm[(h * NCHUNK + c) * 64 + l]);
    float s = 0.f, a = 0.f;
    for (int c = 0; c < NCHUNK; ++c) {
        float wgt = __expf(pm[(h * NCHUNK + c) * 64 + l] - m);
        s += ps[(h * NCHUNK + c) * 64 + l] * wgt;
        a += pacc[((size_t)(h * NCHUNK + c) * 64 + l) * 64 + d] * wgt;
    }
    T[(h * 64 + l) * 64 + d] = a / s;
}

// ---------------- M = z @ T per head; emit M^T split into f16 hi+lo ----------------
__global__ __launch_bounds__(256) void zmatT_k(const float* __restrict__ z_g, const float* __restrict__ T,
                                               f16* __restrict__ MthHi, f16* __restrict__ MthLo) {
    int h = blockIdx.x;
    __shared__ float zs[64][68], Ts[64][68];
    int t = threadIdx.x;
    for (int idx = t; idx < 4096; idx += 256) {
        int r = idx >> 6, c = idx & 63;
        zs[r][c] = z_g[h * 4096 + idx];
        Ts[r][c] = T[h * 4096 + idx];
    }
    __syncthreads();
    int i0 = (t >> 4) * 4, j0 = (t & 15) * 4;   // i0 -> l, j0 -> d
    float o[4][4];
    mm_blk(zs, Ts, i0, j0, o);
    #pragma unroll
    for (int ii = 0; ii < 4; ++ii)
        #pragma unroll
        for (int jj = 0; jj < 4; ++jj) {
            float mv = o[ii][jj];
            f16 hiv = (f16)mv;
            f16 lov = (f16)(mv - (float)hiv);
            // transposed layout: [h][d][l]
            MthHi[h * 4096 + (j0 + jj) * 64 + (i0 + ii)] = hiv;
            MthLo[h * 4096 + (j0 + jj) * 64 + (i0 + ii)] = lov;
        }
}

// ---------------- depthwise conv over sorted v (streaming) -> resH (f16) ----------------
__global__ __launch_bounds__(256) void conv_k(const f16* __restrict__ qkvh,
                                              const float* __restrict__ resk, f16* __restrict__ resH) {
    int h = blockIdx.y;
    int p0 = blockIdx.x * 256;
    __shared__ f16 vt[288][72];
    int t = threadIdx.x;
    for (int id = t; id < 288 * 8; id += 256) {
        int rr = id >> 3, c = id & 7;
        int pg = p0 - 16 + rr;
        int4 v = {0, 0, 0, 0};
        if (pg >= 0 && pg < N_TOK)
            v = *(const int4*)&qkvh[(size_t)pg * QKVC + 1024 + h * 64 + c * 8];
        *(int4*)&vt[rr][c * 8] = v;
    }
    float wk[KSZ];
    #pragma unroll
    for (int k = 0; k < KSZ; ++k) wk[k] = resk[h * KSZ + k];
    __syncthreads();
    int d = t & 63, pg4 = t >> 6;
    float col[96];
    #pragma unroll
    for (int i2 = 0; i2 < 96; ++i2) col[i2] = (float)vt[pg4 * 64 + i2][d];
    #pragma unroll
    for (int pp = 0; pp < 64; ++pp) {
        float acc = 0.f;
        #pragma unroll
        for (int k = 0; k < KSZ; ++k) acc += wk[k] * col[pp + k];
        resH[(size_t)(p0 + pg4 * 64 + pp) * 512 + h * 64 + d] = (f16)acc;
    }
}

// ---------------- attn1 via MFMA: softmax(Q@kl^T) @ M + residual -> Yh ----------------
// block: 128 rows x 1 head, 4 waves (each 32 rows). S^T = mfma(kl, Q); P via LDS; O = mfma(P, Mt).
__global__ __launch_bounds__(256) void attn1_k(const f16* __restrict__ qkvh, const f16* __restrict__ klh,
                                               const f16* __restrict__ MthHi, const f16* __restrict__ MthLo,
                                               const f16* __restrict__ resH, f16* __restrict__ Yh) {
    const int h = blockIdx.y;
    const int p0 = blockIdx.x * 128;
    const int t = threadIdx.x;
    const int w = t >> 6, lane = t & 63;
    const int lr = lane & 15, hi = lane >> 4;
    __shared__ f16 Qs[128][72];
    __shared__ f16 Ks[64][72];
    __shared__ f16 Mhi[64][72];
    __shared__ f16 Mlo[64][72];
    __shared__ f16 Ps[128][72];   // P, then reused as Y tile

    // stage Q (128x64) + kl/Mhi/Mlo (64x64 each), all coalesced f16x8
    #pragma unroll
    for (int i = 0; i < 4; ++i) {
        int id = i * 256 + t, row = id >> 3, c8 = id & 7;
        *(f16x8*)&Qs[row][c8 * 8] = *(const f16x8*)&qkvh[(size_t)(p0 + row) * QKVC + h * 64 + c8 * 8];
    }
    #pragma unroll
    for (int i = 0; i < 2; ++i) {
        int id = i * 256 + t, row = id >> 3, c8 = id & 7;
        *(f16x8*)&Ks[row][c8 * 8]  = *(const f16x8*)&klh[h * 4096 + id * 8];
        *(f16x8*)&Mhi[row][c8 * 8] = *(const f16x8*)&MthHi[h * 4096 + id * 8];
        *(f16x8*)&Mlo[row][c8 * 8] = *(const f16x8*)&MthLo[h * 4096 + id * 8];
    }
    __syncthreads();

    // S^T[l][n] = sum_d kl[l][d] * Q[n][d]; wave w covers n in [w*32, w*32+32)
    f32x4 c[4][2];
    #pragma unroll
    for (int lf = 0; lf < 4; ++lf)
        #pragma unroll
        for (int nf = 0; nf < 2; ++nf) c[lf][nf] = (f32x4){0.f, 0.f, 0.f, 0.f};
    #pragma unroll
    for (int ks = 0; ks < 2; ++ks) {
        f16x8 af[4], bf[2];
        #pragma unroll
        for (int lf = 0; lf < 4; ++lf) af[lf] = *(const f16x8*)&Ks[lf * 16 + lr][ks * 32 + hi * 8];
        #pragma unroll
        for (int nf = 0; nf < 2; ++nf) bf[nf] = *(const f16x8*)&Qs[w * 32 + nf * 16 + lr][ks * 32 + hi * 8];
        #pragma unroll
        for (int lf = 0; lf < 4; ++lf)
            #pragma unroll
            for (int nf = 0; nf < 2; ++nf)
                c[lf][nf] = __builtin_amdgcn_mfma_f32_16x16x32_f16(af[lf], bf[nf], c[lf][nf], 0, 0, 0);
    }

    // softmax over l (per n column): 16 lane-local values + xor-16/32 reduce
    #pragma unroll
    for (int nf = 0; nf < 2; ++nf) {
        float m = -1e30f;
        #pragma unroll
        for (int lf = 0; lf < 4; ++lf)
            #pragma unroll
            for (int j = 0; j < 4; ++j) m = fmaxf(m, c[lf][nf][j]);
        m = fmaxf(m, __shfl_xor(m, 16));
        m = fmaxf(m, __shfl_xor(m, 32));
        float s = 0.f;
        #pragma unroll
        for (int lf = 0; lf < 4; ++lf)
            #pragma unroll
            for (int j = 0; j < 4; ++j) { float e = __expf(c[lf][nf][j] - m); c[lf][nf][j] = e; s += e; }
        s += __shfl_xor(s, 16);
        s += __shfl_xor(s, 32);
        float inv = 1.0f / s;
        #pragma unroll
        for (int lf = 0; lf < 4; ++lf) {
            f16x4 pk;
            #pragma unroll
            for (int j = 0; j < 4; ++j) pk[j] = (f16)(c[lf][nf][j] * inv);
            // P[n][l]: n = w*32+nf*16+lr, l = lf*16 + hi*4 + j
            *(f16x4*)&Ps[w * 32 + nf * 16 + lr][lf * 16 + hi * 4] = pk;
        }
    }
    // no barrier needed: each wave reads back only its own 32 rows (DS ops in-order per wave)

    // O[n][d] = sum_l P[n][l] * M[l][d], M = Mhi + Mlo
    f32x4 o[2][4];
    #pragma unroll
    for (int nf = 0; nf < 2; ++nf)
        #pragma unroll
        for (int df = 0; df < 4; ++df) o[nf][df] = (f32x4){0.f, 0.f, 0.f, 0.f};
    #pragma unroll
    for (int ks = 0; ks < 2; ++ks) {
        f16x8 pa[2], bh[4], bl[4];
        #pragma unroll
        for (int nf = 0; nf < 2; ++nf) pa[nf] = *(const f16x8*)&Ps[w * 32 + nf * 16 + lr][ks * 32 + hi * 8];
        #pragma unroll
        for (int df = 0; df < 4; ++df) {
            bh[df] = *(const f16x8*)&Mhi[df * 16 + lr][ks * 32 + hi * 8];
            bl[df] = *(const f16x8*)&Mlo[df * 16 + lr][ks * 32 + hi * 8];
        }
        #pragma unroll
        for (int nf = 0; nf < 2; ++nf)
            #pragma unroll
            for (int df = 0; df < 4; ++df) {
                o[nf][df] = __builtin_amdgcn_mfma_f32_16x16x32_f16(pa[nf], bh[df], o[nf][df], 0, 0, 0);
                o[nf][df] = __builtin_amdgcn_mfma_f32_16x16x32_f16(pa[nf], bl[df], o[nf][df], 0, 0, 0);
            }
    }

    // write O into Ps (reuse) as Y tile: row n, col d
    #pragma unroll
    for (int nf = 0; nf < 2; ++nf)
        #pragma unroll
        for (int df = 0; df < 4; ++df)
            #pragma unroll
            for (int j = 0; j < 4; ++j)
                Ps[w * 32 + nf * 16 + hi * 4 + j][df * 16 + lr] = (f16)(o[nf][df][j]);
    __syncthreads();

    // coalesced combine with residual and store
    #pragma unroll
    for (int i = 0; i < 4; ++i) {
        int id = i * 256 + t, row = id >> 3, c8 = id & 7;
        size_t go = (size_t)(p0 + row) * 512 + h * 64 + c8 * 8;
        f16x8 yv = *(const f16x8*)&Ps[row][c8 * 8];
        f16x8 rv = *(const f16x8*)&resH[go];
        f16x8 sv;
        #pragma unroll
        for (int e = 0; e < 8; ++e) sv[e] = (f16)((float)yv[e] + (float)rv[e]);
        *(f16x8*)&Yh[go] = sv;
    }
}

// ---------------- host launch ----------------
extern "C" void kernel_launch(void* const* d_in, const int* in_sizes, int n_in,
                              void* d_out, int out_size, void* d_ws, size_t ws_size,
                              hipStream_t stream) {
    const float* x    = (const float*)d_in[0];
    const float* Wqkv = (const float*)d_in[1];
    const float* Wout = (const float*)d_in[2];
    const float* bout = (const float*)d_in[3];
    const float* resk = (const float*)d_in[4];
    const int*   labels = (const int*)d_in[5];
    float* out = (float*)d_out;

    char* w = (char*)d_ws;
    size_t off = 0;
    auto alloc = [&](size_t bytes) {
        void* p = w + off;
        off += (bytes + 255) & ~(size_t)255;
        return p;
    };
    f16* xh     = (f16*)alloc((size_t)N_TOK * DIMC * 2);       // sorted
    f16* qkvh   = (f16*)alloc((size_t)N_TOK * QKVC * 2);       // sorted
    f16* WqkvT  = (f16*)alloc((size_t)QKVC * DIMC * 2);
    f16* WoutT  = (f16*)alloc((size_t)DIMC * DIMC * 2);
    f16* Yh     = (f16*)alloc((size_t)N_TOK * DIMC * 2);       // sorted
    int* counts = (int*)alloc(NL * 4);
    int* baseA  = (int*)alloc(NL * 4);
    int* indexA = (int*)alloc((size_t)N_TOK * 4);
    float* ql   = (float*)alloc((size_t)NH * 64 * 64 * 4);
    float* kl   = (float*)alloc((size_t)NH * 64 * 64 * 4);
    f16* klh    = (f16*)alloc((size_t)NH * 64 * 64 * 2);
    float* a2   = (float*)alloc((size_t)NH * 64 * 64 * 4);
    float* mrow = (float*)alloc(NH * 4);
    float* mcol = (float*)alloc(NH * 4);
    float* zb   = (float*)alloc((size_t)NH * 64 * 64 * 4);
    float* Tb   = (float*)alloc((size_t)NH * 64 * 64 * 4);
    f16* MthHi  = (f16*)alloc((size_t)NH * 64 * 64 * 2);
    f16* MthLo  = (f16*)alloc((size_t)NH * 64 * 64 * 2);
    float* pm   = (float*)alloc((size_t)NH * NCHUNK * 64 * 4);
    float* ps   = (float*)alloc((size_t)NH * NCHUNK * 64 * 4);
    float* pacc = (float*)alloc((size_t)NH * NCHUNK * 64 * 64 * 4);
    f16* resH = (f16*)d_out;  // reuse d_out (64MB) as f16 conv output (32MB); overwritten by final GEMM

    hipMemsetAsync(counts, 0, NL * 4, stream);

    // stable counting sort
    hist_k<<<N_TOK / 256, 256, 0, stream>>>(labels, counts);
    scan_k<<<1, 64, 0, stream>>>(counts, baseA);
    compact_k<<<NL, 256, 0, stream>>>(labels, baseA, indexA);
    // gather+convert x rows into sorted order
    gather_cvt_k<<<N_TOK / 2, 256, 0, stream>>>((const float4*)x, indexA, (f16x4*)xh);
    // weight transposes
    transpose_k<<<dim3(QKVC / 32, DIMC / 32), dim3(32, 8), 0, stream>>>(Wqkv, WqkvT, DIMC, QKVC);
    transpose_k<<<dim3(DIMC / 32, DIMC / 32), dim3(32, 8), 0, stream>>>(Wout, WoutT, DIMC, DIMC);
    // qkv = x_sorted @ Wqkv  (sorted domain)
    gemm_k512<QKVC, false><<<dim3(N_TOK / 128, QKVC / 256), 256, 0, stream>>>(xh, WqkvT, qkvh, nullptr, nullptr);
    // segment pooling (contiguous segments)
    pool_k<<<dim3(NL, NH), 256, 0, stream>>>(qkvh, baseA, counts, ql, kl, klh);
    // attn2 + pinv chain (f32)
    attn2_k<<<NH, 256, 0, stream>>>(ql, kl, a2, mrow, mcol);
    pinv_k<<<NH, 256, 0, stream>>>(a2, mrow, mcol, zb);
    // T = softmax(ql@k^T) @ v  (chunked online softmax)
    attn3_k<<<dim3(NCHUNK, NH), 256, 0, stream>>>(qkvh, ql, pm, ps, pacc);
    attn3_merge_k<<<dim3(NL, NH), 64, 0, stream>>>(pm, ps, pacc, Tb);
    // M^T (hi+lo f16) = (z @ T)^T
    zmatT_k<<<NH, 256, 0, stream>>>(zb, Tb, MthHi, MthLo);
    // depthwise conv over sorted v (streaming)
    conv_k<<<dim3(N_TOK / 256, NH), 256, 0, stream>>>(qkvh, resk, resH);
    // attn1 (MFMA) + combine -> Yh (sorted)
    attn1_k<<<dim3(N_TOK / 128, NH), 256, 0, stream>>>(qkvh, klh, MthHi, MthLo, resH, Yh);
    // final projection + bias, scatter rows back to original order
    gemm_k512<DIMC, true><<<dim3(N_TOK / 128, DIMC / 256), 256, 0, stream>>>(Yh, WoutT, out, bout, indexA);
}

// Round 4
// 462.014 us; speedup vs baseline: 2.4503x; 1.2493x over previous
//
#include <hip/hip_runtime.h>
#include <hip/hip_bf16.h>

// ---------------- problem constants ----------------
#define N_TOK 32768
#define DIMC  512
#define NH    8
#define DHD   64
#define NL    64
#define KSZ   33
#define QKVC  1536
#define NCHUNK 64   // attn3 chunks; 512 tokens per block

typedef _Float16 f16;
typedef _Float16 f16x8 __attribute__((ext_vector_type(8)));
typedef _Float16 f16x4 __attribute__((ext_vector_type(4)));
typedef float    f32x4 __attribute__((ext_vector_type(4)));

#define GLOAD_LDS16(gp, lp) \
    __builtin_amdgcn_global_load_lds((const __attribute__((address_space(1))) void*)(gp), \
                                     (__attribute__((address_space(3))) void*)(lp), 16, 0, 0)

// ---------------- transpose f32 (R x C) -> f16 (C x R) ----------------
__global__ void transpose_k(const float* __restrict__ W, f16* __restrict__ WT, int R, int C) {
    __shared__ float tile[32][33];
    int bx = blockIdx.x * 32, by = blockIdx.y * 32;
    int tx = threadIdx.x, ty = threadIdx.y;
    #pragma unroll
    for (int i = 0; i < 32; i += 8)
        tile[ty + i][tx] = W[(size_t)(by + ty + i) * C + bx + tx];
    __syncthreads();
    #pragma unroll
    for (int i = 0; i < 32; i += 8)
        WT[(size_t)(bx + ty + i) * R + by + tx] = (f16)tile[tx][ty + i];
}

// ---------------- label histogram ----------------
__global__ void hist_k(const int* __restrict__ labels, int* __restrict__ counts) {
    __shared__ int hloc[NL];
    int t = threadIdx.x;
    if (t < NL) hloc[t] = 0;
    __syncthreads();
    int i = blockIdx.x * 256 + t;
    atomicAdd(&hloc[labels[i]], 1);
    __syncthreads();
    if (t < NL) atomicAdd(&counts[t], hloc[t]);
}

// ---------------- exclusive prefix over 64 counts ----------------
__global__ void scan_k(const int* __restrict__ counts, int* __restrict__ base) {
    if (threadIdx.x == 0) {
        int s = 0;
        for (int l = 0; l < NL; ++l) { base[l] = s; s += counts[l]; }
    }
}

// ---------------- stable compaction: one block per label ----------------
__global__ __launch_bounds__(256) void compact_k(const int* __restrict__ labels,
                                                 const int* __restrict__ base,
                                                 int* __restrict__ indexArr) {
    const int l = blockIdx.x;
    __shared__ int wtot[4];
    __shared__ int s_run;
    int t = threadIdx.x, lane = t & 63, w = t >> 6;
    if (t == 0) s_run = base[l];
    __syncthreads();
    for (int c0 = 0; c0 < N_TOK; c0 += 256) {
        int ii = c0 + t;
        bool flag = (labels[ii] == l);
        unsigned long long mask = __ballot(flag);
        int before = __popcll(mask & ((1ull << lane) - 1ull));
        if (lane == 0) wtot[w] = __popcll(mask);
        __syncthreads();
        int off = 0;
        #pragma unroll
        for (int ww = 0; ww < 4; ++ww) off += (ww < w) ? wtot[ww] : 0;
        int tot = wtot[0] + wtot[1] + wtot[2] + wtot[3];
        int rb = s_run;
        if (flag) indexArr[rb + off + before] = ii;
        __syncthreads();
        if (t == 0) s_run = rb + tot;
    }
}

// ---------------- gather rows of x via index, convert to f16 (sorted domain) ----------------
__global__ __launch_bounds__(256) void gather_cvt_k(const float4* __restrict__ x4,
                                                    const int* __restrict__ indexArr,
                                                    f16x4* __restrict__ xh4) {
    int t = threadIdx.x;
    int row = blockIdx.x * 2 + (t >> 7);
    int c4 = t & 127;
    int j = indexArr[row];
    float4 v = x4[(size_t)j * 128 + c4];
    f16x4 o = { (f16)v.x, (f16)v.y, (f16)v.z, (f16)v.w };
    xh4[(size_t)row * 128 + c4] = o;
}

// ---------------- f16 MFMA GEMM: C[M x BNTOT] = A[M x 512] @ BT[BNTOT x 512]^T ----------------
template<int BNTOT, bool OUT_F32>
__global__ __launch_bounds__(256) void gemm_k512(const f16* __restrict__ A, const f16* __restrict__ BT,
                                                 void* __restrict__ Cout, const float* __restrict__ bias,
                                                 const int* __restrict__ scatterIdx) {
    constexpr int K = 512;
    __shared__ f16 As[128][32];
    __shared__ f16 Bs[256][32];
    const int t = threadIdx.x;
    const int mBase = blockIdx.x * 128;
    const int nBase = blockIdx.y * 256;
    const int w = t >> 6, lane = t & 63;
    const int lr = lane & 15, lk = lane >> 4;
    f32x4 acc[8][4];
    #pragma unroll
    for (int m = 0; m < 8; ++m)
        #pragma unroll
        for (int n = 0; n < 4; ++n) acc[m][n] = (f32x4){0.f, 0.f, 0.f, 0.f};

    for (int kt = 0; kt < K / 32; ++kt) {
        __syncthreads();
        #pragma unroll
        for (int r = 0; r < 2; ++r) {
            int c = r * 256 + w * 64 + lane;
            int row = c >> 2, slot = c & 3;
            const f16* gp = &A[(size_t)(mBase + row) * K + kt * 32 + slot * 8];
            f16* lp = &As[0][0] + (size_t)(r * 256 + w * 64) * 8;
            GLOAD_LDS16(gp, lp);
        }
        #pragma unroll
        for (int r = 0; r < 4; ++r) {
            int c = r * 256 + w * 64 + lane;
            int row = c >> 2, slot = c & 3;
            const f16* gp = &BT[(size_t)(nBase + row) * K + kt * 32 + slot * 8];
            f16* lp = &Bs[0][0] + (size_t)(r * 256 + w * 64) * 8;
            GLOAD_LDS16(gp, lp);
        }
        __syncthreads();
        f16x8 af[8], bf[4];
        #pragma unroll
        for (int m = 0; m < 8; ++m) af[m] = *(const f16x8*)&As[m * 16 + lr][lk * 8];
        #pragma unroll
        for (int n = 0; n < 4; ++n) bf[n] = *(const f16x8*)&Bs[w * 64 + n * 16 + lr][lk * 8];
        #pragma unroll
        for (int m = 0; m < 8; ++m)
            #pragma unroll
            for (int n = 0; n < 4; ++n)
                acc[m][n] = __builtin_amdgcn_mfma_f32_16x16x32_f16(af[m], bf[n], acc[m][n], 0, 0, 0);
    }
    #pragma unroll
    for (int m = 0; m < 8; ++m) {
        #pragma unroll
        for (int j = 0; j < 4; ++j) {
            int row = mBase + m * 16 + lk * 4 + j;
            int srow = OUT_F32 ? scatterIdx[row] : row;
            #pragma unroll
            for (int n = 0; n < 4; ++n) {
                int col = nBase + w * 64 + n * 16 + lr;
                if constexpr (OUT_F32)
                    ((float*)Cout)[(size_t)srow * BNTOT + col] = acc[m][n][j] + bias[col];
                else
                    ((f16*)Cout)[(size_t)srow * BNTOT + col] = (f16)acc[m][n][j];
            }
        }
    }
}

// ---------------- segment-mean pooling (vectorized): sorted q,k -> ql,kl (f32) + qlh,klh (f16) ----------------
__global__ __launch_bounds__(1024) void pool_k(const f16* __restrict__ qkvh,
                                               const int* __restrict__ base, const int* __restrict__ counts,
                                               float* __restrict__ ql, float* __restrict__ kl,
                                               f16* __restrict__ qlh, f16* __restrict__ klh) {
    int l = blockIdx.x;
    int t = threadIdx.x;
    int c = t & 127, rg = t >> 7;     // c: 16B chunk over q+k (2KB); rg: 0..7 row group
    int b0 = base[l], cnt = counts[l];
    f32x4 a0 = {0.f,0.f,0.f,0.f}, a1 = {0.f,0.f,0.f,0.f};
    for (int p = rg; p < cnt; p += 8) {
        f16x8 v = *(const f16x8*)&qkvh[(size_t)(b0 + p) * QKVC + c * 8];
        a0[0] += (float)v[0]; a0[1] += (float)v[1]; a0[2] += (float)v[2]; a0[3] += (float)v[3];
        a1[0] += (float)v[4]; a1[1] += (float)v[5]; a1[2] += (float)v[6]; a1[3] += (float)v[7];
    }
    __shared__ f32x4 red[8][128][2];
    red[rg][c][0] = a0; red[rg][c][1] = a1;
    __syncthreads();
    if (t < 128) {
        float inv = 1.0f / (float)(cnt > 0 ? cnt : 1);
        f32x4 s0 = {0.f,0.f,0.f,0.f}, s1 = {0.f,0.f,0.f,0.f};
        #pragma unroll
        for (int g = 0; g < 8; ++g) { s0 += red[g][t][0]; s1 += red[g][t][1]; }
        s0 *= inv; s1 *= inv;
        int h = (t & 63) >> 3, d0 = (t & 7) * 8;
        size_t o = ((size_t)(h * 64 + l)) * 64 + d0;
        f16x8 hv;
        #pragma unroll
        for (int e = 0; e < 4; ++e) { hv[e] = (f16)s0[e]; hv[4 + e] = (f16)s1[e]; }
        if (t < 64) {
            *(f32x4*)&ql[o] = s0; *(f32x4*)&ql[o + 4] = s1;
            *(f16x8*)&qlh[o] = hv;
        } else {
            *(f32x4*)&kl[o] = s0; *(f32x4*)&kl[o + 4] = s1;
            *(f16x8*)&klh[o] = hv;
        }
    }
}

// ---------------- attn2 = softmax(ql@kl^T) rows; per-head row/col abs-sum maxes ----------------
__global__ __launch_bounds__(256) void attn2_k(const float* __restrict__ ql, const float* __restrict__ kl,
                                               float* __restrict__ a_out, float* __restrict__ mrow,
                                               float* __restrict__ mcol) {
    int h = blockIdx.x;
    __shared__ float qs[64][65], ks[64][65], a[64][65];
    __shared__ float red[64][4];
    __shared__ float rowv[64], colv[64];
    int t = threadIdx.x;
    for (int idx = t; idx < 4096; idx += 256) {
        int r = idx >> 6, c = idx & 63;
        qs[r][c] = ql[h * 4096 + idx];
        ks[r][c] = kl[h * 4096 + idx];
    }
    __syncthreads();
    int i = t >> 2, q4 = t & 3, j0 = q4 * 16;
    float o[16];
    #pragma unroll
    for (int jj = 0; jj < 16; ++jj) o[jj] = 0.f;
    for (int d = 0; d < 64; ++d) {
        float qv = qs[i][d];
        #pragma unroll
        for (int jj = 0; jj < 16; ++jj) o[jj] += qv * ks[j0 + jj][d];
    }
    float pmx = o[0];
    #pragma unroll
    for (int jj = 1; jj < 16; ++jj) pmx = fmaxf(pmx, o[jj]);
    red[i][q4] = pmx;
    __syncthreads();
    float rm = fmaxf(fmaxf(red[i][0], red[i][1]), fmaxf(red[i][2], red[i][3]));
    float psum = 0.f;
    #pragma unroll
    for (int jj = 0; jj < 16; ++jj) { o[jj] = expf(o[jj] - rm); psum += o[jj]; }
    __syncthreads();
    red[i][q4] = psum;
    __syncthreads();
    float rs = red[i][0] + red[i][1] + red[i][2] + red[i][3];
    float inv = 1.0f / rs;
    #pragma unroll
    for (int jj = 0; jj < 16; ++jj) { o[jj] *= inv; a[i][j0 + jj] = o[jj]; }
    __syncthreads();
    for (int idx = t; idx < 4096; idx += 256) a_out[h * 4096 + idx] = a[idx >> 6][idx & 63];
    float rsum = 0.f;
    #pragma unroll
    for (int jj = 0; jj < 16; ++jj) rsum += o[jj];
    __syncthreads();
    red[i][q4] = rsum;
    __syncthreads();
    if (q4 == 0) rowv[i] = red[i][0] + red[i][1] + red[i][2] + red[i][3];
    float csum = 0.f;
    #pragma unroll
    for (int jj = 0; jj < 16; ++jj) csum += a[j0 + jj][i];
    __syncthreads();
    red[i][q4] = csum;
    __syncthreads();
    if (q4 == 0) colv[i] = red[i][0] + red[i][1] + red[i][2] + red[i][3];
    __syncthreads();
    if (t == 0) {
        float mr = rowv[0], mc = colv[0];
        for (int j = 1; j < 64; ++j) { mr = fmaxf(mr, rowv[j]); mc = fmaxf(mc, colv[j]); }
        mrow[h] = mr; mcol[h] = mc;
    }
}

// 4x4-blocked 64x64 matmul helper (operands in LDS, stride 68)
__device__ __forceinline__ void mm_blk(const float (*X)[68], const float (*Y)[68],
                                       int i0, int j0, float o[4][4]) {
    #pragma unroll
    for (int ii = 0; ii < 4; ++ii)
        #pragma unroll
        for (int jj = 0; jj < 4; ++jj) o[ii][jj] = 0.f;
    for (int k = 0; k < 64; ++k) {
        float4 yv = *(const float4*)&Y[k][j0];
        float x0 = X[i0][k], x1 = X[i0 + 1][k], x2 = X[i0 + 2][k], x3 = X[i0 + 3][k];
        o[0][0] += x0 * yv.x; o[0][1] += x0 * yv.y; o[0][2] += x0 * yv.z; o[0][3] += x0 * yv.w;
        o[1][0] += x1 * yv.x; o[1][1] += x1 * yv.y; o[1][2] += x1 * yv.z; o[1][3] += x1 * yv.w;
        o[2][0] += x2 * yv.x; o[2][1] += x2 * yv.y; o[2][2] += x2 * yv.z; o[2][3] += x2 * yv.w;
        o[3][0] += x3 * yv.x; o[3][1] += x3 * yv.y; o[3][2] += x3 * yv.z; o[3][3] += x3 * yv.w;
    }
}

// ---------------- Newton-Schulz pinv (6 iters, f32, per head) ----------------
__global__ __launch_bounds__(256) void pinv_k(const float* __restrict__ a_g, const float* __restrict__ mrow,
                                              const float* __restrict__ mcol, float* __restrict__ z_g) {
    int h = blockIdx.x;
    __shared__ float a[64][68], z[64][68], C[64][68], D[64][68], E[64][68];
    int t = threadIdx.x;
    float mr = mrow[0], mc = mcol[0];
    #pragma unroll
    for (int k = 1; k < 8; ++k) { mr = fmaxf(mr, mrow[k]); mc = fmaxf(mc, mcol[k]); }
    float inv0 = 1.0f / (mr * mc);
    for (int idx = t; idx < 4096; idx += 256) {
        int r = idx >> 6, c = idx & 63;
        float av = a_g[h * 4096 + idx];
        a[r][c] = av;
        z[c][r] = av * inv0;
    }
    __syncthreads();
    int i0 = (t >> 4) * 4, j0 = (t & 15) * 4;
    float o[4][4];
    for (int it = 0; it < 6; ++it) {
        mm_blk(a, z, i0, j0, o);
        #pragma unroll
        for (int ii = 0; ii < 4; ++ii)
            #pragma unroll
            for (int jj = 0; jj < 4; ++jj) C[i0 + ii][j0 + jj] = o[ii][jj];
        __syncthreads();
        mm_blk(C, C, i0, j0, o);
        #pragma unroll
        for (int ii = 0; ii < 4; ++ii)
            #pragma unroll
            for (int jj = 0; jj < 4; ++jj) D[i0 + ii][j0 + jj] = 7.f * C[i0 + ii][j0 + jj] - o[ii][jj];
        __syncthreads();
        mm_blk(C, D, i0, j0, o);
        #pragma unroll
        for (int ii = 0; ii < 4; ++ii)
            #pragma unroll
            for (int jj = 0; jj < 4; ++jj) E[i0 + ii][j0 + jj] = 15.f * C[i0 + ii][j0 + jj] - o[ii][jj];
        __syncthreads();
        mm_blk(z, E, i0, j0, o);
        #pragma unroll
        for (int ii = 0; ii < 4; ++ii)
            #pragma unroll
            for (int jj = 0; jj < 4; ++jj) D[i0 + ii][j0 + jj] = 0.25f * (13.f * z[i0 + ii][j0 + jj] - o[ii][jj]);
        __syncthreads();
        #pragma unroll
        for (int ii = 0; ii < 4; ++ii)
            #pragma unroll
            for (int jj = 0; jj < 4; ++jj) z[i0 + ii][j0 + jj] = D[i0 + ii][j0 + jj];
        __syncthreads();
    }
    for (int idx = t; idx < 4096; idx += 256) z_g[h * 4096 + idx] = z[idx >> 6][idx & 63];
}

// ---------------- attn3 @ v via MFMA: flash-style online softmax, per-block partials ----------------
// block = (chunk cx of 512 tokens, head h); 4 waves. Wave w owns l-cols [w*16,w*16+16) for softmax
// state, and d-cols [w*16,w*16+16) of the T accumulator. 8 subtiles of 64 tokens.
__global__ __launch_bounds__(256) void attn3_k(const f16* __restrict__ qkvh, const f16* __restrict__ qlh,
                                               float* __restrict__ pm, float* __restrict__ ps,
                                               float* __restrict__ pacc) {
    const int cx = blockIdx.x, h = blockIdx.y;
    const int t = threadIdx.x;
    const int w = t >> 6, lane = t & 63;
    const int lr = lane & 15, hi = lane >> 4;
    __shared__ f16 Qls[64 * 64];   // ql rows [l][d], chunk-swizzled
    __shared__ f16 Ks[64 * 64];    // K subtile rows [n][d], chunk-swizzled
    __shared__ f16 vT[64 * 72];    // [d][n], pad 72
    __shared__ f16 Ps[64 * 72];    // [l][n], pad 72
    __shared__ float fsh[64];

    // stage ql once (swizzled source chunks -> linear LDS)
    #pragma unroll
    for (int pss = 0; pss < 2; ++pss) {
        int q = pss * 256 + t;
        int r = q >> 3, cs = (q & 7) ^ (r & 7);
        GLOAD_LDS16(&qlh[(size_t)h * 4096 + r * 64 + cs * 8], &Qls[(size_t)(pss * 256 + w * 64) * 8]);
    }
    float m_reg = -1e30f, s_reg = 0.f;
    f32x4 accT[4];
    #pragma unroll
    for (int lf = 0; lf < 4; ++lf) accT[lf] = (f32x4){0.f, 0.f, 0.f, 0.f};

    const int vk8 = t & 7, vnn = t >> 3;   // v staging: chunk, row-in-32

    for (int sub = 0; sub < 8; ++sub) {
        const int n0 = cx * 512 + sub * 64;
        __syncthreads();   // protect Ks/vT/Ps from prior readers; drains Qls gload on sub=0
        // stage K (global_load_lds, swizzled source)
        #pragma unroll
        for (int pss = 0; pss < 2; ++pss) {
            int q = pss * 256 + t;
            int r = q >> 3, cs = (q & 7) ^ (r & 7);
            GLOAD_LDS16(&qkvh[(size_t)(n0 + r) * QKVC + 512 + h * 64 + cs * 8],
                        &Ks[(size_t)(pss * 256 + w * 64) * 8]);
        }
        // stage v transposed (rotated write order for bank spread)
        #pragma unroll
        for (int p2 = 0; p2 < 2; ++p2) {
            int n = vnn + 32 * p2;
            f16x8 rv = *(const f16x8*)&qkvh[(size_t)(n0 + n) * QKVC + 1024 + h * 64 + vk8 * 8];
            #pragma unroll
            for (int i = 0; i < 8; ++i) {
                int e = i ^ vk8;
                vT[(vk8 * 8 + e) * 72 + n] = rv[e];
            }
        }
        __syncthreads();
        // S^T = K @ ql^T : rows n (64), cols l (wave's 16)
        f32x4 c[4];
        #pragma unroll
        for (int kf = 0; kf < 4; ++kf) c[kf] = (f32x4){0.f, 0.f, 0.f, 0.f};
        const int lq = w * 16 + lr;
        #pragma unroll
        for (int ks = 0; ks < 2; ++ks) {
            f16x8 bf = *(const f16x8*)&Qls[lq * 64 + (((ks * 4 + hi) ^ (lq & 7)) * 8)];
            #pragma unroll
            for (int kf = 0; kf < 4; ++kf) {
                int rn = kf * 16 + lr;
                f16x8 af = *(const f16x8*)&Ks[rn * 64 + (((ks * 4 + hi) ^ (rn & 7)) * 8)];
                c[kf] = __builtin_amdgcn_mfma_f32_16x16x32_f16(af, bf, c[kf], 0, 0, 0);
            }
        }
        // online softmax over n for col l = lq
        float tmax = -1e30f;
        #pragma unroll
        for (int kf = 0; kf < 4; ++kf)
            #pragma unroll
            for (int j = 0; j < 4; ++j) tmax = fmaxf(tmax, c[kf][j]);
        tmax = fmaxf(tmax, __shfl_xor(tmax, 16));
        tmax = fmaxf(tmax, __shfl_xor(tmax, 32));
        float newm = fmaxf(m_reg, tmax);
        float fct = __expf(m_reg - newm);
        float psum = 0.f;
        #pragma unroll
        for (int kf = 0; kf < 4; ++kf) {
            f16x4 pk;
            #pragma unroll
            for (int j = 0; j < 4; ++j) {
                float e = __expf(c[kf][j] - newm);
                psum += e;
                pk[j] = (f16)e;
            }
            *(f16x4*)&Ps[lq * 72 + kf * 16 + hi * 4] = pk;
        }
        psum += __shfl_xor(psum, 16);
        psum += __shfl_xor(psum, 32);
        s_reg = s_reg * fct + psum;
        m_reg = newm;
        if (hi == 0) fsh[lq] = fct;
        __syncthreads();
        // rescale T accumulator by per-l factors
        #pragma unroll
        for (int lf = 0; lf < 4; ++lf) {
            f32x4 fr = *(const f32x4*)&fsh[lf * 16 + hi * 4];
            accT[lf] *= fr;
        }
        // T += P @ v : af = Ps rows l, bf = vT rows d (wave's 16 d-cols)
        #pragma unroll
        for (int ks = 0; ks < 2; ++ks) {
            f16x8 bf = *(const f16x8*)&vT[(w * 16 + lr) * 72 + ks * 32 + hi * 8];
            #pragma unroll
            for (int lf = 0; lf < 4; ++lf) {
                f16x8 af = *(const f16x8*)&Ps[(lf * 16 + lr) * 72 + ks * 32 + hi * 8];
                accT[lf] = __builtin_amdgcn_mfma_f32_16x16x32_f16(af, bf, accT[lf], 0, 0, 0);
            }
        }
    }
    // write partials
    int part = h * NCHUNK + cx;
    if (hi == 0) {
        pm[part * 64 + w * 16 + lr] = m_reg;
        ps[part * 64 + w * 16 + lr] = s_reg;
    }
    #pragma unroll
    for (int lf = 0; lf < 4; ++lf)
        #pragma unroll
        for (int j = 0; j < 4; ++j)
            pacc[((size_t)part * 64 + (lf * 16 + hi * 4 + j)) * 64 + (w * 16 + lr)] = accT[lf][j];
}

// ---------------- merge attn3 partials -> T[h][l][d] ----------------
__global__ void attn3_merge_k(const float* __restrict__ pm, const float* __restrict__ ps,
                              const float* __restrict__ pacc, float* __restrict__ T) {
    int l = blockIdx.x, h = blockIdx.y, d = threadIdx.x;
    float m = -1e30f;
    for (int c = 0; c < NCHUNK; ++c) m = fmaxf(m, pm[(h * NCHUNK + c) * 64 + l]);
    float s = 0.f, a = 0.f;
    for (int c = 0; c < NCHUNK; ++c) {
        float wgt = __expf(pm[(h * NCHUNK + c) * 64 + l] - m);
        s += ps[(h * NCHUNK + c) * 64 + l] * wgt;
        a += pacc[((size_t)(h * NCHUNK + c) * 64 + l) * 64 + d] * wgt;
    }
    T[(h * 64 + l) * 64 + d] = a / s;
}

// ---------------- M = z @ T per head; emit M^T split into f16 hi+lo ----------------
__global__ __launch_bounds__(256) void zmatT_k(const float* __restrict__ z_g, const float* __restrict__ T,
                                               f16* __restrict__ MthHi, f16* __restrict__ MthLo) {
    int h = blockIdx.x;
    __shared__ float zs[64][68], Ts[64][68];
    int t = threadIdx.x;
    for (int idx = t; idx < 4096; idx += 256) {
        int r = idx >> 6, c = idx & 63;
        zs[r][c] = z_g[h * 4096 + idx];
        Ts[r][c] = T[h * 4096 + idx];
    }
    __syncthreads();
    int i0 = (t >> 4) * 4, j0 = (t & 15) * 4;   // i0 -> l, j0 -> d
    float o[4][4];
    mm_blk(zs, Ts, i0, j0, o);
    #pragma unroll
    for (int ii = 0; ii < 4; ++ii)
        #pragma unroll
        for (int jj = 0; jj < 4; ++jj) {
            float mv = o[ii][jj];
            f16 hiv = (f16)mv;
            f16 lov = (f16)(mv - (float)hiv);
            MthHi[h * 4096 + (j0 + jj) * 64 + (i0 + ii)] = hiv;
            MthLo[h * 4096 + (j0 + jj) * 64 + (i0 + ii)] = lov;
        }
}

// ---------------- depthwise conv over sorted v (streaming) -> resH (f16) ----------------
__global__ __launch_bounds__(256) void conv_k(const f16* __restrict__ qkvh,
                                              const float* __restrict__ resk, f16* __restrict__ resH) {
    int h = blockIdx.y;
    int p0 = blockIdx.x * 256;
    __shared__ f16 vt[288][72];
    int t = threadIdx.x;
    for (int id = t; id < 288 * 8; id += 256) {
        int rr = id >> 3, c = id & 7;
        int pg = p0 - 16 + rr;
        int4 v = {0, 0, 0, 0};
        if (pg >= 0 && pg < N_TOK)
            v = *(const int4*)&qkvh[(size_t)pg * QKVC + 1024 + h * 64 + c * 8];
        *(int4*)&vt[rr][c * 8] = v;
    }
    float wk[KSZ];
    #pragma unroll
    for (int k = 0; k < KSZ; ++k) wk[k] = resk[h * KSZ + k];
    __syncthreads();
    int d = t & 63, pg4 = t >> 6;
    float col[96];
    #pragma unroll
    for (int i2 = 0; i2 < 96; ++i2) col[i2] = (float)vt[pg4 * 64 + i2][d];
    #pragma unroll
    for (int pp = 0; pp < 64; ++pp) {
        float acc = 0.f;
        #pragma unroll
        for (int k = 0; k < KSZ; ++k) acc += wk[k] * col[pp + k];
        resH[(size_t)(p0 + pg4 * 64 + pp) * 512 + h * 64 + d] = (f16)acc;
    }
}

// ---------------- attn1 via MFMA: softmax(Q@kl^T) @ M + residual -> Yh ----------------
__global__ __launch_bounds__(256) void attn1_k(const f16* __restrict__ qkvh, const f16* __restrict__ klh,
                                               const f16* __restrict__ MthHi, const f16* __restrict__ MthLo,
                                               const f16* __restrict__ resH, f16* __restrict__ Yh) {
    const int h = blockIdx.y;
    const int p0 = blockIdx.x * 128;
    const int t = threadIdx.x;
    const int w = t >> 6, lane = t & 63;
    const int lr = lane & 15, hi = lane >> 4;
    __shared__ f16 Qs[128][72];
    __shared__ f16 Ks[64][72];
    __shared__ f16 Mhi[64][72];
    __shared__ f16 Mlo[64][72];
    __shared__ f16 Ps[128][72];

    #pragma unroll
    for (int i = 0; i < 4; ++i) {
        int id = i * 256 + t, row = id >> 3, c8 = id & 7;
        *(f16x8*)&Qs[row][c8 * 8] = *(const f16x8*)&qkvh[(size_t)(p0 + row) * QKVC + h * 64 + c8 * 8];
    }
    #pragma unroll
    for (int i = 0; i < 2; ++i) {
        int id = i * 256 + t, row = id >> 3, c8 = id & 7;
        *(f16x8*)&Ks[row][c8 * 8]  = *(const f16x8*)&klh[h * 4096 + id * 8];
        *(f16x8*)&Mhi[row][c8 * 8] = *(const f16x8*)&MthHi[h * 4096 + id * 8];
        *(f16x8*)&Mlo[row][c8 * 8] = *(const f16x8*)&MthLo[h * 4096 + id * 8];
    }
    __syncthreads();

    f32x4 c[4][2];
    #pragma unroll
    for (int lf = 0; lf < 4; ++lf)
        #pragma unroll
        for (int nf = 0; nf < 2; ++nf) c[lf][nf] = (f32x4){0.f, 0.f, 0.f, 0.f};
    #pragma unroll
    for (int ks = 0; ks < 2; ++ks) {
        f16x8 af[4], bf[2];
        #pragma unroll
        for (int lf = 0; lf < 4; ++lf) af[lf] = *(const f16x8*)&Ks[lf * 16 + lr][ks * 32 + hi * 8];
        #pragma unroll
        for (int nf = 0; nf < 2; ++nf) bf[nf] = *(const f16x8*)&Qs[w * 32 + nf * 16 + lr][ks * 32 + hi * 8];
        #pragma unroll
        for (int lf = 0; lf < 4; ++lf)
            #pragma unroll
            for (int nf = 0; nf < 2; ++nf)
                c[lf][nf] = __builtin_amdgcn_mfma_f32_16x16x32_f16(af[lf], bf[nf], c[lf][nf], 0, 0, 0);
    }

    #pragma unroll
    for (int nf = 0; nf < 2; ++nf) {
        float m = -1e30f;
        #pragma unroll
        for (int lf = 0; lf < 4; ++lf)
            #pragma unroll
            for (int j = 0; j < 4; ++j) m = fmaxf(m, c[lf][nf][j]);
        m = fmaxf(m, __shfl_xor(m, 16));
        m = fmaxf(m, __shfl_xor(m, 32));
        float s = 0.f;
        #pragma unroll
        for (int lf = 0; lf < 4; ++lf)
            #pragma unroll
            for (int j = 0; j < 4; ++j) { float e = __expf(c[lf][nf][j] - m); c[lf][nf][j] = e; s += e; }
        s += __shfl_xor(s, 16);
        s += __shfl_xor(s, 32);
        float inv = 1.0f / s;
        #pragma unroll
        for (int lf = 0; lf < 4; ++lf) {
            f16x4 pk;
            #pragma unroll
            for (int j = 0; j < 4; ++j) pk[j] = (f16)(c[lf][nf][j] * inv);
            *(f16x4*)&Ps[w * 32 + nf * 16 + lr][lf * 16 + hi * 4] = pk;
        }
    }

    f32x4 o[2][4];
    #pragma unroll
    for (int nf = 0; nf < 2; ++nf)
        #pragma unroll
        for (int df = 0; df < 4; ++df) o[nf][df] = (f32x4){0.f, 0.f, 0.f, 0.f};
    #pragma unroll
    for (int ks = 0; ks < 2; ++ks) {
        f16x8 pa[2], bh[4], bl[4];
        #pragma unroll
        for (int nf = 0; nf < 2; ++nf) pa[nf] = *(const f16x8*)&Ps[w * 32 + nf * 16 + lr][ks * 32 + hi * 8];
        #pragma unroll
        for (int df = 0; df < 4; ++df) {
            bh[df] = *(const f16x8*)&Mhi[df * 16 + lr][ks * 32 + hi * 8];
            bl[df] = *(const f16x8*)&Mlo[df * 16 + lr][ks * 32 + hi * 8];
        }
        #pragma unroll
        for (int nf = 0; nf < 2; ++nf)
            #pragma unroll
            for (int df = 0; df < 4; ++df) {
                o[nf][df] = __builtin_amdgcn_mfma_f32_16x16x32_f16(pa[nf], bh[df], o[nf][df], 0, 0, 0);
                o[nf][df] = __builtin_amdgcn_mfma_f32_16x16x32_f16(pa[nf], bl[df], o[nf][df], 0, 0, 0);
            }
    }

    #pragma unroll
    for (int nf = 0; nf < 2; ++nf)
        #pragma unroll
        for (int df = 0; df < 4; ++df)
            #pragma unroll
            for (int j = 0; j < 4; ++j)
                Ps[w * 32 + nf * 16 + hi * 4 + j][df * 16 + lr] = (f16)(o[nf][df][j]);
    __syncthreads();

    #pragma unroll
    for (int i = 0; i < 4; ++i) {
        int id = i * 256 + t, row = id >> 3, c8 = id & 7;
        size_t go = (size_t)(p0 + row) * 512 + h * 64 + c8 * 8;
        f16x8 yv = *(const f16x8*)&Ps[row][c8 * 8];
        f16x8 rv = *(const f16x8*)&resH[go];
        f16x8 sv;
        #pragma unroll
        for (int e = 0; e < 8; ++e) sv[e] = (f16)((float)yv[e] + (float)rv[e]);
        *(f16x8*)&Yh[go] = sv;
    }
}

// ---------------- host launch ----------------
extern "C" void kernel_launch(void* const* d_in, const int* in_sizes, int n_in,
                              void* d_out, int out_size, void* d_ws, size_t ws_size,
                              hipStream_t stream) {
    const float* x    = (const float*)d_in[0];
    const float* Wqkv = (const float*)d_in[1];
    const float* Wout = (const float*)d_in[2];
    const float* bout = (const float*)d_in[3];
    const float* resk = (const float*)d_in[4];
    const int*   labels = (const int*)d_in[5];
    float* out = (float*)d_out;

    char* w = (char*)d_ws;
    size_t off = 0;
    auto alloc = [&](size_t bytes) {
        void* p = w + off;
        off += (bytes + 255) & ~(size_t)255;
        return p;
    };
    f16* xh     = (f16*)alloc((size_t)N_TOK * DIMC * 2);       // sorted
    f16* qkvh   = (f16*)alloc((size_t)N_TOK * QKVC * 2);       // sorted
    f16* WqkvT  = (f16*)alloc((size_t)QKVC * DIMC * 2);
    f16* WoutT  = (f16*)alloc((size_t)DIMC * DIMC * 2);
    f16* Yh     = (f16*)alloc((size_t)N_TOK * DIMC * 2);       // sorted
    int* counts = (int*)alloc(NL * 4);
    int* baseA  = (int*)alloc(NL * 4);
    int* indexA = (int*)alloc((size_t)N_TOK * 4);
    float* ql   = (float*)alloc((size_t)NH * 64 * 64 * 4);
    float* kl   = (float*)alloc((size_t)NH * 64 * 64 * 4);
    f16* qlh    = (f16*)alloc((size_t)NH * 64 * 64 * 2);
    f16* klh    = (f16*)alloc((size_t)NH * 64 * 64 * 2);
    float* a2   = (float*)alloc((size_t)NH * 64 * 64 * 4);
    float* mrow = (float*)alloc(NH * 4);
    float* mcol = (float*)alloc(NH * 4);
    float* zb   = (float*)alloc((size_t)NH * 64 * 64 * 4);
    float* Tb   = (float*)alloc((size_t)NH * 64 * 64 * 4);
    f16* MthHi  = (f16*)alloc((size_t)NH * 64 * 64 * 2);
    f16* MthLo  = (f16*)alloc((size_t)NH * 64 * 64 * 2);
    float* pm   = (float*)alloc((size_t)NH * NCHUNK * 64 * 4);
    float* ps   = (float*)alloc((size_t)NH * NCHUNK * 64 * 4);
    float* pacc = (float*)alloc((size_t)NH * NCHUNK * 64 * 64 * 4);   // 8 MiB
    f16* resH = (f16*)d_out;  // reuse d_out (64MB) as f16 conv output (32MB); overwritten by final GEMM

    hipMemsetAsync(counts, 0, NL * 4, stream);

    // stable counting sort
    hist_k<<<N_TOK / 256, 256, 0, stream>>>(labels, counts);
    scan_k<<<1, 64, 0, stream>>>(counts, baseA);
    compact_k<<<NL, 256, 0, stream>>>(labels, baseA, indexA);
    // gather+convert x rows into sorted order
    gather_cvt_k<<<N_TOK / 2, 256, 0, stream>>>((const float4*)x, indexA, (f16x4*)xh);
    // weight transposes
    transpose_k<<<dim3(QKVC / 32, DIMC / 32), dim3(32, 8), 0, stream>>>(Wqkv, WqkvT, DIMC, QKVC);
    transpose_k<<<dim3(DIMC / 32, DIMC / 32), dim3(32, 8), 0, stream>>>(Wout, WoutT, DIMC, DIMC);
    // qkv = x_sorted @ Wqkv  (sorted domain)
    gemm_k512<QKVC, false><<<dim3(N_TOK / 128, QKVC / 256), 256, 0, stream>>>(xh, WqkvT, qkvh, nullptr, nullptr);
    // segment pooling (vectorized)
    pool_k<<<NL, 1024, 0, stream>>>(qkvh, baseA, counts, ql, kl, qlh, klh);
    // attn2 + pinv chain (f32)
    attn2_k<<<NH, 256, 0, stream>>>(ql, kl, a2, mrow, mcol);
    pinv_k<<<NH, 256, 0, stream>>>(a2, mrow, mcol, zb);
    // T = softmax(ql@k^T) @ v  (MFMA flash-style)
    attn3_k<<<dim3(NCHUNK, NH), 256, 0, stream>>>(qkvh, qlh, pm, ps, pacc);
    attn3_merge_k<<<dim3(NL, NH), 64, 0, stream>>>(pm, ps, pacc, Tb);
    // M^T (hi+lo f16) = (z @ T)^T
    zmatT_k<<<NH, 256, 0, stream>>>(zb, Tb, MthHi, MthLo);
    // depthwise conv over sorted v (streaming)
    conv_k<<<dim3(N_TOK / 256, NH), 256, 0, stream>>>(qkvh, resk, resH);
    // attn1 (MFMA) + combine -> Yh (sorted)
    attn1_k<<<dim3(N_TOK / 128, NH), 256, 0, stream>>>(qkvh, klh, MthHi, MthLo, resH, Yh);
    // final projection + bias, scatter rows back to original order
    gemm_k512<DIMC, true><<<dim3(N_TOK / 128, DIMC / 256), 256, 0, stream>>>(Yh, WoutT, out, bout, indexA);
}

// Round 5
// 447.012 us; speedup vs baseline: 2.5326x; 1.0336x over previous
//
#include <hip/hip_runtime.h>
#include <hip/hip_bf16.h>

// ---------------- problem constants ----------------
#define N_TOK 32768
#define DIMC  512
#define NH    8
#define DHD   64
#define NL    64
#define KSZ   33
#define QKVC  1536
#define NCHUNK 64   // attn3 chunks; 512 tokens per block

typedef _Float16 f16;
typedef _Float16 f16x8 __attribute__((ext_vector_type(8)));
typedef _Float16 f16x4 __attribute__((ext_vector_type(4)));
typedef float    f32x4 __attribute__((ext_vector_type(4)));

#define GLOAD_LDS16(gp, lp) \
    __builtin_amdgcn_global_load_lds((const __attribute__((address_space(1))) void*)(gp), \
                                     (__attribute__((address_space(3))) void*)(lp), 16, 0, 0)

// ---------------- transpose f32 (R x C) -> f16 (C x R) ----------------
__global__ void transpose_k(const float* __restrict__ W, f16* __restrict__ WT, int R, int C) {
    __shared__ float tile[32][33];
    int bx = blockIdx.x * 32, by = blockIdx.y * 32;
    int tx = threadIdx.x, ty = threadIdx.y;
    #pragma unroll
    for (int i = 0; i < 32; i += 8)
        tile[ty + i][tx] = W[(size_t)(by + ty + i) * C + bx + tx];
    __syncthreads();
    #pragma unroll
    for (int i = 0; i < 32; i += 8)
        WT[(size_t)(bx + ty + i) * R + by + tx] = (f16)tile[tx][ty + i];
}

// ---------------- label histogram ----------------
__global__ void hist_k(const int* __restrict__ labels, int* __restrict__ counts) {
    __shared__ int hloc[NL];
    int t = threadIdx.x;
    if (t < NL) hloc[t] = 0;
    __syncthreads();
    int i = blockIdx.x * 256 + t;
    atomicAdd(&hloc[labels[i]], 1);
    __syncthreads();
    if (t < NL) atomicAdd(&counts[t], hloc[t]);
}

// ---------------- exclusive prefix over 64 counts ----------------
__global__ void scan_k(const int* __restrict__ counts, int* __restrict__ base) {
    if (threadIdx.x == 0) {
        int s = 0;
        for (int l = 0; l < NL; ++l) { base[l] = s; s += counts[l]; }
    }
}

// ---------------- stable compaction: one block per label ----------------
__global__ __launch_bounds__(256) void compact_k(const int* __restrict__ labels,
                                                 const int* __restrict__ base,
                                                 int* __restrict__ indexArr) {
    const int l = blockIdx.x;
    __shared__ int wtot[4];
    __shared__ int s_run;
    int t = threadIdx.x, lane = t & 63, w = t >> 6;
    if (t == 0) s_run = base[l];
    __syncthreads();
    for (int c0 = 0; c0 < N_TOK; c0 += 256) {
        int ii = c0 + t;
        bool flag = (labels[ii] == l);
        unsigned long long mask = __ballot(flag);
        int before = __popcll(mask & ((1ull << lane) - 1ull));
        if (lane == 0) wtot[w] = __popcll(mask);
        __syncthreads();
        int off = 0;
        #pragma unroll
        for (int ww = 0; ww < 4; ++ww) off += (ww < w) ? wtot[ww] : 0;
        int tot = wtot[0] + wtot[1] + wtot[2] + wtot[3];
        int rb = s_run;
        if (flag) indexArr[rb + off + before] = ii;
        __syncthreads();
        if (t == 0) s_run = rb + tot;
    }
}

// ---------------- gather rows of x via index, convert to f16 (sorted domain) ----------------
__global__ __launch_bounds__(256) void gather_cvt_k(const float4* __restrict__ x4,
                                                    const int* __restrict__ indexArr,
                                                    f16x4* __restrict__ xh4) {
    int t = threadIdx.x;
    int row = blockIdx.x * 2 + (t >> 7);
    int c4 = t & 127;
    int j = indexArr[row];
    float4 v = x4[(size_t)j * 128 + c4];
    f16x4 o = { (f16)v.x, (f16)v.y, (f16)v.z, (f16)v.w };
    xh4[(size_t)row * 128 + c4] = o;
}

// ---------------- f16 MFMA GEMM: C[M x BNTOT] = A[M x 512] @ BT[BNTOT x 512]^T ----------------
// tile 128x256, BK=32, 4 waves. LDS chunk-XOR swizzle (T2, source-side for global_load_lds);
// swapped-operand MFMA so each lane owns 4 consecutive C-cols (vector epilogue);
// bijective XCD-aware block swizzle (T1). NY = gridDim.y.
template<int BNTOT, bool OUT_F32, int NY>
__global__ __launch_bounds__(256) void gemm_k512(const f16* __restrict__ A, const f16* __restrict__ BT,
                                                 void* __restrict__ Cout, const float* __restrict__ bias,
                                                 const int* __restrict__ scatterIdx) {
    constexpr int K = 512;
    __shared__ f16 As[128 * 32];
    __shared__ f16 Bs[256 * 32];
    const int t = threadIdx.x;
    // XCD-aware swizzle: dispatch id -> contiguous chunk per XCD, n-fastest within chunk
    const int orig = blockIdx.x + gridDim.x * blockIdx.y;
    constexpr int NWG = 256 * NY;           // gridDim.x == 256 always (N_TOK/128)
    constexpr int CPX = NWG / 8;
    const int lin = (orig & 7) * CPX + (orig >> 3);
    const int mBase = (lin / NY) * 128;
    const int nBase = (lin % NY) * 256;
    const int w = t >> 6, lane = t & 63;
    const int lr = lane & 15, lk = lane >> 4;
    const int kc = (lk ^ ((lr >> 1) & 3)) * 8;   // swizzled chunk offset (halves) for fragment reads
    f32x4 acc[8][4];
    #pragma unroll
    for (int m = 0; m < 8; ++m)
        #pragma unroll
        for (int n = 0; n < 4; ++n) acc[m][n] = (f32x4){0.f, 0.f, 0.f, 0.f};

    for (int kt = 0; kt < K / 32; ++kt) {
        __syncthreads();
        // A: 512 chunks of 16B; LDS linear dest, inverse-swizzled global source
        #pragma unroll
        for (int r = 0; r < 2; ++r) {
            int id = r * 256 + w * 64 + lane;
            int row = id >> 2, c = id & 3;
            int cg = c ^ ((row >> 1) & 3);
            GLOAD_LDS16(&A[(size_t)(mBase + row) * K + kt * 32 + cg * 8],
                        &As[(size_t)(r * 256 + w * 64) * 8]);
        }
        // B: 1024 chunks
        #pragma unroll
        for (int r = 0; r < 4; ++r) {
            int id = r * 256 + w * 64 + lane;
            int row = id >> 2, c = id & 3;
            int cg = c ^ ((row >> 1) & 3);
            GLOAD_LDS16(&BT[(size_t)(nBase + row) * K + kt * 32 + cg * 8],
                        &Bs[(size_t)(r * 256 + w * 64) * 8]);
        }
        __syncthreads();
        f16x8 af[8], bf[4];
        #pragma unroll
        for (int m = 0; m < 8; ++m) af[m] = *(const f16x8*)&As[(m * 16 + lr) * 32 + kc];
        #pragma unroll
        for (int n = 0; n < 4; ++n) bf[n] = *(const f16x8*)&Bs[(w * 64 + n * 16 + lr) * 32 + kc];
        // swapped operands: lane element j maps to C col = nBase + w*64 + n*16 + lk*4 + j,
        // C row = mBase + m*16 + lr
        #pragma unroll
        for (int m = 0; m < 8; ++m)
            #pragma unroll
            for (int n = 0; n < 4; ++n)
                acc[m][n] = __builtin_amdgcn_mfma_f32_16x16x32_f16(bf[n], af[m], acc[m][n], 0, 0, 0);
    }
    #pragma unroll
    for (int m = 0; m < 8; ++m) {
        int row = mBase + m * 16 + lr;
        int srow = OUT_F32 ? scatterIdx[row] : row;
        #pragma unroll
        for (int n = 0; n < 4; ++n) {
            int col = nBase + w * 64 + n * 16 + lk * 4;
            if constexpr (OUT_F32) {
                float4 bv = *(const float4*)&bias[col];
                float4 sv = make_float4(acc[m][n][0] + bv.x, acc[m][n][1] + bv.y,
                                        acc[m][n][2] + bv.z, acc[m][n][3] + bv.w);
                *(float4*)&((float*)Cout)[(size_t)srow * BNTOT + col] = sv;
            } else {
                f16x4 hv = { (f16)acc[m][n][0], (f16)acc[m][n][1],
                             (f16)acc[m][n][2], (f16)acc[m][n][3] };
                *(f16x4*)&((f16*)Cout)[(size_t)srow * BNTOT + col] = hv;
            }
        }
    }
}

// ---------------- segment-mean pooling (vectorized): sorted q,k -> ql,kl (f32) + qlh,klh (f16) ----------------
__global__ __launch_bounds__(1024) void pool_k(const f16* __restrict__ qkvh,
                                               const int* __restrict__ base, const int* __restrict__ counts,
                                               float* __restrict__ ql, float* __restrict__ kl,
                                               f16* __restrict__ qlh, f16* __restrict__ klh) {
    int l = blockIdx.x;
    int t = threadIdx.x;
    int c = t & 127, rg = t >> 7;
    int b0 = base[l], cnt = counts[l];
    f32x4 a0 = {0.f,0.f,0.f,0.f}, a1 = {0.f,0.f,0.f,0.f};
    for (int p = rg; p < cnt; p += 8) {
        f16x8 v = *(const f16x8*)&qkvh[(size_t)(b0 + p) * QKVC + c * 8];
        a0[0] += (float)v[0]; a0[1] += (float)v[1]; a0[2] += (float)v[2]; a0[3] += (float)v[3];
        a1[0] += (float)v[4]; a1[1] += (float)v[5]; a1[2] += (float)v[6]; a1[3] += (float)v[7];
    }
    __shared__ f32x4 red[8][128][2];
    red[rg][c][0] = a0; red[rg][c][1] = a1;
    __syncthreads();
    if (t < 128) {
        float inv = 1.0f / (float)(cnt > 0 ? cnt : 1);
        f32x4 s0 = {0.f,0.f,0.f,0.f}, s1 = {0.f,0.f,0.f,0.f};
        #pragma unroll
        for (int g = 0; g < 8; ++g) { s0 += red[g][t][0]; s1 += red[g][t][1]; }
        s0 *= inv; s1 *= inv;
        int h = (t & 63) >> 3, d0 = (t & 7) * 8;
        size_t o = ((size_t)(h * 64 + l)) * 64 + d0;
        f16x8 hv;
        #pragma unroll
        for (int e = 0; e < 4; ++e) { hv[e] = (f16)s0[e]; hv[4 + e] = (f16)s1[e]; }
        if (t < 64) {
            *(f32x4*)&ql[o] = s0; *(f32x4*)&ql[o + 4] = s1;
            *(f16x8*)&qlh[o] = hv;
        } else {
            *(f32x4*)&kl[o] = s0; *(f32x4*)&kl[o + 4] = s1;
            *(f16x8*)&klh[o] = hv;
        }
    }
}

// ---------------- attn2 = softmax(ql@kl^T) rows; per-head row/col abs-sum maxes ----------------
__global__ __launch_bounds__(256) void attn2_k(const float* __restrict__ ql, const float* __restrict__ kl,
                                               float* __restrict__ a_out, float* __restrict__ mrow,
                                               float* __restrict__ mcol) {
    int h = blockIdx.x;
    __shared__ float qs[64][65], ks[64][65], a[64][65];
    __shared__ float red[64][4];
    __shared__ float rowv[64], colv[64];
    int t = threadIdx.x;
    for (int idx = t; idx < 4096; idx += 256) {
        int r = idx >> 6, c = idx & 63;
        qs[r][c] = ql[h * 4096 + idx];
        ks[r][c] = kl[h * 4096 + idx];
    }
    __syncthreads();
    int i = t >> 2, q4 = t & 3, j0 = q4 * 16;
    float o[16];
    #pragma unroll
    for (int jj = 0; jj < 16; ++jj) o[jj] = 0.f;
    for (int d = 0; d < 64; ++d) {
        float qv = qs[i][d];
        #pragma unroll
        for (int jj = 0; jj < 16; ++jj) o[jj] += qv * ks[j0 + jj][d];
    }
    float pmx = o[0];
    #pragma unroll
    for (int jj = 1; jj < 16; ++jj) pmx = fmaxf(pmx, o[jj]);
    red[i][q4] = pmx;
    __syncthreads();
    float rm = fmaxf(fmaxf(red[i][0], red[i][1]), fmaxf(red[i][2], red[i][3]));
    float psum = 0.f;
    #pragma unroll
    for (int jj = 0; jj < 16; ++jj) { o[jj] = expf(o[jj] - rm); psum += o[jj]; }
    __syncthreads();
    red[i][q4] = psum;
    __syncthreads();
    float rs = red[i][0] + red[i][1] + red[i][2] + red[i][3];
    float inv = 1.0f / rs;
    #pragma unroll
    for (int jj = 0; jj < 16; ++jj) { o[jj] *= inv; a[i][j0 + jj] = o[jj]; }
    __syncthreads();
    for (int idx = t; idx < 4096; idx += 256) a_out[h * 4096 + idx] = a[idx >> 6][idx & 63];
    float rsum = 0.f;
    #pragma unroll
    for (int jj = 0; jj < 16; ++jj) rsum += o[jj];
    __syncthreads();
    red[i][q4] = rsum;
    __syncthreads();
    if (q4 == 0) rowv[i] = red[i][0] + red[i][1] + red[i][2] + red[i][3];
    float csum = 0.f;
    #pragma unroll
    for (int jj = 0; jj < 16; ++jj) csum += a[j0 + jj][i];
    __syncthreads();
    red[i][q4] = csum;
    __syncthreads();
    if (q4 == 0) colv[i] = red[i][0] + red[i][1] + red[i][2] + red[i][3];
    __syncthreads();
    if (t == 0) {
        float mr = rowv[0], mc = colv[0];
        for (int j = 1; j < 64; ++j) { mr = fmaxf(mr, rowv[j]); mc = fmaxf(mc, colv[j]); }
        mrow[h] = mr; mcol[h] = mc;
    }
}

// 4x4-blocked 64x64 matmul helper (operands in LDS, stride 68)
__device__ __forceinline__ void mm_blk(const float (*X)[68], const float (*Y)[68],
                                       int i0, int j0, float o[4][4]) {
    #pragma unroll
    for (int ii = 0; ii < 4; ++ii)
        #pragma unroll
        for (int jj = 0; jj < 4; ++jj) o[ii][jj] = 0.f;
    for (int k = 0; k < 64; ++k) {
        float4 yv = *(const float4*)&Y[k][j0];
        float x0 = X[i0][k], x1 = X[i0 + 1][k], x2 = X[i0 + 2][k], x3 = X[i0 + 3][k];
        o[0][0] += x0 * yv.x; o[0][1] += x0 * yv.y; o[0][2] += x0 * yv.z; o[0][3] += x0 * yv.w;
        o[1][0] += x1 * yv.x; o[1][1] += x1 * yv.y; o[1][2] += x1 * yv.z; o[1][3] += x1 * yv.w;
        o[2][0] += x2 * yv.x; o[2][1] += x2 * yv.y; o[2][2] += x2 * yv.z; o[2][3] += x2 * yv.w;
        o[3][0] += x3 * yv.x; o[3][1] += x3 * yv.y; o[3][2] += x3 * yv.z; o[3][3] += x3 * yv.w;
    }
}

// ---------------- Newton-Schulz pinv (6 iters, f32, per head) ----------------
__global__ __launch_bounds__(256) void pinv_k(const float* __restrict__ a_g, const float* __restrict__ mrow,
                                              const float* __restrict__ mcol, float* __restrict__ z_g) {
    int h = blockIdx.x;
    __shared__ float a[64][68], z[64][68], C[64][68], D[64][68], E[64][68];
    int t = threadIdx.x;
    float mr = mrow[0], mc = mcol[0];
    #pragma unroll
    for (int k = 1; k < 8; ++k) { mr = fmaxf(mr, mrow[k]); mc = fmaxf(mc, mcol[k]); }
    float inv0 = 1.0f / (mr * mc);
    for (int idx = t; idx < 4096; idx += 256) {
        int r = idx >> 6, c = idx & 63;
        float av = a_g[h * 4096 + idx];
        a[r][c] = av;
        z[c][r] = av * inv0;
    }
    __syncthreads();
    int i0 = (t >> 4) * 4, j0 = (t & 15) * 4;
    float o[4][4];
    for (int it = 0; it < 6; ++it) {
        mm_blk(a, z, i0, j0, o);
        #pragma unroll
        for (int ii = 0; ii < 4; ++ii)
            #pragma unroll
            for (int jj = 0; jj < 4; ++jj) C[i0 + ii][j0 + jj] = o[ii][jj];
        __syncthreads();
        mm_blk(C, C, i0, j0, o);
        #pragma unroll
        for (int ii = 0; ii < 4; ++ii)
            #pragma unroll
            for (int jj = 0; jj < 4; ++jj) D[i0 + ii][j0 + jj] = 7.f * C[i0 + ii][j0 + jj] - o[ii][jj];
        __syncthreads();
        mm_blk(C, D, i0, j0, o);
        #pragma unroll
        for (int ii = 0; ii < 4; ++ii)
            #pragma unroll
            for (int jj = 0; jj < 4; ++jj) E[i0 + ii][j0 + jj] = 15.f * C[i0 + ii][j0 + jj] - o[ii][jj];
        __syncthreads();
        mm_blk(z, E, i0, j0, o);
        #pragma unroll
        for (int ii = 0; ii < 4; ++ii)
            #pragma unroll
            for (int jj = 0; jj < 4; ++jj) D[i0 + ii][j0 + jj] = 0.25f * (13.f * z[i0 + ii][j0 + jj] - o[ii][jj]);
        __syncthreads();
        #pragma unroll
        for (int ii = 0; ii < 4; ++ii)
            #pragma unroll
            for (int jj = 0; jj < 4; ++jj) z[i0 + ii][j0 + jj] = D[i0 + ii][j0 + jj];
        __syncthreads();
    }
    for (int idx = t; idx < 4096; idx += 256) z_g[h * 4096 + idx] = z[idx >> 6][idx & 63];
}

// ---------------- attn3 @ v via MFMA: flash-style online softmax, per-block partials ----------------
__global__ __launch_bounds__(256) void attn3_k(const f16* __restrict__ qkvh, const f16* __restrict__ qlh,
                                               float* __restrict__ pm, float* __restrict__ ps,
                                               float* __restrict__ pacc) {
    const int cx = blockIdx.x, h = blockIdx.y;
    const int t = threadIdx.x;
    const int w = t >> 6, lane = t & 63;
    const int lr = lane & 15, hi = lane >> 4;
    __shared__ f16 Qls[64 * 64];
    __shared__ f16 Ks[64 * 64];
    __shared__ f16 vT[64 * 72];
    __shared__ f16 Ps[64 * 72];
    __shared__ float fsh[64];

    #pragma unroll
    for (int pss = 0; pss < 2; ++pss) {
        int q = pss * 256 + t;
        int r = q >> 3, cs = (q & 7) ^ (r & 7);
        GLOAD_LDS16(&qlh[(size_t)h * 4096 + r * 64 + cs * 8], &Qls[(size_t)(pss * 256 + w * 64) * 8]);
    }
    float m_reg = -1e30f, s_reg = 0.f;
    f32x4 accT[4];
    #pragma unroll
    for (int lf = 0; lf < 4; ++lf) accT[lf] = (f32x4){0.f, 0.f, 0.f, 0.f};

    const int vk8 = t & 7, vnn = t >> 3;

    for (int sub = 0; sub < 8; ++sub) {
        const int n0 = cx * 512 + sub * 64;
        __syncthreads();
        #pragma unroll
        for (int pss = 0; pss < 2; ++pss) {
            int q = pss * 256 + t;
            int r = q >> 3, cs = (q & 7) ^ (r & 7);
            GLOAD_LDS16(&qkvh[(size_t)(n0 + r) * QKVC + 512 + h * 64 + cs * 8],
                        &Ks[(size_t)(pss * 256 + w * 64) * 8]);
        }
        #pragma unroll
        for (int p2 = 0; p2 < 2; ++p2) {
            int n = vnn + 32 * p2;
            f16x8 rv = *(const f16x8*)&qkvh[(size_t)(n0 + n) * QKVC + 1024 + h * 64 + vk8 * 8];
            #pragma unroll
            for (int i = 0; i < 8; ++i) {
                int e = i ^ vk8;
                vT[(vk8 * 8 + e) * 72 + n] = rv[e];
            }
        }
        __syncthreads();
        f32x4 c[4];
        #pragma unroll
        for (int kf = 0; kf < 4; ++kf) c[kf] = (f32x4){0.f, 0.f, 0.f, 0.f};
        const int lq = w * 16 + lr;
        #pragma unroll
        for (int ks = 0; ks < 2; ++ks) {
            f16x8 bf = *(const f16x8*)&Qls[lq * 64 + (((ks * 4 + hi) ^ (lq & 7)) * 8)];
            #pragma unroll
            for (int kf = 0; kf < 4; ++kf) {
                int rn = kf * 16 + lr;
                f16x8 af = *(const f16x8*)&Ks[rn * 64 + (((ks * 4 + hi) ^ (rn & 7)) * 8)];
                c[kf] = __builtin_amdgcn_mfma_f32_16x16x32_f16(af, bf, c[kf], 0, 0, 0);
            }
        }
        float tmax = -1e30f;
        #pragma unroll
        for (int kf = 0; kf < 4; ++kf)
            #pragma unroll
            for (int j = 0; j < 4; ++j) tmax = fmaxf(tmax, c[kf][j]);
        tmax = fmaxf(tmax, __shfl_xor(tmax, 16));
        tmax = fmaxf(tmax, __shfl_xor(tmax, 32));
        float newm = fmaxf(m_reg, tmax);
        float fct = __expf(m_reg - newm);
        float psum = 0.f;
        #pragma unroll
        for (int kf = 0; kf < 4; ++kf) {
            f16x4 pk;
            #pragma unroll
            for (int j = 0; j < 4; ++j) {
                float e = __expf(c[kf][j] - newm);
                psum += e;
                pk[j] = (f16)e;
            }
            *(f16x4*)&Ps[lq * 72 + kf * 16 + hi * 4] = pk;
        }
        psum += __shfl_xor(psum, 16);
        psum += __shfl_xor(psum, 32);
        s_reg = s_reg * fct + psum;
        m_reg = newm;
        if (hi == 0) fsh[lq] = fct;
        __syncthreads();
        #pragma unroll
        for (int lf = 0; lf < 4; ++lf) {
            f32x4 fr = *(const f32x4*)&fsh[lf * 16 + hi * 4];
            accT[lf] *= fr;
        }
        #pragma unroll
        for (int ks = 0; ks < 2; ++ks) {
            f16x8 bf = *(const f16x8*)&vT[(w * 16 + lr) * 72 + ks * 32 + hi * 8];
            #pragma unroll
            for (int lf = 0; lf < 4; ++lf) {
                f16x8 af = *(const f16x8*)&Ps[(lf * 16 + lr) * 72 + ks * 32 + hi * 8];
                accT[lf] = __builtin_amdgcn_mfma_f32_16x16x32_f16(af, bf, accT[lf], 0, 0, 0);
            }
        }
    }
    int part = h * NCHUNK + cx;
    if (hi == 0) {
        pm[part * 64 + w * 16 + lr] = m_reg;
        ps[part * 64 + w * 16 + lr] = s_reg;
    }
    #pragma unroll
    for (int lf = 0; lf < 4; ++lf)
        #pragma unroll
        for (int j = 0; j < 4; ++j)
            pacc[((size_t)part * 64 + (lf * 16 + hi * 4 + j)) * 64 + (w * 16 + lr)] = accT[lf][j];
}

// ---------------- merge attn3 partials -> T[h][l][d] ----------------
__global__ void attn3_merge_k(const float* __restrict__ pm, const float* __restrict__ ps,
                              const float* __restrict__ pacc, float* __restrict__ T) {
    int l = blockIdx.x, h = blockIdx.y, d = threadIdx.x;
    float m = -1e30f;
    for (int c = 0; c < NCHUNK; ++c) m = fmaxf(m, pm[(h * NCHUNK + c) * 64 + l]);
    float s = 0.f, a = 0.f;
    for (int c = 0; c < NCHUNK; ++c) {
        float wgt = __expf(pm[(h * NCHUNK + c) * 64 + l] - m);
        s += ps[(h * NCHUNK + c) * 64 + l] * wgt;
        a += pacc[((size_t)(h * NCHUNK + c) * 64 + l) * 64 + d] * wgt;
    }
    T[(h * 64 + l) * 64 + d] = a / s;
}

// ---------------- M = z @ T per head; emit M^T split into f16 hi+lo ----------------
__global__ __launch_bounds__(256) void zmatT_k(const float* __restrict__ z_g, const float* __restrict__ T,
                                               f16* __restrict__ MthHi, f16* __restrict__ MthLo) {
    int h = blockIdx.x;
    __shared__ float zs[64][68], Ts[64][68];
    int t = threadIdx.x;
    for (int idx = t; idx < 4096; idx += 256) {
        int r = idx >> 6, c = idx & 63;
        zs[r][c] = z_g[h * 4096 + idx];
        Ts[r][c] = T[h * 4096 + idx];
    }
    __syncthreads();
    int i0 = (t >> 4) * 4, j0 = (t & 15) * 4;
    float o[4][4];
    mm_blk(zs, Ts, i0, j0, o);
    #pragma unroll
    for (int ii = 0; ii < 4; ++ii)
        #pragma unroll
        for (int jj = 0; jj < 4; ++jj) {
            float mv = o[ii][jj];
            f16 hiv = (f16)mv;
            f16 lov = (f16)(mv - (float)hiv);
            MthHi[h * 4096 + (j0 + jj) * 64 + (i0 + ii)] = hiv;
            MthLo[h * 4096 + (j0 + jj) * 64 + (i0 + ii)] = lov;
        }
}

// ---------------- depthwise conv over sorted v (streaming) -> resH (f16) ----------------
__global__ __launch_bounds__(256) void conv_k(const f16* __restrict__ qkvh,
                                              const float* __restrict__ resk, f16* __restrict__ resH) {
    int h = blockIdx.y;
    int p0 = blockIdx.x * 256;
    __shared__ f16 vt[288][72];
    int t = threadIdx.x;
    for (int id = t; id < 288 * 8; id += 256) {
        int rr = id >> 3, c = id & 7;
        int pg = p0 - 16 + rr;
        int4 v = {0, 0, 0, 0};
        if (pg >= 0 && pg < N_TOK)
            v = *(const int4*)&qkvh[(size_t)pg * QKVC + 1024 + h * 64 + c * 8];
        *(int4*)&vt[rr][c * 8] = v;
    }
    float wk[KSZ];
    #pragma unroll
    for (int k = 0; k < KSZ; ++k) wk[k] = resk[h * KSZ + k];
    __syncthreads();
    int d = t & 63, pg4 = t >> 6;
    float col[96];
    #pragma unroll
    for (int i2 = 0; i2 < 96; ++i2) col[i2] = (float)vt[pg4 * 64 + i2][d];
    #pragma unroll
    for (int pp = 0; pp < 64; ++pp) {
        float acc = 0.f;
        #pragma unroll
        for (int k = 0; k < KSZ; ++k) acc += wk[k] * col[pp + k];
        resH[(size_t)(p0 + pg4 * 64 + pp) * 512 + h * 64 + d] = (f16)acc;
    }
}

// ---------------- attn1 via MFMA: softmax(Q@kl^T) @ M + residual -> Yh ----------------
__global__ __launch_bounds__(256) void attn1_k(const f16* __restrict__ qkvh, const f16* __restrict__ klh,
                                               const f16* __restrict__ MthHi, const f16* __restrict__ MthLo,
                                               const f16* __restrict__ resH, f16* __restrict__ Yh) {
    const int h = blockIdx.y;
    const int p0 = blockIdx.x * 128;
    const int t = threadIdx.x;
    const int w = t >> 6, lane = t & 63;
    const int lr = lane & 15, hi = lane >> 4;
    __shared__ f16 Qs[128][72];
    __shared__ f16 Ks[64][72];
    __shared__ f16 Mhi[64][72];
    __shared__ f16 Mlo[64][72];
    __shared__ f16 Ps[128][72];

    #pragma unroll
    for (int i = 0; i < 4; ++i) {
        int id = i * 256 + t, row = id >> 3, c8 = id & 7;
        *(f16x8*)&Qs[row][c8 * 8] = *(const f16x8*)&qkvh[(size_t)(p0 + row) * QKVC + h * 64 + c8 * 8];
    }
    #pragma unroll
    for (int i = 0; i < 2; ++i) {
        int id = i * 256 + t, row = id >> 3, c8 = id & 7;
        *(f16x8*)&Ks[row][c8 * 8]  = *(const f16x8*)&klh[h * 4096 + id * 8];
        *(f16x8*)&Mhi[row][c8 * 8] = *(const f16x8*)&MthHi[h * 4096 + id * 8];
        *(f16x8*)&Mlo[row][c8 * 8] = *(const f16x8*)&MthLo[h * 4096 + id * 8];
    }
    __syncthreads();

    f32x4 c[4][2];
    #pragma unroll
    for (int lf = 0; lf < 4; ++lf)
        #pragma unroll
        for (int nf = 0; nf < 2; ++nf) c[lf][nf] = (f32x4){0.f, 0.f, 0.f, 0.f};
    #pragma unroll
    for (int ks = 0; ks < 2; ++ks) {
        f16x8 af[4], bf[2];
        #pragma unroll
        for (int lf = 0; lf < 4; ++lf) af[lf] = *(const f16x8*)&Ks[lf * 16 + lr][ks * 32 + hi * 8];
        #pragma unroll
        for (int nf = 0; nf < 2; ++nf) bf[nf] = *(const f16x8*)&Qs[w * 32 + nf * 16 + lr][ks * 32 + hi * 8];
        #pragma unroll
        for (int lf = 0; lf < 4; ++lf)
            #pragma unroll
            for (int nf = 0; nf < 2; ++nf)
                c[lf][nf] = __builtin_amdgcn_mfma_f32_16x16x32_f16(af[lf], bf[nf], c[lf][nf], 0, 0, 0);
    }

    #pragma unroll
    for (int nf = 0; nf < 2; ++nf) {
        float m = -1e30f;
        #pragma unroll
        for (int lf = 0; lf < 4; ++lf)
            #pragma unroll
            for (int j = 0; j < 4; ++j) m = fmaxf(m, c[lf][nf][j]);
        m = fmaxf(m, __shfl_xor(m, 16));
        m = fmaxf(m, __shfl_xor(m, 32));
        float s = 0.f;
        #pragma unroll
        for (int lf = 0; lf < 4; ++lf)
            #pragma unroll
            for (int j = 0; j < 4; ++j) { float e = __expf(c[lf][nf][j] - m); c[lf][nf][j] = e; s += e; }
        s += __shfl_xor(s, 16);
        s += __shfl_xor(s, 32);
        float inv = 1.0f / s;
        #pragma unroll
        for (int lf = 0; lf < 4; ++lf) {
            f16x4 pk;
            #pragma unroll
            for (int j = 0; j < 4; ++j) pk[j] = (f16)(c[lf][nf][j] * inv);
            *(f16x4*)&Ps[w * 32 + nf * 16 + lr][lf * 16 + hi * 4] = pk;
        }
    }

    f32x4 o[2][4];
    #pragma unroll
    for (int nf = 0; nf < 2; ++nf)
        #pragma unroll
        for (int df = 0; df < 4; ++df) o[nf][df] = (f32x4){0.f, 0.f, 0.f, 0.f};
    #pragma unroll
    for (int ks = 0; ks < 2; ++ks) {
        f16x8 pa[2], bh[4], bl[4];
        #pragma unroll
        for (int nf = 0; nf < 2; ++nf) pa[nf] = *(const f16x8*)&Ps[w * 32 + nf * 16 + lr][ks * 32 + hi * 8];
        #pragma unroll
        for (int df = 0; df < 4; ++df) {
            bh[df] = *(const f16x8*)&Mhi[df * 16 + lr][ks * 32 + hi * 8];
            bl[df] = *(const f16x8*)&Mlo[df * 16 + lr][ks * 32 + hi * 8];
        }
        #pragma unroll
        for (int nf = 0; nf < 2; ++nf)
            #pragma unroll
            for (int df = 0; df < 4; ++df) {
                o[nf][df] = __builtin_amdgcn_mfma_f32_16x16x32_f16(pa[nf], bh[df], o[nf][df], 0, 0, 0);
                o[nf][df] = __builtin_amdgcn_mfma_f32_16x16x32_f16(pa[nf], bl[df], o[nf][df], 0, 0, 0);
            }
    }

    #pragma unroll
    for (int nf = 0; nf < 2; ++nf)
        #pragma unroll
        for (int df = 0; df < 4; ++df)
            #pragma unroll
            for (int j = 0; j < 4; ++j)
                Ps[w * 32 + nf * 16 + hi * 4 + j][df * 16 + lr] = (f16)(o[nf][df][j]);
    __syncthreads();

    #pragma unroll
    for (int i = 0; i < 4; ++i) {
        int id = i * 256 + t, row = id >> 3, c8 = id & 7;
        size_t go = (size_t)(p0 + row) * 512 + h * 64 + c8 * 8;
        f16x8 yv = *(const f16x8*)&Ps[row][c8 * 8];
        f16x8 rv = *(const f16x8*)&resH[go];
        f16x8 sv;
        #pragma unroll
        for (int e = 0; e < 8; ++e) sv[e] = (f16)((float)yv[e] + (float)rv[e]);
        *(f16x8*)&Yh[go] = sv;
    }
}

// ---------------- host launch ----------------
extern "C" void kernel_launch(void* const* d_in, const int* in_sizes, int n_in,
                              void* d_out, int out_size, void* d_ws, size_t ws_size,
                              hipStream_t stream) {
    const float* x    = (const float*)d_in[0];
    const float* Wqkv = (const float*)d_in[1];
    const float* Wout = (const float*)d_in[2];
    const float* bout = (const float*)d_in[3];
    const float* resk = (const float*)d_in[4];
    const int*   labels = (const int*)d_in[5];
    float* out = (float*)d_out;

    char* w = (char*)d_ws;
    size_t off = 0;
    auto alloc = [&](size_t bytes) {
        void* p = w + off;
        off += (bytes + 255) & ~(size_t)255;
        return p;
    };
    f16* xh     = (f16*)alloc((size_t)N_TOK * DIMC * 2);       // sorted
    f16* qkvh   = (f16*)alloc((size_t)N_TOK * QKVC * 2);       // sorted
    f16* WqkvT  = (f16*)alloc((size_t)QKVC * DIMC * 2);
    f16* WoutT  = (f16*)alloc((size_t)DIMC * DIMC * 2);
    f16* Yh     = (f16*)alloc((size_t)N_TOK * DIMC * 2);       // sorted
    int* counts = (int*)alloc(NL * 4);
    int* baseA  = (int*)alloc(NL * 4);
    int* indexA = (int*)alloc((size_t)N_TOK * 4);
    float* ql   = (float*)alloc((size_t)NH * 64 * 64 * 4);
    float* kl   = (float*)alloc((size_t)NH * 64 * 64 * 4);
    f16* qlh    = (f16*)alloc((size_t)NH * 64 * 64 * 2);
    f16* klh    = (f16*)alloc((size_t)NH * 64 * 64 * 2);
    float* a2   = (float*)alloc((size_t)NH * 64 * 64 * 4);
    float* mrow = (float*)alloc(NH * 4);
    float* mcol = (float*)alloc(NH * 4);
    float* zb   = (float*)alloc((size_t)NH * 64 * 64 * 4);
    float* Tb   = (float*)alloc((size_t)NH * 64 * 64 * 4);
    f16* MthHi  = (f16*)alloc((size_t)NH * 64 * 64 * 2);
    f16* MthLo  = (f16*)alloc((size_t)NH * 64 * 64 * 2);
    float* pm   = (float*)alloc((size_t)NH * NCHUNK * 64 * 4);
    float* ps   = (float*)alloc((size_t)NH * NCHUNK * 64 * 4);
    float* pacc = (float*)alloc((size_t)NH * NCHUNK * 64 * 64 * 4);
    f16* resH = (f16*)d_out;  // reuse d_out (64MB) as f16 conv output (32MB); overwritten by final GEMM

    hipMemsetAsync(counts, 0, NL * 4, stream);

    // stable counting sort
    hist_k<<<N_TOK / 256, 256, 0, stream>>>(labels, counts);
    scan_k<<<1, 64, 0, stream>>>(counts, baseA);
    compact_k<<<NL, 256, 0, stream>>>(labels, baseA, indexA);
    // gather+convert x rows into sorted order
    gather_cvt_k<<<N_TOK / 2, 256, 0, stream>>>((const float4*)x, indexA, (f16x4*)xh);
    // weight transposes
    transpose_k<<<dim3(QKVC / 32, DIMC / 32), dim3(32, 8), 0, stream>>>(Wqkv, WqkvT, DIMC, QKVC);
    transpose_k<<<dim3(DIMC / 32, DIMC / 32), dim3(32, 8), 0, stream>>>(Wout, WoutT, DIMC, DIMC);
    // qkv = x_sorted @ Wqkv  (sorted domain)
    gemm_k512<QKVC, false, 6><<<dim3(N_TOK / 128, QKVC / 256), 256, 0, stream>>>(xh, WqkvT, qkvh, nullptr, nullptr);
    // segment pooling (vectorized)
    pool_k<<<NL, 1024, 0, stream>>>(qkvh, baseA, counts, ql, kl, qlh, klh);
    // attn2 + pinv chain (f32)
    attn2_k<<<NH, 256, 0, stream>>>(ql, kl, a2, mrow, mcol);
    pinv_k<<<NH, 256, 0, stream>>>(a2, mrow, mcol, zb);
    // T = softmax(ql@k^T) @ v  (MFMA flash-style)
    attn3_k<<<dim3(NCHUNK, NH), 256, 0, stream>>>(qkvh, qlh, pm, ps, pacc);
    attn3_merge_k<<<dim3(NL, NH), 64, 0, stream>>>(pm, ps, pacc, Tb);
    // M^T (hi+lo f16) = (z @ T)^T
    zmatT_k<<<NH, 256, 0, stream>>>(zb, Tb, MthHi, MthLo);
    // depthwise conv over sorted v (streaming)
    conv_k<<<dim3(N_TOK / 256, NH), 256, 0, stream>>>(qkvh, resk, resH);
    // attn1 (MFMA) + combine -> Yh (sorted)
    attn1_k<<<dim3(N_TOK / 128, NH), 256, 0, stream>>>(qkvh, klh, MthHi, MthLo, resH, Yh);
    // final projection + bias, scatter rows back to original order
    gemm_k512<DIMC, true, 2><<<dim3(N_TOK / 128, DIMC / 256), 256, 0, stream>>>(Yh, WoutT, out, bout, indexA);
}

// Round 6
// 411.375 us; speedup vs baseline: 2.7520x; 1.0866x over previous
//
#include <hip/hip_runtime.h>
#include <hip/hip_bf16.h>

// ---------------- problem constants ----------------
#define N_TOK 32768
#define DIMC  512
#define NH    8
#define DHD   64
#define NL    64
#define KSZ   33
#define QKVC  1536
#define NCHUNK 64   // attn3 chunks; 512 tokens per block

typedef _Float16 f16;
typedef _Float16 f16x8 __attribute__((ext_vector_type(8)));
typedef _Float16 f16x4 __attribute__((ext_vector_type(4)));
typedef float    f32x4 __attribute__((ext_vector_type(4)));

#define GLOAD_LDS16(gp, lp) \
    __builtin_amdgcn_global_load_lds((const __attribute__((address_space(1))) void*)(gp), \
                                     (__attribute__((address_space(3))) void*)(lp), 16, 0, 0)

// ---------------- transpose f32 (R x C) -> f16 (C x R) ----------------
__global__ void transpose_k(const float* __restrict__ W, f16* __restrict__ WT, int R, int C) {
    __shared__ float tile[32][33];
    int bx = blockIdx.x * 32, by = blockIdx.y * 32;
    int tx = threadIdx.x, ty = threadIdx.y;
    #pragma unroll
    for (int i = 0; i < 32; i += 8)
        tile[ty + i][tx] = W[(size_t)(by + ty + i) * C + bx + tx];
    __syncthreads();
    #pragma unroll
    for (int i = 0; i < 32; i += 8)
        WT[(size_t)(bx + ty + i) * R + by + tx] = (f16)tile[tx][ty + i];
}

// ---------------- label histogram ----------------
__global__ void hist_k(const int* __restrict__ labels, int* __restrict__ counts) {
    __shared__ int hloc[NL];
    int t = threadIdx.x;
    if (t < NL) hloc[t] = 0;
    __syncthreads();
    int i = blockIdx.x * 256 + t;
    atomicAdd(&hloc[labels[i]], 1);
    __syncthreads();
    if (t < NL) atomicAdd(&counts[t], hloc[t]);
}

// ---------------- exclusive prefix over 64 counts ----------------
__global__ void scan_k(const int* __restrict__ counts, int* __restrict__ base) {
    if (threadIdx.x == 0) {
        int s = 0;
        for (int l = 0; l < NL; ++l) { base[l] = s; s += counts[l]; }
    }
}

// ---------------- stable compaction: one block per label ----------------
__global__ __launch_bounds__(256) void compact_k(const int* __restrict__ labels,
                                                 const int* __restrict__ base,
                                                 int* __restrict__ indexArr) {
    const int l = blockIdx.x;
    __shared__ int wtot[4];
    __shared__ int s_run;
    int t = threadIdx.x, lane = t & 63, w = t >> 6;
    if (t == 0) s_run = base[l];
    __syncthreads();
    for (int c0 = 0; c0 < N_TOK; c0 += 256) {
        int ii = c0 + t;
        bool flag = (labels[ii] == l);
        unsigned long long mask = __ballot(flag);
        int before = __popcll(mask & ((1ull << lane) - 1ull));
        if (lane == 0) wtot[w] = __popcll(mask);
        __syncthreads();
        int off = 0;
        #pragma unroll
        for (int ww = 0; ww < 4; ++ww) off += (ww < w) ? wtot[ww] : 0;
        int tot = wtot[0] + wtot[1] + wtot[2] + wtot[3];
        int rb = s_run;
        if (flag) indexArr[rb + off + before] = ii;
        __syncthreads();
        if (t == 0) s_run = rb + tot;
    }
}

// ---------------- gather rows of x via index, convert to f16 (sorted domain) ----------------
__global__ __launch_bounds__(256) void gather_cvt_k(const float4* __restrict__ x4,
                                                    const int* __restrict__ indexArr,
                                                    f16x4* __restrict__ xh4) {
    int t = threadIdx.x;
    int row = blockIdx.x * 2 + (t >> 7);
    int c4 = t & 127;
    int j = indexArr[row];
    float4 v = x4[(size_t)j * 128 + c4];
    f16x4 o = { (f16)v.x, (f16)v.y, (f16)v.z, (f16)v.w };
    xh4[(size_t)row * 128 + c4] = o;
}

// ---------------- f16 MFMA GEMM: C[M x BNTOT] = A[M x 512] @ BT[BNTOT x 512]^T ----------------
// tile 128x256, BK=32, 4 waves. T2 chunk-XOR swizzle (source-side for global_load_lds);
// swapped-operand MFMA (vector epilogue); T1 bijective XCD swizzle;
// T3 minimum 2-phase pipeline: double-buffered LDS, STAGE(next) issued before compute(cur),
// raw s_barrier + asm vmcnt(0) so next-tile loads fly under the MFMA phase.
template<int BNTOT, bool OUT_F32, int NY>
__global__ __launch_bounds__(256) void gemm_k512(const f16* __restrict__ A, const f16* __restrict__ BT,
                                                 void* __restrict__ Cout, const float* __restrict__ bias,
                                                 const int* __restrict__ scatterIdx) {
    constexpr int K = 512;
    constexpr int NKT = K / 32;             // 16 K-tiles
    __shared__ f16 As[2][128 * 32];
    __shared__ f16 Bs[2][256 * 32];
    const int t = threadIdx.x;
    const int orig = blockIdx.x + gridDim.x * blockIdx.y;
    constexpr int NWG = 256 * NY;
    constexpr int CPX = NWG / 8;
    const int lin = (orig & 7) * CPX + (orig >> 3);
    const int mBase = (lin / NY) * 128;
    const int nBase = (lin % NY) * 256;
    const int w = t >> 6, lane = t & 63;
    const int lr = lane & 15, lk = lane >> 4;
    const int kc = (lk ^ ((lr >> 1) & 3)) * 8;   // swizzled chunk offset (halves)
    f32x4 acc[8][4];
    #pragma unroll
    for (int m = 0; m < 8; ++m)
        #pragma unroll
        for (int n = 0; n < 4; ++n) acc[m][n] = (f32x4){0.f, 0.f, 0.f, 0.f};

    auto stage = [&](int buf, int kt) {
        #pragma unroll
        for (int r = 0; r < 2; ++r) {
            int id = r * 256 + w * 64 + lane;
            int row = id >> 2, c = id & 3;
            int cg = c ^ ((row >> 1) & 3);
            GLOAD_LDS16(&A[(size_t)(mBase + row) * K + kt * 32 + cg * 8],
                        &As[buf][(size_t)(r * 256 + w * 64) * 8]);
        }
        #pragma unroll
        for (int r = 0; r < 4; ++r) {
            int id = r * 256 + w * 64 + lane;
            int row = id >> 2, c = id & 3;
            int cg = c ^ ((row >> 1) & 3);
            GLOAD_LDS16(&BT[(size_t)(nBase + row) * K + kt * 32 + cg * 8],
                        &Bs[buf][(size_t)(r * 256 + w * 64) * 8]);
        }
    };
    auto compute = [&](int buf) {
        f16x8 af[8], bf[4];
        #pragma unroll
        for (int m = 0; m < 8; ++m) af[m] = *(const f16x8*)&As[buf][(m * 16 + lr) * 32 + kc];
        #pragma unroll
        for (int n = 0; n < 4; ++n) bf[n] = *(const f16x8*)&Bs[buf][(w * 64 + n * 16 + lr) * 32 + kc];
        #pragma unroll
        for (int m = 0; m < 8; ++m)
            #pragma unroll
            for (int n = 0; n < 4; ++n)
                acc[m][n] = __builtin_amdgcn_mfma_f32_16x16x32_f16(bf[n], af[m], acc[m][n], 0, 0, 0);
    };

    // prologue: stage tile 0, wait, barrier
    stage(0, 0);
    asm volatile("s_waitcnt vmcnt(0)" ::: "memory");
    __builtin_amdgcn_s_barrier();
    int cur = 0;
    for (int kt = 0; kt < NKT - 1; ++kt) {
        stage(cur ^ 1, kt + 1);      // next-tile DMA in flight under compute
        compute(cur);                // ds_read + MFMA (lgkmcnt auto-inserted)
        asm volatile("s_waitcnt vmcnt(0)" ::: "memory");
        __builtin_amdgcn_s_barrier();
        cur ^= 1;
    }
    compute(cur);                    // epilogue tile, no prefetch

    #pragma unroll
    for (int m = 0; m < 8; ++m) {
        int row = mBase + m * 16 + lr;
        int srow = OUT_F32 ? scatterIdx[row] : row;
        #pragma unroll
        for (int n = 0; n < 4; ++n) {
            int col = nBase + w * 64 + n * 16 + lk * 4;
            if constexpr (OUT_F32) {
                float4 bv = *(const float4*)&bias[col];
                float4 sv = make_float4(acc[m][n][0] + bv.x, acc[m][n][1] + bv.y,
                                        acc[m][n][2] + bv.z, acc[m][n][3] + bv.w);
                *(float4*)&((float*)Cout)[(size_t)srow * BNTOT + col] = sv;
            } else {
                f16x4 hv = { (f16)acc[m][n][0], (f16)acc[m][n][1],
                             (f16)acc[m][n][2], (f16)acc[m][n][3] };
                *(f16x4*)&((f16*)Cout)[(size_t)srow * BNTOT + col] = hv;
            }
        }
    }
}

// ---------------- segment-mean pooling (vectorized): sorted q,k -> ql,kl (f32) + qlh,klh (f16) ----------------
__global__ __launch_bounds__(1024) void pool_k(const f16* __restrict__ qkvh,
                                               const int* __restrict__ base, const int* __restrict__ counts,
                                               float* __restrict__ ql, float* __restrict__ kl,
                                               f16* __restrict__ qlh, f16* __restrict__ klh) {
    int l = blockIdx.x;
    int t = threadIdx.x;
    int c = t & 127, rg = t >> 7;
    int b0 = base[l], cnt = counts[l];
    f32x4 a0 = {0.f,0.f,0.f,0.f}, a1 = {0.f,0.f,0.f,0.f};
    for (int p = rg; p < cnt; p += 8) {
        f16x8 v = *(const f16x8*)&qkvh[(size_t)(b0 + p) * QKVC + c * 8];
        a0[0] += (float)v[0]; a0[1] += (float)v[1]; a0[2] += (float)v[2]; a0[3] += (float)v[3];
        a1[0] += (float)v[4]; a1[1] += (float)v[5]; a1[2] += (float)v[6]; a1[3] += (float)v[7];
    }
    __shared__ f32x4 red[8][128][2];
    red[rg][c][0] = a0; red[rg][c][1] = a1;
    __syncthreads();
    if (t < 128) {
        float inv = 1.0f / (float)(cnt > 0 ? cnt : 1);
        f32x4 s0 = {0.f,0.f,0.f,0.f}, s1 = {0.f,0.f,0.f,0.f};
        #pragma unroll
        for (int g = 0; g < 8; ++g) { s0 += red[g][t][0]; s1 += red[g][t][1]; }
        s0 *= inv; s1 *= inv;
        int h = (t & 63) >> 3, d0 = (t & 7) * 8;
        size_t o = ((size_t)(h * 64 + l)) * 64 + d0;
        f16x8 hv;
        #pragma unroll
        for (int e = 0; e < 4; ++e) { hv[e] = (f16)s0[e]; hv[4 + e] = (f16)s1[e]; }
        if (t < 64) {
            *(f32x4*)&ql[o] = s0; *(f32x4*)&ql[o + 4] = s1;
            *(f16x8*)&qlh[o] = hv;
        } else {
            *(f32x4*)&kl[o] = s0; *(f32x4*)&kl[o + 4] = s1;
            *(f16x8*)&klh[o] = hv;
        }
    }
}

// ---------------- attn2 = softmax(ql@kl^T) rows; per-head row/col abs-sum maxes ----------------
__global__ __launch_bounds__(256) void attn2_k(const float* __restrict__ ql, const float* __restrict__ kl,
                                               float* __restrict__ a_out, float* __restrict__ mrow,
                                               float* __restrict__ mcol) {
    int h = blockIdx.x;
    __shared__ float qs[64][65], ks[64][65], a[64][65];
    __shared__ float red[64][4];
    __shared__ float rowv[64], colv[64];
    int t = threadIdx.x;
    for (int idx = t; idx < 4096; idx += 256) {
        int r = idx >> 6, c = idx & 63;
        qs[r][c] = ql[h * 4096 + idx];
        ks[r][c] = kl[h * 4096 + idx];
    }
    __syncthreads();
    int i = t >> 2, q4 = t & 3, j0 = q4 * 16;
    float o[16];
    #pragma unroll
    for (int jj = 0; jj < 16; ++jj) o[jj] = 0.f;
    for (int d = 0; d < 64; ++d) {
        float qv = qs[i][d];
        #pragma unroll
        for (int jj = 0; jj < 16; ++jj) o[jj] += qv * ks[j0 + jj][d];
    }
    float pmx = o[0];
    #pragma unroll
    for (int jj = 1; jj < 16; ++jj) pmx = fmaxf(pmx, o[jj]);
    red[i][q4] = pmx;
    __syncthreads();
    float rm = fmaxf(fmaxf(red[i][0], red[i][1]), fmaxf(red[i][2], red[i][3]));
    float psum = 0.f;
    #pragma unroll
    for (int jj = 0; jj < 16; ++jj) { o[jj] = expf(o[jj] - rm); psum += o[jj]; }
    __syncthreads();
    red[i][q4] = psum;
    __syncthreads();
    float rs = red[i][0] + red[i][1] + red[i][2] + red[i][3];
    float inv = 1.0f / rs;
    #pragma unroll
    for (int jj = 0; jj < 16; ++jj) { o[jj] *= inv; a[i][j0 + jj] = o[jj]; }
    __syncthreads();
    for (int idx = t; idx < 4096; idx += 256) a_out[h * 4096 + idx] = a[idx >> 6][idx & 63];
    float rsum = 0.f;
    #pragma unroll
    for (int jj = 0; jj < 16; ++jj) rsum += o[jj];
    __syncthreads();
    red[i][q4] = rsum;
    __syncthreads();
    if (q4 == 0) rowv[i] = red[i][0] + red[i][1] + red[i][2] + red[i][3];
    float csum = 0.f;
    #pragma unroll
    for (int jj = 0; jj < 16; ++jj) csum += a[j0 + jj][i];
    __syncthreads();
    red[i][q4] = csum;
    __syncthreads();
    if (q4 == 0) colv[i] = red[i][0] + red[i][1] + red[i][2] + red[i][3];
    __syncthreads();
    if (t == 0) {
        float mr = rowv[0], mc = colv[0];
        for (int j = 1; j < 64; ++j) { mr = fmaxf(mr, rowv[j]); mc = fmaxf(mc, colv[j]); }
        mrow[h] = mr; mcol[h] = mc;
    }
}

// 4x4-blocked 64x64 matmul helper (operands in LDS, stride 68)
__device__ __forceinline__ void mm_blk(const float (*X)[68], const float (*Y)[68],
                                       int i0, int j0, float o[4][4]) {
    #pragma unroll
    for (int ii = 0; ii < 4; ++ii)
        #pragma unroll
        for (int jj = 0; jj < 4; ++jj) o[ii][jj] = 0.f;
    for (int k = 0; k < 64; ++k) {
        float4 yv = *(const float4*)&Y[k][j0];
        float x0 = X[i0][k], x1 = X[i0 + 1][k], x2 = X[i0 + 2][k], x3 = X[i0 + 3][k];
        o[0][0] += x0 * yv.x; o[0][1] += x0 * yv.y; o[0][2] += x0 * yv.z; o[0][3] += x0 * yv.w;
        o[1][0] += x1 * yv.x; o[1][1] += x1 * yv.y; o[1][2] += x1 * yv.z; o[1][3] += x1 * yv.w;
        o[2][0] += x2 * yv.x; o[2][1] += x2 * yv.y; o[2][2] += x2 * yv.z; o[2][3] += x2 * yv.w;
        o[3][0] += x3 * yv.x; o[3][1] += x3 * yv.y; o[3][2] += x3 * yv.z; o[3][3] += x3 * yv.w;
    }
}

// ---------------- Newton-Schulz pinv (6 iters, f32, per head) ----------------
__global__ __launch_bounds__(256) void pinv_k(const float* __restrict__ a_g, const float* __restrict__ mrow,
                                              const float* __restrict__ mcol, float* __restrict__ z_g) {
    int h = blockIdx.x;
    __shared__ float a[64][68], z[64][68], C[64][68], D[64][68], E[64][68];
    int t = threadIdx.x;
    float mr = mrow[0], mc = mcol[0];
    #pragma unroll
    for (int k = 1; k < 8; ++k) { mr = fmaxf(mr, mrow[k]); mc = fmaxf(mc, mcol[k]); }
    float inv0 = 1.0f / (mr * mc);
    for (int idx = t; idx < 4096; idx += 256) {
        int r = idx >> 6, c = idx & 63;
        float av = a_g[h * 4096 + idx];
        a[r][c] = av;
        z[c][r] = av * inv0;
    }
    __syncthreads();
    int i0 = (t >> 4) * 4, j0 = (t & 15) * 4;
    float o[4][4];
    for (int it = 0; it < 6; ++it) {
        mm_blk(a, z, i0, j0, o);
        #pragma unroll
        for (int ii = 0; ii < 4; ++ii)
            #pragma unroll
            for (int jj = 0; jj < 4; ++jj) C[i0 + ii][j0 + jj] = o[ii][jj];
        __syncthreads();
        mm_blk(C, C, i0, j0, o);
        #pragma unroll
        for (int ii = 0; ii < 4; ++ii)
            #pragma unroll
            for (int jj = 0; jj < 4; ++jj) D[i0 + ii][j0 + jj] = 7.f * C[i0 + ii][j0 + jj] - o[ii][jj];
        __syncthreads();
        mm_blk(C, D, i0, j0, o);
        #pragma unroll
        for (int ii = 0; ii < 4; ++ii)
            #pragma unroll
            for (int jj = 0; jj < 4; ++jj) E[i0 + ii][j0 + jj] = 15.f * C[i0 + ii][j0 + jj] - o[ii][jj];
        __syncthreads();
        mm_blk(z, E, i0, j0, o);
        #pragma unroll
        for (int ii = 0; ii < 4; ++ii)
            #pragma unroll
            for (int jj = 0; jj < 4; ++jj) D[i0 + ii][j0 + jj] = 0.25f * (13.f * z[i0 + ii][j0 + jj] - o[ii][jj]);
        __syncthreads();
        #pragma unroll
        for (int ii = 0; ii < 4; ++ii)
            #pragma unroll
            for (int jj = 0; jj < 4; ++jj) z[i0 + ii][j0 + jj] = D[i0 + ii][j0 + jj];
        __syncthreads();
    }
    for (int idx = t; idx < 4096; idx += 256) z_g[h * 4096 + idx] = z[idx >> 6][idx & 63];
}

// ---------------- attn3 @ v via MFMA: flash-style online softmax, per-block partials ----------------
__global__ __launch_bounds__(256) void attn3_k(const f16* __restrict__ qkvh, const f16* __restrict__ qlh,
                                               float* __restrict__ pm, float* __restrict__ ps,
                                               float* __restrict__ pacc) {
    const int cx = blockIdx.x, h = blockIdx.y;
    const int t = threadIdx.x;
    const int w = t >> 6, lane = t & 63;
    const int lr = lane & 15, hi = lane >> 4;
    __shared__ f16 Qls[64 * 64];
    __shared__ f16 Ks[64 * 64];
    __shared__ f16 vT[64 * 72];
    __shared__ f16 Ps[64 * 72];
    __shared__ float fsh[64];

    #pragma unroll
    for (int pss = 0; pss < 2; ++pss) {
        int q = pss * 256 + t;
        int r = q >> 3, cs = (q & 7) ^ (r & 7);
        GLOAD_LDS16(&qlh[(size_t)h * 4096 + r * 64 + cs * 8], &Qls[(size_t)(pss * 256 + w * 64) * 8]);
    }
    float m_reg = -1e30f, s_reg = 0.f;
    f32x4 accT[4];
    #pragma unroll
    for (int lf = 0; lf < 4; ++lf) accT[lf] = (f32x4){0.f, 0.f, 0.f, 0.f};

    const int vk8 = t & 7, vnn = t >> 3;

    for (int sub = 0; sub < 8; ++sub) {
        const int n0 = cx * 512 + sub * 64;
        __syncthreads();
        #pragma unroll
        for (int pss = 0; pss < 2; ++pss) {
            int q = pss * 256 + t;
            int r = q >> 3, cs = (q & 7) ^ (r & 7);
            GLOAD_LDS16(&qkvh[(size_t)(n0 + r) * QKVC + 512 + h * 64 + cs * 8],
                        &Ks[(size_t)(pss * 256 + w * 64) * 8]);
        }
        #pragma unroll
        for (int p2 = 0; p2 < 2; ++p2) {
            int n = vnn + 32 * p2;
            f16x8 rv = *(const f16x8*)&qkvh[(size_t)(n0 + n) * QKVC + 1024 + h * 64 + vk8 * 8];
            #pragma unroll
            for (int i = 0; i < 8; ++i) {
                int e = i ^ vk8;
                vT[(vk8 * 8 + e) * 72 + n] = rv[e];
            }
        }
        __syncthreads();
        f32x4 c[4];
        #pragma unroll
        for (int kf = 0; kf < 4; ++kf) c[kf] = (f32x4){0.f, 0.f, 0.f, 0.f};
        const int lq = w * 16 + lr;
        #pragma unroll
        for (int ks = 0; ks < 2; ++ks) {
            f16x8 bf = *(const f16x8*)&Qls[lq * 64 + (((ks * 4 + hi) ^ (lq & 7)) * 8)];
            #pragma unroll
            for (int kf = 0; kf < 4; ++kf) {
                int rn = kf * 16 + lr;
                f16x8 af = *(const f16x8*)&Ks[rn * 64 + (((ks * 4 + hi) ^ (rn & 7)) * 8)];
                c[kf] = __builtin_amdgcn_mfma_f32_16x16x32_f16(af, bf, c[kf], 0, 0, 0);
            }
        }
        float tmax = -1e30f;
        #pragma unroll
        for (int kf = 0; kf < 4; ++kf)
            #pragma unroll
            for (int j = 0; j < 4; ++j) tmax = fmaxf(tmax, c[kf][j]);
        tmax = fmaxf(tmax, __shfl_xor(tmax, 16));
        tmax = fmaxf(tmax, __shfl_xor(tmax, 32));
        float newm = fmaxf(m_reg, tmax);
        float fct = __expf(m_reg - newm);
        float psum = 0.f;
        #pragma unroll
        for (int kf = 0; kf < 4; ++kf) {
            f16x4 pk;
            #pragma unroll
            for (int j = 0; j < 4; ++j) {
                float e = __expf(c[kf][j] - newm);
                psum += e;
                pk[j] = (f16)e;
            }
            *(f16x4*)&Ps[lq * 72 + kf * 16 + hi * 4] = pk;
        }
        psum += __shfl_xor(psum, 16);
        psum += __shfl_xor(psum, 32);
        s_reg = s_reg * fct + psum;
        m_reg = newm;
        if (hi == 0) fsh[lq] = fct;
        __syncthreads();
        #pragma unroll
        for (int lf = 0; lf < 4; ++lf) {
            f32x4 fr = *(const f32x4*)&fsh[lf * 16 + hi * 4];
            accT[lf] *= fr;
        }
        #pragma unroll
        for (int ks = 0; ks < 2; ++ks) {
            f16x8 bf = *(const f16x8*)&vT[(w * 16 + lr) * 72 + ks * 32 + hi * 8];
            #pragma unroll
            for (int lf = 0; lf < 4; ++lf) {
                f16x8 af = *(const f16x8*)&Ps[(lf * 16 + lr) * 72 + ks * 32 + hi * 8];
                accT[lf] = __builtin_amdgcn_mfma_f32_16x16x32_f16(af, bf, accT[lf], 0, 0, 0);
            }
        }
    }
    int part = h * NCHUNK + cx;
    if (hi == 0) {
        pm[part * 64 + w * 16 + lr] = m_reg;
        ps[part * 64 + w * 16 + lr] = s_reg;
    }
    #pragma unroll
    for (int lf = 0; lf < 4; ++lf)
        #pragma unroll
        for (int j = 0; j < 4; ++j)
            pacc[((size_t)part * 64 + (lf * 16 + hi * 4 + j)) * 64 + (w * 16 + lr)] = accT[lf][j];
}

// ---------------- merge attn3 partials -> T[h][l][d] ----------------
__global__ void attn3_merge_k(const float* __restrict__ pm, const float* __restrict__ ps,
                              const float* __restrict__ pacc, float* __restrict__ T) {
    int l = blockIdx.x, h = blockIdx.y, d = threadIdx.x;
    float m = -1e30f;
    for (int c = 0; c < NCHUNK; ++c) m = fmaxf(m, pm[(h * NCHUNK + c) * 64 + l]);
    float s = 0.f, a = 0.f;
    for (int c = 0; c < NCHUNK; ++c) {
        float wgt = __expf(pm[(h * NCHUNK + c) * 64 + l] - m);
        s += ps[(h * NCHUNK + c) * 64 + l] * wgt;
        a += pacc[((size_t)(h * NCHUNK + c) * 64 + l) * 64 + d] * wgt;
    }
    T[(h * 64 + l) * 64 + d] = a / s;
}

// ---------------- M = z @ T per head; emit M^T split into f16 hi+lo ----------------
__global__ __launch_bounds__(256) void zmatT_k(const float* __restrict__ z_g, const float* __restrict__ T,
                                               f16* __restrict__ MthHi, f16* __restrict__ MthLo) {
    int h = blockIdx.x;
    __shared__ float zs[64][68], Ts[64][68];
    int t = threadIdx.x;
    for (int idx = t; idx < 4096; idx += 256) {
        int r = idx >> 6, c = idx & 63;
        zs[r][c] = z_g[h * 4096 + idx];
        Ts[r][c] = T[h * 4096 + idx];
    }
    __syncthreads();
    int i0 = (t >> 4) * 4, j0 = (t & 15) * 4;
    float o[4][4];
    mm_blk(zs, Ts, i0, j0, o);
    #pragma unroll
    for (int ii = 0; ii < 4; ++ii)
        #pragma unroll
        for (int jj = 0; jj < 4; ++jj) {
            float mv = o[ii][jj];
            f16 hiv = (f16)mv;
            f16 lov = (f16)(mv - (float)hiv);
            MthHi[h * 4096 + (j0 + jj) * 64 + (i0 + ii)] = hiv;
            MthLo[h * 4096 + (j0 + jj) * 64 + (i0 + ii)] = lov;
        }
}

// ---------------- depthwise conv over sorted v (streaming) -> resH (f16) ----------------
__global__ __launch_bounds__(256) void conv_k(const f16* __restrict__ qkvh,
                                              const float* __restrict__ resk, f16* __restrict__ resH) {
    int h = blockIdx.y;
    int p0 = blockIdx.x * 256;
    __shared__ f16 vt[288][72];
    int t = threadIdx.x;
    for (int id = t; id < 288 * 8; id += 256) {
        int rr = id >> 3, c = id & 7;
        int pg = p0 - 16 + rr;
        int4 v = {0, 0, 0, 0};
        if (pg >= 0 && pg < N_TOK)
            v = *(const int4*)&qkvh[(size_t)pg * QKVC + 1024 + h * 64 + c * 8];
        *(int4*)&vt[rr][c * 8] = v;
    }
    float wk[KSZ];
    #pragma unroll
    for (int k = 0; k < KSZ; ++k) wk[k] = resk[h * KSZ + k];
    __syncthreads();
    int d = t & 63, pg4 = t >> 6;
    float col[96];
    #pragma unroll
    for (int i2 = 0; i2 < 96; ++i2) col[i2] = (float)vt[pg4 * 64 + i2][d];
    #pragma unroll
    for (int pp = 0; pp < 64; ++pp) {
        float acc = 0.f;
        #pragma unroll
        for (int k = 0; k < KSZ; ++k) acc += wk[k] * col[pp + k];
        resH[(size_t)(p0 + pg4 * 64 + pp) * 512 + h * 64 + d] = (f16)acc;
    }
}

// ---------------- attn1 via MFMA: softmax(Q@kl^T) @ M + residual -> Yh ----------------
__global__ __launch_bounds__(256) void attn1_k(const f16* __restrict__ qkvh, const f16* __restrict__ klh,
                                               const f16* __restrict__ MthHi, const f16* __restrict__ MthLo,
                                               const f16* __restrict__ resH, f16* __restrict__ Yh) {
    const int h = blockIdx.y;
    const int p0 = blockIdx.x * 128;
    const int t = threadIdx.x;
    const int w = t >> 6, lane = t & 63;
    const int lr = lane & 15, hi = lane >> 4;
    __shared__ f16 Qs[128][72];
    __shared__ f16 Ks[64][72];
    __shared__ f16 Mhi[64][72];
    __shared__ f16 Mlo[64][72];
    __shared__ f16 Ps[128][72];

    #pragma unroll
    for (int i = 0; i < 4; ++i) {
        int id = i * 256 + t, row = id >> 3, c8 = id & 7;
        *(f16x8*)&Qs[row][c8 * 8] = *(const f16x8*)&qkvh[(size_t)(p0 + row) * QKVC + h * 64 + c8 * 8];
    }
    #pragma unroll
    for (int i = 0; i < 2; ++i) {
        int id = i * 256 + t, row = id >> 3, c8 = id & 7;
        *(f16x8*)&Ks[row][c8 * 8]  = *(const f16x8*)&klh[h * 4096 + id * 8];
        *(f16x8*)&Mhi[row][c8 * 8] = *(const f16x8*)&MthHi[h * 4096 + id * 8];
        *(f16x8*)&Mlo[row][c8 * 8] = *(const f16x8*)&MthLo[h * 4096 + id * 8];
    }
    __syncthreads();

    f32x4 c[4][2];
    #pragma unroll
    for (int lf = 0; lf < 4; ++lf)
        #pragma unroll
        for (int nf = 0; nf < 2; ++nf) c[lf][nf] = (f32x4){0.f, 0.f, 0.f, 0.f};
    #pragma unroll
    for (int ks = 0; ks < 2; ++ks) {
        f16x8 af[4], bf[2];
        #pragma unroll
        for (int lf = 0; lf < 4; ++lf) af[lf] = *(const f16x8*)&Ks[lf * 16 + lr][ks * 32 + hi * 8];
        #pragma unroll
        for (int nf = 0; nf < 2; ++nf) bf[nf] = *(const f16x8*)&Qs[w * 32 + nf * 16 + lr][ks * 32 + hi * 8];
        #pragma unroll
        for (int lf = 0; lf < 4; ++lf)
            #pragma unroll
            for (int nf = 0; nf < 2; ++nf)
                c[lf][nf] = __builtin_amdgcn_mfma_f32_16x16x32_f16(af[lf], bf[nf], c[lf][nf], 0, 0, 0);
    }

    #pragma unroll
    for (int nf = 0; nf < 2; ++nf) {
        float m = -1e30f;
        #pragma unroll
        for (int lf = 0; lf < 4; ++lf)
            #pragma unroll
            for (int j = 0; j < 4; ++j) m = fmaxf(m, c[lf][nf][j]);
        m = fmaxf(m, __shfl_xor(m, 16));
        m = fmaxf(m, __shfl_xor(m, 32));
        float s = 0.f;
        #pragma unroll
        for (int lf = 0; lf < 4; ++lf)
            #pragma unroll
            for (int j = 0; j < 4; ++j) { float e = __expf(c[lf][nf][j] - m); c[lf][nf][j] = e; s += e; }
        s += __shfl_xor(s, 16);
        s += __shfl_xor(s, 32);
        float inv = 1.0f / s;
        #pragma unroll
        for (int lf = 0; lf < 4; ++lf) {
            f16x4 pk;
            #pragma unroll
            for (int j = 0; j < 4; ++j) pk[j] = (f16)(c[lf][nf][j] * inv);
            *(f16x4*)&Ps[w * 32 + nf * 16 + lr][lf * 16 + hi * 4] = pk;
        }
    }

    f32x4 o[2][4];
    #pragma unroll
    for (int nf = 0; nf < 2; ++nf)
        #pragma unroll
        for (int df = 0; df < 4; ++df) o[nf][df] = (f32x4){0.f, 0.f, 0.f, 0.f};
    #pragma unroll
    for (int ks = 0; ks < 2; ++ks) {
        f16x8 pa[2], bh[4], bl[4];
        #pragma unroll
        for (int nf = 0; nf < 2; ++nf) pa[nf] = *(const f16x8*)&Ps[w * 32 + nf * 16 + lr][ks * 32 + hi * 8];
        #pragma unroll
        for (int df = 0; df < 4; ++df) {
            bh[df] = *(const f16x8*)&Mhi[df * 16 + lr][ks * 32 + hi * 8];
            bl[df] = *(const f16x8*)&Mlo[df * 16 + lr][ks * 32 + hi * 8];
        }
        #pragma unroll
        for (int nf = 0; nf < 2; ++nf)
            #pragma unroll
            for (int df = 0; df < 4; ++df) {
                o[nf][df] = __builtin_amdgcn_mfma_f32_16x16x32_f16(pa[nf], bh[df], o[nf][df], 0, 0, 0);
                o[nf][df] = __builtin_amdgcn_mfma_f32_16x16x32_f16(pa[nf], bl[df], o[nf][df], 0, 0, 0);
            }
    }

    #pragma unroll
    for (int nf = 0; nf < 2; ++nf)
        #pragma unroll
        for (int df = 0; df < 4; ++df)
            #pragma unroll
            for (int j = 0; j < 4; ++j)
                Ps[w * 32 + nf * 16 + hi * 4 + j][df * 16 + lr] = (f16)(o[nf][df][j]);
    __syncthreads();

    #pragma unroll
    for (int i = 0; i < 4; ++i) {
        int id = i * 256 + t, row = id >> 3, c8 = id & 7;
        size_t go = (size_t)(p0 + row) * 512 + h * 64 + c8 * 8;
        f16x8 yv = *(const f16x8*)&Ps[row][c8 * 8];
        f16x8 rv = *(const f16x8*)&resH[go];
        f16x8 sv;
        #pragma unroll
        for (int e = 0; e < 8; ++e) sv[e] = (f16)((float)yv[e] + (float)rv[e]);
        *(f16x8*)&Yh[go] = sv;
    }
}

// ---------------- host launch ----------------
extern "C" void kernel_launch(void* const* d_in, const int* in_sizes, int n_in,
                              void* d_out, int out_size, void* d_ws, size_t ws_size,
                              hipStream_t stream) {
    const float* x    = (const float*)d_in[0];
    const float* Wqkv = (const float*)d_in[1];
    const float* Wout = (const float*)d_in[2];
    const float* bout = (const float*)d_in[3];
    const float* resk = (const float*)d_in[4];
    const int*   labels = (const int*)d_in[5];
    float* out = (float*)d_out;

    char* w = (char*)d_ws;
    size_t off = 0;
    auto alloc = [&](size_t bytes) {
        void* p = w + off;
        off += (bytes + 255) & ~(size_t)255;
        return p;
    };
    f16* xh     = (f16*)alloc((size_t)N_TOK * DIMC * 2);       // sorted
    f16* qkvh   = (f16*)alloc((size_t)N_TOK * QKVC * 2);       // sorted
    f16* WqkvT  = (f16*)alloc((size_t)QKVC * DIMC * 2);
    f16* WoutT  = (f16*)alloc((size_t)DIMC * DIMC * 2);
    f16* Yh     = (f16*)alloc((size_t)N_TOK * DIMC * 2);       // sorted
    int* counts = (int*)alloc(NL * 4);
    int* baseA  = (int*)alloc(NL * 4);
    int* indexA = (int*)alloc((size_t)N_TOK * 4);
    float* ql   = (float*)alloc((size_t)NH * 64 * 64 * 4);
    float* kl   = (float*)alloc((size_t)NH * 64 * 64 * 4);
    f16* qlh    = (f16*)alloc((size_t)NH * 64 * 64 * 2);
    f16* klh    = (f16*)alloc((size_t)NH * 64 * 64 * 2);
    float* a2   = (float*)alloc((size_t)NH * 64 * 64 * 4);
    float* mrow = (float*)alloc(NH * 4);
    float* mcol = (float*)alloc(NH * 4);
    float* zb   = (float*)alloc((size_t)NH * 64 * 64 * 4);
    float* Tb   = (float*)alloc((size_t)NH * 64 * 64 * 4);
    f16* MthHi  = (f16*)alloc((size_t)NH * 64 * 64 * 2);
    f16* MthLo  = (f16*)alloc((size_t)NH * 64 * 64 * 2);
    float* pm   = (float*)alloc((size_t)NH * NCHUNK * 64 * 4);
    float* ps   = (float*)alloc((size_t)NH * NCHUNK * 64 * 4);
    float* pacc = (float*)alloc((size_t)NH * NCHUNK * 64 * 64 * 4);
    f16* resH = (f16*)d_out;  // reuse d_out (64MB) as f16 conv output (32MB); overwritten by final GEMM

    hipMemsetAsync(counts, 0, NL * 4, stream);

    // stable counting sort
    hist_k<<<N_TOK / 256, 256, 0, stream>>>(labels, counts);
    scan_k<<<1, 64, 0, stream>>>(counts, baseA);
    compact_k<<<NL, 256, 0, stream>>>(labels, baseA, indexA);
    // gather+convert x rows into sorted order
    gather_cvt_k<<<N_TOK / 2, 256, 0, stream>>>((const float4*)x, indexA, (f16x4*)xh);
    // weight transposes
    transpose_k<<<dim3(QKVC / 32, DIMC / 32), dim3(32, 8), 0, stream>>>(Wqkv, WqkvT, DIMC, QKVC);
    transpose_k<<<dim3(DIMC / 32, DIMC / 32), dim3(32, 8), 0, stream>>>(Wout, WoutT, DIMC, DIMC);
    // qkv = x_sorted @ Wqkv  (sorted domain)
    gemm_k512<QKVC, false, 6><<<dim3(N_TOK / 128, QKVC / 256), 256, 0, stream>>>(xh, WqkvT, qkvh, nullptr, nullptr);
    // segment pooling (vectorized)
    pool_k<<<NL, 1024, 0, stream>>>(qkvh, baseA, counts, ql, kl, qlh, klh);
    // attn2 + pinv chain (f32)
    attn2_k<<<NH, 256, 0, stream>>>(ql, kl, a2, mrow, mcol);
    pinv_k<<<NH, 256, 0, stream>>>(a2, mrow, mcol, zb);
    // T = softmax(ql@k^T) @ v  (MFMA flash-style)
    attn3_k<<<dim3(NCHUNK, NH), 256, 0, stream>>>(qkvh, qlh, pm, ps, pacc);
    attn3_merge_k<<<dim3(NL, NH), 64, 0, stream>>>(pm, ps, pacc, Tb);
    // M^T (hi+lo f16) = (z @ T)^T
    zmatT_k<<<NH, 256, 0, stream>>>(zb, Tb, MthHi, MthLo);
    // depthwise conv over sorted v (streaming)
    conv_k<<<dim3(N_TOK / 256, NH), 256, 0, stream>>>(qkvh, resk, resH);
    // attn1 (MFMA) + combine -> Yh (sorted)
    attn1_k<<<dim3(N_TOK / 128, NH), 256, 0, stream>>>(qkvh, klh, MthHi, MthLo, resH, Yh);
    // final projection + bias, scatter rows back to original order
    gemm_k512<DIMC, true, 2><<<dim3(N_TOK / 128, DIMC / 256), 256, 0, stream>>>(Yh, WoutT, out, bout, indexA);
}

// Round 7
// 410.264 us; speedup vs baseline: 2.7594x; 1.0027x over previous
//
#include <hip/hip_runtime.h>
#include <hip/hip_bf16.h>

// ---------------- problem constants ----------------
#define N_TOK 32768
#define DIMC  512
#define NH    8
#define DHD   64
#define NL    64
#define KSZ   33
#define QKVC  1536
#define NCHUNK 64   // attn3 chunks; 512 tokens per block

typedef _Float16 f16;
typedef _Float16 f16x8 __attribute__((ext_vector_type(8)));
typedef _Float16 f16x4 __attribute__((ext_vector_type(4)));
typedef float    f32x4 __attribute__((ext_vector_type(4)));

#define GLOAD_LDS16(gp, lp) \
    __builtin_amdgcn_global_load_lds((const __attribute__((address_space(1))) void*)(gp), \
                                     (__attribute__((address_space(3))) void*)(lp), 16, 0, 0)

// ---------------- transpose f32 (R x C) -> f16 (C x R) ----------------
__global__ void transpose_k(const float* __restrict__ W, f16* __restrict__ WT, int R, int C) {
    __shared__ float tile[32][33];
    int bx = blockIdx.x * 32, by = blockIdx.y * 32;
    int tx = threadIdx.x, ty = threadIdx.y;
    #pragma unroll
    for (int i = 0; i < 32; i += 8)
        tile[ty + i][tx] = W[(size_t)(by + ty + i) * C + bx + tx];
    __syncthreads();
    #pragma unroll
    for (int i = 0; i < 32; i += 8)
        WT[(size_t)(bx + ty + i) * R + by + tx] = (f16)tile[tx][ty + i];
}

// ---------------- label histogram ----------------
__global__ void hist_k(const int* __restrict__ labels, int* __restrict__ counts) {
    __shared__ int hloc[NL];
    int t = threadIdx.x;
    if (t < NL) hloc[t] = 0;
    __syncthreads();
    int i = blockIdx.x * 256 + t;
    atomicAdd(&hloc[labels[i]], 1);
    __syncthreads();
    if (t < NL) atomicAdd(&counts[t], hloc[t]);
}

// ---------------- exclusive prefix over 64 counts ----------------
__global__ void scan_k(const int* __restrict__ counts, int* __restrict__ base) {
    if (threadIdx.x == 0) {
        int s = 0;
        for (int l = 0; l < NL; ++l) { base[l] = s; s += counts[l]; }
    }
}

// ---------------- stable compaction: one block per label ----------------
__global__ __launch_bounds__(256) void compact_k(const int* __restrict__ labels,
                                                 const int* __restrict__ base,
                                                 int* __restrict__ indexArr) {
    const int l = blockIdx.x;
    __shared__ int wtot[4];
    __shared__ int s_run;
    int t = threadIdx.x, lane = t & 63, w = t >> 6;
    if (t == 0) s_run = base[l];
    __syncthreads();
    for (int c0 = 0; c0 < N_TOK; c0 += 256) {
        int ii = c0 + t;
        bool flag = (labels[ii] == l);
        unsigned long long mask = __ballot(flag);
        int before = __popcll(mask & ((1ull << lane) - 1ull));
        if (lane == 0) wtot[w] = __popcll(mask);
        __syncthreads();
        int off = 0;
        #pragma unroll
        for (int ww = 0; ww < 4; ++ww) off += (ww < w) ? wtot[ww] : 0;
        int tot = wtot[0] + wtot[1] + wtot[2] + wtot[3];
        int rb = s_run;
        if (flag) indexArr[rb + off + before] = ii;
        __syncthreads();
        if (t == 0) s_run = rb + tot;
    }
}

// ---------------- gather rows of x via index, convert to f16 (sorted domain) ----------------
__global__ __launch_bounds__(256) void gather_cvt_k(const float4* __restrict__ x4,
                                                    const int* __restrict__ indexArr,
                                                    f16x4* __restrict__ xh4) {
    int t = threadIdx.x;
    int row = blockIdx.x * 2 + (t >> 7);
    int c4 = t & 127;
    int j = indexArr[row];
    float4 v = x4[(size_t)j * 128 + c4];
    f16x4 o = { (f16)v.x, (f16)v.y, (f16)v.z, (f16)v.w };
    xh4[(size_t)row * 128 + c4] = o;
}

// ---------------- f16 MFMA GEMM: C[M x BNTOT] = A[M x 512] @ BT[BNTOT x 512]^T ----------------
// tile 128x256, BK=32, 4 waves. T2 chunk-XOR swizzle (source-side for global_load_lds);
// swapped-operand MFMA (vector epilogue); T1 bijective XCD swizzle;
// T4 counted-vmcnt 2-deep pipeline: 2 LDS buffers, 12 loads in flight, vmcnt(6) retires
// only the oldest tile's loads -- the newer tile's DMA stays in flight ACROSS the barrier.
template<int BNTOT, bool OUT_F32, int NY>
__global__ __launch_bounds__(256) void gemm_k512(const f16* __restrict__ A, const f16* __restrict__ BT,
                                                 void* __restrict__ Cout, const float* __restrict__ bias,
                                                 const int* __restrict__ scatterIdx) {
    constexpr int K = 512;
    constexpr int NKT = K / 32;             // 16 K-tiles
    __shared__ f16 As[2][128 * 32];
    __shared__ f16 Bs[2][256 * 32];
    const int t = threadIdx.x;
    const int orig = blockIdx.x + gridDim.x * blockIdx.y;
    constexpr int NWG = 256 * NY;
    constexpr int CPX = NWG / 8;
    const int lin = (orig & 7) * CPX + (orig >> 3);
    const int mBase = (lin / NY) * 128;
    const int nBase = (lin % NY) * 256;
    const int w = t >> 6, lane = t & 63;
    const int lr = lane & 15, lk = lane >> 4;
    const int kc = (lk ^ ((lr >> 1) & 3)) * 8;   // swizzled chunk offset (halves)
    f32x4 acc[8][4];
    #pragma unroll
    for (int m = 0; m < 8; ++m)
        #pragma unroll
        for (int n = 0; n < 4; ++n) acc[m][n] = (f32x4){0.f, 0.f, 0.f, 0.f};

    auto stage = [&](int buf, int kt) {
        #pragma unroll
        for (int r = 0; r < 2; ++r) {
            int id = r * 256 + w * 64 + lane;
            int row = id >> 2, c = id & 3;
            int cg = c ^ ((row >> 1) & 3);
            GLOAD_LDS16(&A[(size_t)(mBase + row) * K + kt * 32 + cg * 8],
                        &As[buf][(size_t)(r * 256 + w * 64) * 8]);
        }
        #pragma unroll
        for (int r = 0; r < 4; ++r) {
            int id = r * 256 + w * 64 + lane;
            int row = id >> 2, c = id & 3;
            int cg = c ^ ((row >> 1) & 3);
            GLOAD_LDS16(&BT[(size_t)(nBase + row) * K + kt * 32 + cg * 8],
                        &Bs[buf][(size_t)(r * 256 + w * 64) * 8]);
        }
    };
    auto compute = [&](int buf) {
        f16x8 af[8], bf[4];
        #pragma unroll
        for (int m = 0; m < 8; ++m) af[m] = *(const f16x8*)&As[buf][(m * 16 + lr) * 32 + kc];
        #pragma unroll
        for (int n = 0; n < 4; ++n) bf[n] = *(const f16x8*)&Bs[buf][(w * 64 + n * 16 + lr) * 32 + kc];
        #pragma unroll
        for (int m = 0; m < 8; ++m)
            #pragma unroll
            for (int n = 0; n < 4; ++n)
                acc[m][n] = __builtin_amdgcn_mfma_f32_16x16x32_f16(bf[n], af[m], acc[m][n], 0, 0, 0);
    };

    // prologue: 2-deep prefetch (12 loads in flight)
    stage(0, 0);
    stage(1, 1);
    int cur = 0;
    for (int kt = 0; kt < NKT; ++kt) {
        if (kt < NKT - 1) {
            // retire only the oldest tile's 6 per-wave loads; next tile's 6 keep flying
            asm volatile("s_waitcnt vmcnt(6)" ::: "memory");
        } else {
            asm volatile("s_waitcnt vmcnt(0)" ::: "memory");
        }
        __builtin_amdgcn_s_barrier();     // all waves' tile-kt DMA landed
        compute(cur);
        __builtin_amdgcn_s_barrier();     // all waves done reading buf[cur]
        if (kt + 2 < NKT) stage(cur, kt + 2);
        cur ^= 1;
    }

    #pragma unroll
    for (int m = 0; m < 8; ++m) {
        int row = mBase + m * 16 + lr;
        int srow = OUT_F32 ? scatterIdx[row] : row;
        #pragma unroll
        for (int n = 0; n < 4; ++n) {
            int col = nBase + w * 64 + n * 16 + lk * 4;
            if constexpr (OUT_F32) {
                float4 bv = *(const float4*)&bias[col];
                float4 sv = make_float4(acc[m][n][0] + bv.x, acc[m][n][1] + bv.y,
                                        acc[m][n][2] + bv.z, acc[m][n][3] + bv.w);
                *(float4*)&((float*)Cout)[(size_t)srow * BNTOT + col] = sv;
            } else {
                f16x4 hv = { (f16)acc[m][n][0], (f16)acc[m][n][1],
                             (f16)acc[m][n][2], (f16)acc[m][n][3] };
                *(f16x4*)&((f16*)Cout)[(size_t)srow * BNTOT + col] = hv;
            }
        }
    }
}

// ---------------- segment-mean pooling (vectorized): sorted q,k -> ql,kl (f32) + qlh,klh (f16) ----------------
__global__ __launch_bounds__(1024) void pool_k(const f16* __restrict__ qkvh,
                                               const int* __restrict__ base, const int* __restrict__ counts,
                                               float* __restrict__ ql, float* __restrict__ kl,
                                               f16* __restrict__ qlh, f16* __restrict__ klh) {
    int l = blockIdx.x;
    int t = threadIdx.x;
    int c = t & 127, rg = t >> 7;
    int b0 = base[l], cnt = counts[l];
    f32x4 a0 = {0.f,0.f,0.f,0.f}, a1 = {0.f,0.f,0.f,0.f};
    for (int p = rg; p < cnt; p += 8) {
        f16x8 v = *(const f16x8*)&qkvh[(size_t)(b0 + p) * QKVC + c * 8];
        a0[0] += (float)v[0]; a0[1] += (float)v[1]; a0[2] += (float)v[2]; a0[3] += (float)v[3];
        a1[0] += (float)v[4]; a1[1] += (float)v[5]; a1[2] += (float)v[6]; a1[3] += (float)v[7];
    }
    __shared__ f32x4 red[8][128][2];
    red[rg][c][0] = a0; red[rg][c][1] = a1;
    __syncthreads();
    if (t < 128) {
        float inv = 1.0f / (float)(cnt > 0 ? cnt : 1);
        f32x4 s0 = {0.f,0.f,0.f,0.f}, s1 = {0.f,0.f,0.f,0.f};
        #pragma unroll
        for (int g = 0; g < 8; ++g) { s0 += red[g][t][0]; s1 += red[g][t][1]; }
        s0 *= inv; s1 *= inv;
        int h = (t & 63) >> 3, d0 = (t & 7) * 8;
        size_t o = ((size_t)(h * 64 + l)) * 64 + d0;
        f16x8 hv;
        #pragma unroll
        for (int e = 0; e < 4; ++e) { hv[e] = (f16)s0[e]; hv[4 + e] = (f16)s1[e]; }
        if (t < 64) {
            *(f32x4*)&ql[o] = s0; *(f32x4*)&ql[o + 4] = s1;
            *(f16x8*)&qlh[o] = hv;
        } else {
            *(f32x4*)&kl[o] = s0; *(f32x4*)&kl[o + 4] = s1;
            *(f16x8*)&klh[o] = hv;
        }
    }
}

// ---------------- attn2 = softmax(ql@kl^T) rows; per-head row/col abs-sum maxes ----------------
__global__ __launch_bounds__(256) void attn2_k(const float* __restrict__ ql, const float* __restrict__ kl,
                                               float* __restrict__ a_out, float* __restrict__ mrow,
                                               float* __restrict__ mcol) {
    int h = blockIdx.x;
    __shared__ float qs[64][65], ks[64][65], a[64][65];
    __shared__ float red[64][4];
    __shared__ float rowv[64], colv[64];
    int t = threadIdx.x;
    for (int idx = t; idx < 4096; idx += 256) {
        int r = idx >> 6, c = idx & 63;
        qs[r][c] = ql[h * 4096 + idx];
        ks[r][c] = kl[h * 4096 + idx];
    }
    __syncthreads();
    int i = t >> 2, q4 = t & 3, j0 = q4 * 16;
    float o[16];
    #pragma unroll
    for (int jj = 0; jj < 16; ++jj) o[jj] = 0.f;
    for (int d = 0; d < 64; ++d) {
        float qv = qs[i][d];
        #pragma unroll
        for (int jj = 0; jj < 16; ++jj) o[jj] += qv * ks[j0 + jj][d];
    }
    float pmx = o[0];
    #pragma unroll
    for (int jj = 1; jj < 16; ++jj) pmx = fmaxf(pmx, o[jj]);
    red[i][q4] = pmx;
    __syncthreads();
    float rm = fmaxf(fmaxf(red[i][0], red[i][1]), fmaxf(red[i][2], red[i][3]));
    float psum = 0.f;
    #pragma unroll
    for (int jj = 0; jj < 16; ++jj) { o[jj] = expf(o[jj] - rm); psum += o[jj]; }
    __syncthreads();
    red[i][q4] = psum;
    __syncthreads();
    float rs = red[i][0] + red[i][1] + red[i][2] + red[i][3];
    float inv = 1.0f / rs;
    #pragma unroll
    for (int jj = 0; jj < 16; ++jj) { o[jj] *= inv; a[i][j0 + jj] = o[jj]; }
    __syncthreads();
    for (int idx = t; idx < 4096; idx += 256) a_out[h * 4096 + idx] = a[idx >> 6][idx & 63];
    float rsum = 0.f;
    #pragma unroll
    for (int jj = 0; jj < 16; ++jj) rsum += o[jj];
    __syncthreads();
    red[i][q4] = rsum;
    __syncthreads();
    if (q4 == 0) rowv[i] = red[i][0] + red[i][1] + red[i][2] + red[i][3];
    float csum = 0.f;
    #pragma unroll
    for (int jj = 0; jj < 16; ++jj) csum += a[j0 + jj][i];
    __syncthreads();
    red[i][q4] = csum;
    __syncthreads();
    if (q4 == 0) colv[i] = red[i][0] + red[i][1] + red[i][2] + red[i][3];
    __syncthreads();
    if (t == 0) {
        float mr = rowv[0], mc = colv[0];
        for (int j = 1; j < 64; ++j) { mr = fmaxf(mr, rowv[j]); mc = fmaxf(mc, colv[j]); }
        mrow[h] = mr; mcol[h] = mc;
    }
}

// 4x4-blocked 64x64 matmul helper (operands in LDS, stride 68)
__device__ __forceinline__ void mm_blk(const float (*X)[68], const float (*Y)[68],
                                       int i0, int j0, float o[4][4]) {
    #pragma unroll
    for (int ii = 0; ii < 4; ++ii)
        #pragma unroll
        for (int jj = 0; jj < 4; ++jj) o[ii][jj] = 0.f;
    for (int k = 0; k < 64; ++k) {
        float4 yv = *(const float4*)&Y[k][j0];
        float x0 = X[i0][k], x1 = X[i0 + 1][k], x2 = X[i0 + 2][k], x3 = X[i0 + 3][k];
        o[0][0] += x0 * yv.x; o[0][1] += x0 * yv.y; o[0][2] += x0 * yv.z; o[0][3] += x0 * yv.w;
        o[1][0] += x1 * yv.x; o[1][1] += x1 * yv.y; o[1][2] += x1 * yv.z; o[1][3] += x1 * yv.w;
        o[2][0] += x2 * yv.x; o[2][1] += x2 * yv.y; o[2][2] += x2 * yv.z; o[2][3] += x2 * yv.w;
        o[3][0] += x3 * yv.x; o[3][1] += x3 * yv.y; o[3][2] += x3 * yv.z; o[3][3] += x3 * yv.w;
    }
}

// ---------------- Newton-Schulz pinv (6 iters, f32, per head) ----------------
__global__ __launch_bounds__(256) void pinv_k(const float* __restrict__ a_g, const float* __restrict__ mrow,
                                              const float* __restrict__ mcol, float* __restrict__ z_g) {
    int h = blockIdx.x;
    __shared__ float a[64][68], z[64][68], C[64][68], D[64][68], E[64][68];
    int t = threadIdx.x;
    float mr = mrow[0], mc = mcol[0];
    #pragma unroll
    for (int k = 1; k < 8; ++k) { mr = fmaxf(mr, mrow[k]); mc = fmaxf(mc, mcol[k]); }
    float inv0 = 1.0f / (mr * mc);
    for (int idx = t; idx < 4096; idx += 256) {
        int r = idx >> 6, c = idx & 63;
        float av = a_g[h * 4096 + idx];
        a[r][c] = av;
        z[c][r] = av * inv0;
    }
    __syncthreads();
    int i0 = (t >> 4) * 4, j0 = (t & 15) * 4;
    float o[4][4];
    for (int it = 0; it < 6; ++it) {
        mm_blk(a, z, i0, j0, o);
        #pragma unroll
        for (int ii = 0; ii < 4; ++ii)
            #pragma unroll
            for (int jj = 0; jj < 4; ++jj) C[i0 + ii][j0 + jj] = o[ii][jj];
        __syncthreads();
        mm_blk(C, C, i0, j0, o);
        #pragma unroll
        for (int ii = 0; ii < 4; ++ii)
            #pragma unroll
            for (int jj = 0; jj < 4; ++jj) D[i0 + ii][j0 + jj] = 7.f * C[i0 + ii][j0 + jj] - o[ii][jj];
        __syncthreads();
        mm_blk(C, D, i0, j0, o);
        #pragma unroll
        for (int ii = 0; ii < 4; ++ii)
            #pragma unroll
            for (int jj = 0; jj < 4; ++jj) E[i0 + ii][j0 + jj] = 15.f * C[i0 + ii][j0 + jj] - o[ii][jj];
        __syncthreads();
        mm_blk(z, E, i0, j0, o);
        #pragma unroll
        for (int ii = 0; ii < 4; ++ii)
            #pragma unroll
            for (int jj = 0; jj < 4; ++jj) D[i0 + ii][j0 + jj] = 0.25f * (13.f * z[i0 + ii][j0 + jj] - o[ii][jj]);
        __syncthreads();
        #pragma unroll
        for (int ii = 0; ii < 4; ++ii)
            #pragma unroll
            for (int jj = 0; jj < 4; ++jj) z[i0 + ii][j0 + jj] = D[i0 + ii][j0 + jj];
        __syncthreads();
    }
    for (int idx = t; idx < 4096; idx += 256) z_g[h * 4096 + idx] = z[idx >> 6][idx & 63];
}

// ---------------- attn3 @ v via MFMA: flash-style online softmax, per-block partials ----------------
__global__ __launch_bounds__(256) void attn3_k(const f16* __restrict__ qkvh, const f16* __restrict__ qlh,
                                               float* __restrict__ pm, float* __restrict__ ps,
                                               float* __restrict__ pacc) {
    const int cx = blockIdx.x, h = blockIdx.y;
    const int t = threadIdx.x;
    const int w = t >> 6, lane = t & 63;
    const int lr = lane & 15, hi = lane >> 4;
    __shared__ f16 Qls[64 * 64];
    __shared__ f16 Ks[64 * 64];
    __shared__ f16 vT[64 * 72];
    __shared__ f16 Ps[64 * 72];
    __shared__ float fsh[64];

    #pragma unroll
    for (int pss = 0; pss < 2; ++pss) {
        int q = pss * 256 + t;
        int r = q >> 3, cs = (q & 7) ^ (r & 7);
        GLOAD_LDS16(&qlh[(size_t)h * 4096 + r * 64 + cs * 8], &Qls[(size_t)(pss * 256 + w * 64) * 8]);
    }
    float m_reg = -1e30f, s_reg = 0.f;
    f32x4 accT[4];
    #pragma unroll
    for (int lf = 0; lf < 4; ++lf) accT[lf] = (f32x4){0.f, 0.f, 0.f, 0.f};

    const int vk8 = t & 7, vnn = t >> 3;

    for (int sub = 0; sub < 8; ++sub) {
        const int n0 = cx * 512 + sub * 64;
        __syncthreads();
        #pragma unroll
        for (int pss = 0; pss < 2; ++pss) {
            int q = pss * 256 + t;
            int r = q >> 3, cs = (q & 7) ^ (r & 7);
            GLOAD_LDS16(&qkvh[(size_t)(n0 + r) * QKVC + 512 + h * 64 + cs * 8],
                        &Ks[(size_t)(pss * 256 + w * 64) * 8]);
        }
        #pragma unroll
        for (int p2 = 0; p2 < 2; ++p2) {
            int n = vnn + 32 * p2;
            f16x8 rv = *(const f16x8*)&qkvh[(size_t)(n0 + n) * QKVC + 1024 + h * 64 + vk8 * 8];
            #pragma unroll
            for (int i = 0; i < 8; ++i) {
                int e = i ^ vk8;
                vT[(vk8 * 8 + e) * 72 + n] = rv[e];
            }
        }
        __syncthreads();
        f32x4 c[4];
        #pragma unroll
        for (int kf = 0; kf < 4; ++kf) c[kf] = (f32x4){0.f, 0.f, 0.f, 0.f};
        const int lq = w * 16 + lr;
        #pragma unroll
        for (int ks = 0; ks < 2; ++ks) {
            f16x8 bf = *(const f16x8*)&Qls[lq * 64 + (((ks * 4 + hi) ^ (lq & 7)) * 8)];
            #pragma unroll
            for (int kf = 0; kf < 4; ++kf) {
                int rn = kf * 16 + lr;
                f16x8 af = *(const f16x8*)&Ks[rn * 64 + (((ks * 4 + hi) ^ (rn & 7)) * 8)];
                c[kf] = __builtin_amdgcn_mfma_f32_16x16x32_f16(af, bf, c[kf], 0, 0, 0);
            }
        }
        float tmax = -1e30f;
        #pragma unroll
        for (int kf = 0; kf < 4; ++kf)
            #pragma unroll
            for (int j = 0; j < 4; ++j) tmax = fmaxf(tmax, c[kf][j]);
        tmax = fmaxf(tmax, __shfl_xor(tmax, 16));
        tmax = fmaxf(tmax, __shfl_xor(tmax, 32));
        float newm = fmaxf(m_reg, tmax);
        float fct = __expf(m_reg - newm);
        float psum = 0.f;
        #pragma unroll
        for (int kf = 0; kf < 4; ++kf) {
            f16x4 pk;
            #pragma unroll
            for (int j = 0; j < 4; ++j) {
                float e = __expf(c[kf][j] - newm);
                psum += e;
                pk[j] = (f16)e;
            }
            *(f16x4*)&Ps[lq * 72 + kf * 16 + hi * 4] = pk;
        }
        psum += __shfl_xor(psum, 16);
        psum += __shfl_xor(psum, 32);
        s_reg = s_reg * fct + psum;
        m_reg = newm;
        if (hi == 0) fsh[lq] = fct;
        __syncthreads();
        #pragma unroll
        for (int lf = 0; lf < 4; ++lf) {
            f32x4 fr = *(const f32x4*)&fsh[lf * 16 + hi * 4];
            accT[lf] *= fr;
        }
        #pragma unroll
        for (int ks = 0; ks < 2; ++ks) {
            f16x8 bf = *(const f16x8*)&vT[(w * 16 + lr) * 72 + ks * 32 + hi * 8];
            #pragma unroll
            for (int lf = 0; lf < 4; ++lf) {
                f16x8 af = *(const f16x8*)&Ps[(lf * 16 + lr) * 72 + ks * 32 + hi * 8];
                accT[lf] = __builtin_amdgcn_mfma_f32_16x16x32_f16(af, bf, accT[lf], 0, 0, 0);
            }
        }
    }
    int part = h * NCHUNK + cx;
    if (hi == 0) {
        pm[part * 64 + w * 16 + lr] = m_reg;
        ps[part * 64 + w * 16 + lr] = s_reg;
    }
    #pragma unroll
    for (int lf = 0; lf < 4; ++lf)
        #pragma unroll
        for (int j = 0; j < 4; ++j)
            pacc[((size_t)part * 64 + (lf * 16 + hi * 4 + j)) * 64 + (w * 16 + lr)] = accT[lf][j];
}

// ---------------- merge attn3 partials -> T[h][l][d] ----------------
__global__ void attn3_merge_k(const float* __restrict__ pm, const float* __restrict__ ps,
                              const float* __restrict__ pacc, float* __restrict__ T) {
    int l = blockIdx.x, h = blockIdx.y, d = threadIdx.x;
    float m = -1e30f;
    for (int c = 0; c < NCHUNK; ++c) m = fmaxf(m, pm[(h * NCHUNK + c) * 64 + l]);
    float s = 0.f, a = 0.f;
    for (int c = 0; c < NCHUNK; ++c) {
        float wgt = __expf(pm[(h * NCHUNK + c) * 64 + l] - m);
        s += ps[(h * NCHUNK + c) * 64 + l] * wgt;
        a += pacc[((size_t)(h * NCHUNK + c) * 64 + l) * 64 + d] * wgt;
    }
    T[(h * 64 + l) * 64 + d] = a / s;
}

// ---------------- M = z @ T per head; emit M^T split into f16 hi+lo ----------------
__global__ __launch_bounds__(256) void zmatT_k(const float* __restrict__ z_g, const float* __restrict__ T,
                                               f16* __restrict__ MthHi, f16* __restrict__ MthLo) {
    int h = blockIdx.x;
    __shared__ float zs[64][68], Ts[64][68];
    int t = threadIdx.x;
    for (int idx = t; idx < 4096; idx += 256) {
        int r = idx >> 6, c = idx & 63;
        zs[r][c] = z_g[h * 4096 + idx];
        Ts[r][c] = T[h * 4096 + idx];
    }
    __syncthreads();
    int i0 = (t >> 4) * 4, j0 = (t & 15) * 4;
    float o[4][4];
    mm_blk(zs, Ts, i0, j0, o);
    #pragma unroll
    for (int ii = 0; ii < 4; ++ii)
        #pragma unroll
        for (int jj = 0; jj < 4; ++jj) {
            float mv = o[ii][jj];
            f16 hiv = (f16)mv;
            f16 lov = (f16)(mv - (float)hiv);
            MthHi[h * 4096 + (j0 + jj) * 64 + (i0 + ii)] = hiv;
            MthLo[h * 4096 + (j0 + jj) * 64 + (i0 + ii)] = lov;
        }
}

// ---------------- depthwise conv over sorted v (streaming) -> resH (f16) ----------------
__global__ __launch_bounds__(256) void conv_k(const f16* __restrict__ qkvh,
                                              const float* __restrict__ resk, f16* __restrict__ resH) {
    int h = blockIdx.y;
    int p0 = blockIdx.x * 256;
    __shared__ f16 vt[288][72];
    int t = threadIdx.x;
    for (int id = t; id < 288 * 8; id += 256) {
        int rr = id >> 3, c = id & 7;
        int pg = p0 - 16 + rr;
        int4 v = {0, 0, 0, 0};
        if (pg >= 0 && pg < N_TOK)
            v = *(const int4*)&qkvh[(size_t)pg * QKVC + 1024 + h * 64 + c * 8];
        *(int4*)&vt[rr][c * 8] = v;
    }
    float wk[KSZ];
    #pragma unroll
    for (int k = 0; k < KSZ; ++k) wk[k] = resk[h * KSZ + k];
    __syncthreads();
    int d = t & 63, pg4 = t >> 6;
    float col[96];
    #pragma unroll
    for (int i2 = 0; i2 < 96; ++i2) col[i2] = (float)vt[pg4 * 64 + i2][d];
    #pragma unroll
    for (int pp = 0; pp < 64; ++pp) {
        float acc = 0.f;
        #pragma unroll
        for (int k = 0; k < KSZ; ++k) acc += wk[k] * col[pp + k];
        resH[(size_t)(p0 + pg4 * 64 + pp) * 512 + h * 64 + d] = (f16)acc;
    }
}

// ---------------- attn1 via MFMA: softmax(Q@kl^T) @ M + residual -> Yh ----------------
__global__ __launch_bounds__(256) void attn1_k(const f16* __restrict__ qkvh, const f16* __restrict__ klh,
                                               const f16* __restrict__ MthHi, const f16* __restrict__ MthLo,
                                               const f16* __restrict__ resH, f16* __restrict__ Yh) {
    const int h = blockIdx.y;
    const int p0 = blockIdx.x * 128;
    const int t = threadIdx.x;
    const int w = t >> 6, lane = t & 63;
    const int lr = lane & 15, hi = lane >> 4;
    __shared__ f16 Qs[128][72];
    __shared__ f16 Ks[64][72];
    __shared__ f16 Mhi[64][72];
    __shared__ f16 Mlo[64][72];
    __shared__ f16 Ps[128][72];

    #pragma unroll
    for (int i = 0; i < 4; ++i) {
        int id = i * 256 + t, row = id >> 3, c8 = id & 7;
        *(f16x8*)&Qs[row][c8 * 8] = *(const f16x8*)&qkvh[(size_t)(p0 + row) * QKVC + h * 64 + c8 * 8];
    }
    #pragma unroll
    for (int i = 0; i < 2; ++i) {
        int id = i * 256 + t, row = id >> 3, c8 = id & 7;
        *(f16x8*)&Ks[row][c8 * 8]  = *(const f16x8*)&klh[h * 4096 + id * 8];
        *(f16x8*)&Mhi[row][c8 * 8] = *(const f16x8*)&MthHi[h * 4096 + id * 8];
        *(f16x8*)&Mlo[row][c8 * 8] = *(const f16x8*)&MthLo[h * 4096 + id * 8];
    }
    __syncthreads();

    f32x4 c[4][2];
    #pragma unroll
    for (int lf = 0; lf < 4; ++lf)
        #pragma unroll
        for (int nf = 0; nf < 2; ++nf) c[lf][nf] = (f32x4){0.f, 0.f, 0.f, 0.f};
    #pragma unroll
    for (int ks = 0; ks < 2; ++ks) {
        f16x8 af[4], bf[2];
        #pragma unroll
        for (int lf = 0; lf < 4; ++lf) af[lf] = *(const f16x8*)&Ks[lf * 16 + lr][ks * 32 + hi * 8];
        #pragma unroll
        for (int nf = 0; nf < 2; ++nf) bf[nf] = *(const f16x8*)&Qs[w * 32 + nf * 16 + lr][ks * 32 + hi * 8];
        #pragma unroll
        for (int lf = 0; lf < 4; ++lf)
            #pragma unroll
            for (int nf = 0; nf < 2; ++nf)
                c[lf][nf] = __builtin_amdgcn_mfma_f32_16x16x32_f16(af[lf], bf[nf], c[lf][nf], 0, 0, 0);
    }

    #pragma unroll
    for (int nf = 0; nf < 2; ++nf) {
        float m = -1e30f;
        #pragma unroll
        for (int lf = 0; lf < 4; ++lf)
            #pragma unroll
            for (int j = 0; j < 4; ++j) m = fmaxf(m, c[lf][nf][j]);
        m = fmaxf(m, __shfl_xor(m, 16));
        m = fmaxf(m, __shfl_xor(m, 32));
        float s = 0.f;
        #pragma unroll
        for (int lf = 0; lf < 4; ++lf)
            #pragma unroll
            for (int j = 0; j < 4; ++j) { float e = __expf(c[lf][nf][j] - m); c[lf][nf][j] = e; s += e; }
        s += __shfl_xor(s, 16);
        s += __shfl_xor(s, 32);
        float inv = 1.0f / s;
        #pragma unroll
        for (int lf = 0; lf < 4; ++lf) {
            f16x4 pk;
            #pragma unroll
            for (int j = 0; j < 4; ++j) pk[j] = (f16)(c[lf][nf][j] * inv);
            *(f16x4*)&Ps[w * 32 + nf * 16 + lr][lf * 16 + hi * 4] = pk;
        }
    }

    f32x4 o[2][4];
    #pragma unroll
    for (int nf = 0; nf < 2; ++nf)
        #pragma unroll
        for (int df = 0; df < 4; ++df) o[nf][df] = (f32x4){0.f, 0.f, 0.f, 0.f};
    #pragma unroll
    for (int ks = 0; ks < 2; ++ks) {
        f16x8 pa[2], bh[4], bl[4];
        #pragma unroll
        for (int nf = 0; nf < 2; ++nf) pa[nf] = *(const f16x8*)&Ps[w * 32 + nf * 16 + lr][ks * 32 + hi * 8];
        #pragma unroll
        for (int df = 0; df < 4; ++df) {
            bh[df] = *(const f16x8*)&Mhi[df * 16 + lr][ks * 32 + hi * 8];
            bl[df] = *(const f16x8*)&Mlo[df * 16 + lr][ks * 32 + hi * 8];
        }
        #pragma unroll
        for (int nf = 0; nf < 2; ++nf)
            #pragma unroll
            for (int df = 0; df < 4; ++df) {
                o[nf][df] = __builtin_amdgcn_mfma_f32_16x16x32_f16(pa[nf], bh[df], o[nf][df], 0, 0, 0);
                o[nf][df] = __builtin_amdgcn_mfma_f32_16x16x32_f16(pa[nf], bl[df], o[nf][df], 0, 0, 0);
            }
    }

    #pragma unroll
    for (int nf = 0; nf < 2; ++nf)
        #pragma unroll
        for (int df = 0; df < 4; ++df)
            #pragma unroll
            for (int j = 0; j < 4; ++j)
                Ps[w * 32 + nf * 16 + hi * 4 + j][df * 16 + lr] = (f16)(o[nf][df][j]);
    __syncthreads();

    #pragma unroll
    for (int i = 0; i < 4; ++i) {
        int id = i * 256 + t, row = id >> 3, c8 = id & 7;
        size_t go = (size_t)(p0 + row) * 512 + h * 64 + c8 * 8;
        f16x8 yv = *(const f16x8*)&Ps[row][c8 * 8];
        f16x8 rv = *(const f16x8*)&resH[go];
        f16x8 sv;
        #pragma unroll
        for (int e = 0; e < 8; ++e) sv[e] = (f16)((float)yv[e] + (float)rv[e]);
        *(f16x8*)&Yh[go] = sv;
    }
}

// ---------------- host launch ----------------
extern "C" void kernel_launch(void* const* d_in, const int* in_sizes, int n_in,
                              void* d_out, int out_size, void* d_ws, size_t ws_size,
                              hipStream_t stream) {
    const float* x    = (const float*)d_in[0];
    const float* Wqkv = (const float*)d_in[1];
    const float* Wout = (const float*)d_in[2];
    const float* bout = (const float*)d_in[3];
    const float* resk = (const float*)d_in[4];
    const int*   labels = (const int*)d_in[5];
    float* out = (float*)d_out;

    char* w = (char*)d_ws;
    size_t off = 0;
    auto alloc = [&](size_t bytes) {
        void* p = w + off;
        off += (bytes + 255) & ~(size_t)255;
        return p;
    };
    f16* xh     = (f16*)alloc((size_t)N_TOK * DIMC * 2);       // sorted
    f16* qkvh   = (f16*)alloc((size_t)N_TOK * QKVC * 2);       // sorted
    f16* WqkvT  = (f16*)alloc((size_t)QKVC * DIMC * 2);
    f16* WoutT  = (f16*)alloc((size_t)DIMC * DIMC * 2);
    f16* Yh     = (f16*)alloc((size_t)N_TOK * DIMC * 2);       // sorted
    int* counts = (int*)alloc(NL * 4);
    int* baseA  = (int*)alloc(NL * 4);
    int* indexA = (int*)alloc((size_t)N_TOK * 4);
    float* ql   = (float*)alloc((size_t)NH * 64 * 64 * 4);
    float* kl   = (float*)alloc((size_t)NH * 64 * 64 * 4);
    f16* qlh    = (f16*)alloc((size_t)NH * 64 * 64 * 2);
    f16* klh    = (f16*)alloc((size_t)NH * 64 * 64 * 2);
    float* a2   = (float*)alloc((size_t)NH * 64 * 64 * 4);
    float* mrow = (float*)alloc(NH * 4);
    float* mcol = (float*)alloc(NH * 4);
    float* zb   = (float*)alloc((size_t)NH * 64 * 64 * 4);
    float* Tb   = (float*)alloc((size_t)NH * 64 * 64 * 4);
    f16* MthHi  = (f16*)alloc((size_t)NH * 64 * 64 * 2);
    f16* MthLo  = (f16*)alloc((size_t)NH * 64 * 64 * 2);
    float* pm   = (float*)alloc((size_t)NH * NCHUNK * 64 * 4);
    float* ps   = (float*)alloc((size_t)NH * NCHUNK * 64 * 4);
    float* pacc = (float*)alloc((size_t)NH * NCHUNK * 64 * 64 * 4);
    f16* resH = (f16*)d_out;  // reuse d_out (64MB) as f16 conv output (32MB); overwritten by final GEMM

    hipMemsetAsync(counts, 0, NL * 4, stream);

    // stable counting sort
    hist_k<<<N_TOK / 256, 256, 0, stream>>>(labels, counts);
    scan_k<<<1, 64, 0, stream>>>(counts, baseA);
    compact_k<<<NL, 256, 0, stream>>>(labels, baseA, indexA);
    // gather+convert x rows into sorted order
    gather_cvt_k<<<N_TOK / 2, 256, 0, stream>>>((const float4*)x, indexA, (f16x4*)xh);
    // weight transposes
    transpose_k<<<dim3(QKVC / 32, DIMC / 32), dim3(32, 8), 0, stream>>>(Wqkv, WqkvT, DIMC, QKVC);
    transpose_k<<<dim3(DIMC / 32, DIMC / 32), dim3(32, 8), 0, stream>>>(Wout, WoutT, DIMC, DIMC);
    // qkv = x_sorted @ Wqkv  (sorted domain)
    gemm_k512<QKVC, false, 6><<<dim3(N_TOK / 128, QKVC / 256), 256, 0, stream>>>(xh, WqkvT, qkvh, nullptr, nullptr);
    // segment pooling (vectorized)
    pool_k<<<NL, 1024, 0, stream>>>(qkvh, baseA, counts, ql, kl, qlh, klh);
    // attn2 + pinv chain (f32)
    attn2_k<<<NH, 256, 0, stream>>>(ql, kl, a2, mrow, mcol);
    pinv_k<<<NH, 256, 0, stream>>>(a2, mrow, mcol, zb);
    // T = softmax(ql@k^T) @ v  (MFMA flash-style)
    attn3_k<<<dim3(NCHUNK, NH), 256, 0, stream>>>(qkvh, qlh, pm, ps, pacc);
    attn3_merge_k<<<dim3(NL, NH), 64, 0, stream>>>(pm, ps, pacc, Tb);
    // M^T (hi+lo f16) = (z @ T)^T
    zmatT_k<<<NH, 256, 0, stream>>>(zb, Tb, MthHi, MthLo);
    // depthwise conv over sorted v (streaming)
    conv_k<<<dim3(N_TOK / 256, NH), 256, 0, stream>>>(qkvh, resk, resH);
    // attn1 (MFMA) + combine -> Yh (sorted)
    attn1_k<<<dim3(N_TOK / 128, NH), 256, 0, stream>>>(qkvh, klh, MthHi, MthLo, resH, Yh);
    // final projection + bias, scatter rows back to original order
    gemm_k512<DIMC, true, 2><<<dim3(N_TOK / 128, DIMC / 256), 256, 0, stream>>>(Yh, WoutT, out, bout, indexA);
}

// Round 8
// 385.691 us; speedup vs baseline: 2.9352x; 1.0637x over previous
//
#include <hip/hip_runtime.h>
#include <hip/hip_bf16.h>

// ---------------- problem constants ----------------
#define N_TOK 32768
#define DIMC  512
#define NH    8
#define DHD   64
#define NL    64
#define KSZ   33
#define QKVC  1536
#define NCHUNK 64   // attn3 chunks; 512 tokens per block

typedef _Float16 f16;
typedef _Float16 f16x8 __attribute__((ext_vector_type(8)));
typedef _Float16 f16x4 __attribute__((ext_vector_type(4)));
typedef float    f32x4 __attribute__((ext_vector_type(4)));

#define GLOAD_LDS16(gp, lp) \
    __builtin_amdgcn_global_load_lds((const __attribute__((address_space(1))) void*)(gp), \
                                     (__attribute__((address_space(3))) void*)(lp), 16, 0, 0)

// ---------------- transpose f32 (R x C) -> f16 (C x R) ----------------
__global__ void transpose_k(const float* __restrict__ W, f16* __restrict__ WT, int R, int C) {
    __shared__ float tile[32][33];
    int bx = blockIdx.x * 32, by = blockIdx.y * 32;
    int tx = threadIdx.x, ty = threadIdx.y;
    #pragma unroll
    for (int i = 0; i < 32; i += 8)
        tile[ty + i][tx] = W[(size_t)(by + ty + i) * C + bx + tx];
    __syncthreads();
    #pragma unroll
    for (int i = 0; i < 32; i += 8)
        WT[(size_t)(bx + ty + i) * R + by + tx] = (f16)tile[tx][ty + i];
}

// ---------------- label histogram ----------------
__global__ void hist_k(const int* __restrict__ labels, int* __restrict__ counts) {
    __shared__ int hloc[NL];
    int t = threadIdx.x;
    if (t < NL) hloc[t] = 0;
    __syncthreads();
    int i = blockIdx.x * 256 + t;
    atomicAdd(&hloc[labels[i]], 1);
    __syncthreads();
    if (t < NL) atomicAdd(&counts[t], hloc[t]);
}

// ---------------- exclusive prefix over 64 counts ----------------
__global__ void scan_k(const int* __restrict__ counts, int* __restrict__ base) {
    if (threadIdx.x == 0) {
        int s = 0;
        for (int l = 0; l < NL; ++l) { base[l] = s; s += counts[l]; }
    }
}

// ---------------- stable compaction: one block per label ----------------
__global__ __launch_bounds__(256) void compact_k(const int* __restrict__ labels,
                                                 const int* __restrict__ base,
                                                 int* __restrict__ indexArr) {
    const int l = blockIdx.x;
    __shared__ int wtot[4];
    __shared__ int s_run;
    int t = threadIdx.x, lane = t & 63, w = t >> 6;
    if (t == 0) s_run = base[l];
    __syncthreads();
    for (int c0 = 0; c0 < N_TOK; c0 += 256) {
        int ii = c0 + t;
        bool flag = (labels[ii] == l);
        unsigned long long mask = __ballot(flag);
        int before = __popcll(mask & ((1ull << lane) - 1ull));
        if (lane == 0) wtot[w] = __popcll(mask);
        __syncthreads();
        int off = 0;
        #pragma unroll
        for (int ww = 0; ww < 4; ++ww) off += (ww < w) ? wtot[ww] : 0;
        int tot = wtot[0] + wtot[1] + wtot[2] + wtot[3];
        int rb = s_run;
        if (flag) indexArr[rb + off + before] = ii;
        __syncthreads();
        if (t == 0) s_run = rb + tot;
    }
}

// ---------------- gather rows of x via index, convert to f16 (sorted domain) ----------------
__global__ __launch_bounds__(256) void gather_cvt_k(const float4* __restrict__ x4,
                                                    const int* __restrict__ indexArr,
                                                    f16x4* __restrict__ xh4) {
    int t = threadIdx.x;
    int row = blockIdx.x * 2 + (t >> 7);
    int c4 = t & 127;
    int j = indexArr[row];
    float4 v = x4[(size_t)j * 128 + c4];
    f16x4 o = { (f16)v.x, (f16)v.y, (f16)v.z, (f16)v.w };
    xh4[(size_t)row * 128 + c4] = o;
}

// ---------------- f16 MFMA GEMM: C[M x BNTOT] = A[M x 512] @ BT[BNTOT x 512]^T ----------------
// tile 128x256, BK=32, 8 waves x 64 threads (512/block). Wave w owns cols [w*32, w*32+32).
// Per-wave acc = 8x2 frags = 64 VGPR -> total <=128 VGPR (occupancy cliff at 128: m69),
// giving 16 waves/CU (4/SIMD) vs the 132-VGPR 8-wave ceiling of previous rounds.
// T2 chunk-XOR swizzle (source-side), T1 bijective XCD swizzle, swapped-operand epilogue,
// T4 counted-vmcnt 2-deep pipeline (3 DMA/wave/stage -> vmcnt(3)).
template<int BNTOT, bool OUT_F32, int NY>
__global__ __launch_bounds__(512, 4) void gemm_k512(const f16* __restrict__ A, const f16* __restrict__ BT,
                                                    void* __restrict__ Cout, const float* __restrict__ bias,
                                                    const int* __restrict__ scatterIdx) {
    constexpr int K = 512;
    constexpr int NKT = K / 32;             // 16 K-tiles
    __shared__ f16 As[2][128 * 32];         // 16 KB
    __shared__ f16 Bs[2][256 * 32];         // 32 KB
    const int t = threadIdx.x;
    const int orig = blockIdx.x + gridDim.x * blockIdx.y;
    constexpr int NWG = 256 * NY;           // gridDim.x == 256 (N_TOK/128)
    constexpr int CPX = NWG / 8;
    const int lin = (orig & 7) * CPX + (orig >> 3);
    const int mBase = (lin / NY) * 128;
    const int nBase = (lin % NY) * 256;
    const int w = t >> 6, lane = t & 63;
    const int lr = lane & 15, lk = lane >> 4;
    const int kc = (lk ^ ((lr >> 1) & 3)) * 8;   // swizzled chunk offset (halves)
    f32x4 acc[8][2];
    #pragma unroll
    for (int m = 0; m < 8; ++m)
        #pragma unroll
        for (int n = 0; n < 2; ++n) acc[m][n] = (f32x4){0.f, 0.f, 0.f, 0.f};

    auto stage = [&](int buf, int kt) {
        // A: 512 chunks of 16B (128 rows x 4 slots); one round over 512 threads
        {
            int id = t;
            int row = id >> 2, c = id & 3;
            int cg = c ^ ((row >> 1) & 3);
            GLOAD_LDS16(&A[(size_t)(mBase + row) * K + kt * 32 + cg * 8],
                        &As[buf][(size_t)(w * 64) * 8]);
        }
        // B: 1024 chunks; two rounds
        #pragma unroll
        for (int r = 0; r < 2; ++r) {
            int id = r * 512 + t;
            int row = id >> 2, c = id & 3;
            int cg = c ^ ((row >> 1) & 3);
            GLOAD_LDS16(&BT[(size_t)(nBase + row) * K + kt * 32 + cg * 8],
                        &Bs[buf][(size_t)(r * 512 + w * 64) * 8]);
        }
    };
    auto compute = [&](int buf) {
        f16x8 af[8], bf[2];
        #pragma unroll
        for (int m = 0; m < 8; ++m) af[m] = *(const f16x8*)&As[buf][(m * 16 + lr) * 32 + kc];
        #pragma unroll
        for (int n = 0; n < 2; ++n) bf[n] = *(const f16x8*)&Bs[buf][(w * 32 + n * 16 + lr) * 32 + kc];
        // swapped operands: lane element j -> C col = nBase + w*32 + n*16 + lk*4 + j,
        // C row = mBase + m*16 + lr
        #pragma unroll
        for (int m = 0; m < 8; ++m)
            #pragma unroll
            for (int n = 0; n < 2; ++n)
                acc[m][n] = __builtin_amdgcn_mfma_f32_16x16x32_f16(bf[n], af[m], acc[m][n], 0, 0, 0);
    };

    // prologue: 2-deep prefetch (6 loads/wave in flight)
    stage(0, 0);
    stage(1, 1);
    int cur = 0;
    for (int kt = 0; kt < NKT; ++kt) {
        if (kt < NKT - 1) {
            asm volatile("s_waitcnt vmcnt(3)" ::: "memory");   // retire oldest tile's 3/wave
        } else {
            asm volatile("s_waitcnt vmcnt(0)" ::: "memory");
        }
        __builtin_amdgcn_s_barrier();     // tile-kt fully in LDS
        compute(cur);
        __builtin_amdgcn_s_barrier();     // all waves done reading buf[cur]
        if (kt + 2 < NKT) stage(cur, kt + 2);
        cur ^= 1;
    }

    #pragma unroll
    for (int m = 0; m < 8; ++m) {
        int row = mBase + m * 16 + lr;
        int srow = OUT_F32 ? scatterIdx[row] : row;
        #pragma unroll
        for (int n = 0; n < 2; ++n) {
            int col = nBase + w * 32 + n * 16 + lk * 4;
            if constexpr (OUT_F32) {
                float4 bv = *(const float4*)&bias[col];
                float4 sv = make_float4(acc[m][n][0] + bv.x, acc[m][n][1] + bv.y,
                                        acc[m][n][2] + bv.z, acc[m][n][3] + bv.w);
                *(float4*)&((float*)Cout)[(size_t)srow * BNTOT + col] = sv;
            } else {
                f16x4 hv = { (f16)acc[m][n][0], (f16)acc[m][n][1],
                             (f16)acc[m][n][2], (f16)acc[m][n][3] };
                *(f16x4*)&((f16*)Cout)[(size_t)srow * BNTOT + col] = hv;
            }
        }
    }
}

// ---------------- segment-mean pooling (vectorized): sorted q,k -> ql,kl (f32) + qlh,klh (f16) ----------------
__global__ __launch_bounds__(1024) void pool_k(const f16* __restrict__ qkvh,
                                               const int* __restrict__ base, const int* __restrict__ counts,
                                               float* __restrict__ ql, float* __restrict__ kl,
                                               f16* __restrict__ qlh, f16* __restrict__ klh) {
    int l = blockIdx.x;
    int t = threadIdx.x;
    int c = t & 127, rg = t >> 7;
    int b0 = base[l], cnt = counts[l];
    f32x4 a0 = {0.f,0.f,0.f,0.f}, a1 = {0.f,0.f,0.f,0.f};
    for (int p = rg; p < cnt; p += 8) {
        f16x8 v = *(const f16x8*)&qkvh[(size_t)(b0 + p) * QKVC + c * 8];
        a0[0] += (float)v[0]; a0[1] += (float)v[1]; a0[2] += (float)v[2]; a0[3] += (float)v[3];
        a1[0] += (float)v[4]; a1[1] += (float)v[5]; a1[2] += (float)v[6]; a1[7 - 7] += 0.f; a1[3] += (float)v[7];
    }
    __shared__ f32x4 red[8][128][2];
    red[rg][c][0] = a0; red[rg][c][1] = a1;
    __syncthreads();
    if (t < 128) {
        float inv = 1.0f / (float)(cnt > 0 ? cnt : 1);
        f32x4 s0 = {0.f,0.f,0.f,0.f}, s1 = {0.f,0.f,0.f,0.f};
        #pragma unroll
        for (int g = 0; g < 8; ++g) { s0 += red[g][t][0]; s1 += red[g][t][1]; }
        s0 *= inv; s1 *= inv;
        int h = (t & 63) >> 3, d0 = (t & 7) * 8;
        size_t o = ((size_t)(h * 64 + l)) * 64 + d0;
        f16x8 hv;
        #pragma unroll
        for (int e = 0; e < 4; ++e) { hv[e] = (f16)s0[e]; hv[4 + e] = (f16)s1[e]; }
        if (t < 64) {
            *(f32x4*)&ql[o] = s0; *(f32x4*)&ql[o + 4] = s1;
            *(f16x8*)&qlh[o] = hv;
        } else {
            *(f32x4*)&kl[o] = s0; *(f32x4*)&kl[o + 4] = s1;
            *(f16x8*)&klh[o] = hv;
        }
    }
}

// ---------------- attn2 = softmax(ql@kl^T) rows; per-head row/col abs-sum maxes ----------------
__global__ __launch_bounds__(256) void attn2_k(const float* __restrict__ ql, const float* __restrict__ kl,
                                               float* __restrict__ a_out, float* __restrict__ mrow,
                                               float* __restrict__ mcol) {
    int h = blockIdx.x;
    __shared__ float qs[64][65], ks[64][65], a[64][65];
    __shared__ float red[64][4];
    __shared__ float rowv[64], colv[64];
    int t = threadIdx.x;
    for (int idx = t; idx < 4096; idx += 256) {
        int r = idx >> 6, c = idx & 63;
        qs[r][c] = ql[h * 4096 + idx];
        ks[r][c] = kl[h * 4096 + idx];
    }
    __syncthreads();
    int i = t >> 2, q4 = t & 3, j0 = q4 * 16;
    float o[16];
    #pragma unroll
    for (int jj = 0; jj < 16; ++jj) o[jj] = 0.f;
    for (int d = 0; d < 64; ++d) {
        float qv = qs[i][d];
        #pragma unroll
        for (int jj = 0; jj < 16; ++jj) o[jj] += qv * ks[j0 + jj][d];
    }
    float pmx = o[0];
    #pragma unroll
    for (int jj = 1; jj < 16; ++jj) pmx = fmaxf(pmx, o[jj]);
    red[i][q4] = pmx;
    __syncthreads();
    float rm = fmaxf(fmaxf(red[i][0], red[i][1]), fmaxf(red[i][2], red[i][3]));
    float psum = 0.f;
    #pragma unroll
    for (int jj = 0; jj < 16; ++jj) { o[jj] = expf(o[jj] - rm); psum += o[jj]; }
    __syncthreads();
    red[i][q4] = psum;
    __syncthreads();
    float rs = red[i][0] + red[i][1] + red[i][2] + red[i][3];
    float inv = 1.0f / rs;
    #pragma unroll
    for (int jj = 0; jj < 16; ++jj) { o[jj] *= inv; a[i][j0 + jj] = o[jj]; }
    __syncthreads();
    for (int idx = t; idx < 4096; idx += 256) a_out[h * 4096 + idx] = a[idx >> 6][idx & 63];
    float rsum = 0.f;
    #pragma unroll
    for (int jj = 0; jj < 16; ++jj) rsum += o[jj];
    __syncthreads();
    red[i][q4] = rsum;
    __syncthreads();
    if (q4 == 0) rowv[i] = red[i][0] + red[i][1] + red[i][2] + red[i][3];
    float csum = 0.f;
    #pragma unroll
    for (int jj = 0; jj < 16; ++jj) csum += a[j0 + jj][i];
    __syncthreads();
    red[i][q4] = csum;
    __syncthreads();
    if (q4 == 0) colv[i] = red[i][0] + red[i][1] + red[i][2] + red[i][3];
    __syncthreads();
    if (t == 0) {
        float mr = rowv[0], mc = colv[0];
        for (int j = 1; j < 64; ++j) { mr = fmaxf(mr, rowv[j]); mc = fmaxf(mc, colv[j]); }
        mrow[h] = mr; mcol[h] = mc;
    }
}

// 4x4-blocked 64x64 matmul helper (operands in LDS, stride 68)
__device__ __forceinline__ void mm_blk(const float (*X)[68], const float (*Y)[68],
                                       int i0, int j0, float o[4][4]) {
    #pragma unroll
    for (int ii = 0; ii < 4; ++ii)
        #pragma unroll
        for (int jj = 0; jj < 4; ++jj) o[ii][jj] = 0.f;
    for (int k = 0; k < 64; ++k) {
        float4 yv = *(const float4*)&Y[k][j0];
        float x0 = X[i0][k], x1 = X[i0 + 1][k], x2 = X[i0 + 2][k], x3 = X[i0 + 3][k];
        o[0][0] += x0 * yv.x; o[0][1] += x0 * yv.y; o[0][2] += x0 * yv.z; o[0][3] += x0 * yv.w;
        o[1][0] += x1 * yv.x; o[1][1] += x1 * yv.y; o[1][2] += x1 * yv.z; o[1][3] += x1 * yv.w;
        o[2][0] += x2 * yv.x; o[2][1] += x2 * yv.y; o[2][2] += x2 * yv.z; o[2][3] += x2 * yv.w;
        o[3][0] += x3 * yv.x; o[3][1] += x3 * yv.y; o[3][2] += x3 * yv.z; o[3][3] += x3 * yv.w;
    }
}

// ---------------- Newton-Schulz pinv (6 iters, f32, per head) ----------------
__global__ __launch_bounds__(256) void pinv_k(const float* __restrict__ a_g, const float* __restrict__ mrow,
                                              const float* __restrict__ mcol, float* __restrict__ z_g) {
    int h = blockIdx.x;
    __shared__ float a[64][68], z[64][68], C[64][68], D[64][68], E[64][68];
    int t = threadIdx.x;
    float mr = mrow[0], mc = mcol[0];
    #pragma unroll
    for (int k = 1; k < 8; ++k) { mr = fmaxf(mr, mrow[k]); mc = fmaxf(mc, mcol[k]); }
    float inv0 = 1.0f / (mr * mc);
    for (int idx = t; idx < 4096; idx += 256) {
        int r = idx >> 6, c = idx & 63;
        float av = a_g[h * 4096 + idx];
        a[r][c] = av;
        z[c][r] = av * inv0;
    }
    __syncthreads();
    int i0 = (t >> 4) * 4, j0 = (t & 15) * 4;
    float o[4][4];
    for (int it = 0; it < 6; ++it) {
        mm_blk(a, z, i0, j0, o);
        #pragma unroll
        for (int ii = 0; ii < 4; ++ii)
            #pragma unroll
            for (int jj = 0; jj < 4; ++jj) C[i0 + ii][j0 + jj] = o[ii][jj];
        __syncthreads();
        mm_blk(C, C, i0, j0, o);
        #pragma unroll
        for (int ii = 0; ii < 4; ++ii)
            #pragma unroll
            for (int jj = 0; jj < 4; ++jj) D[i0 + ii][j0 + jj] = 7.f * C[i0 + ii][j0 + jj] - o[ii][jj];
        __syncthreads();
        mm_blk(C, D, i0, j0, o);
        #pragma unroll
        for (int ii = 0; ii < 4; ++ii)
            #pragma unroll
            for (int jj = 0; jj < 4; ++jj) E[i0 + ii][j0 + jj] = 15.f * C[i0 + ii][j0 + jj] - o[ii][jj];
        __syncthreads();
        mm_blk(z, E, i0, j0, o);
        #pragma unroll
        for (int ii = 0; ii < 4; ++ii)
            #pragma unroll
            for (int jj = 0; jj < 4; ++jj) D[i0 + ii][j0 + jj] = 0.25f * (13.f * z[i0 + ii][j0 + jj] - o[ii][jj]);
        __syncthreads();
        #pragma unroll
        for (int ii = 0; ii < 4; ++ii)
            #pragma unroll
            for (int jj = 0; jj < 4; ++jj) z[i0 + ii][j0 + jj] = D[i0 + ii][j0 + jj];
        __syncthreads();
    }
    for (int idx = t; idx < 4096; idx += 256) z_g[h * 4096 + idx] = z[idx >> 6][idx & 63];
}

// ---------------- attn3 @ v via MFMA: flash-style online softmax, per-block partials ----------------
__global__ __launch_bounds__(256) void attn3_k(const f16* __restrict__ qkvh, const f16* __restrict__ qlh,
                                               float* __restrict__ pm, float* __restrict__ ps,
                                               float* __restrict__ pacc) {
    const int cx = blockIdx.x, h = blockIdx.y;
    const int t = threadIdx.x;
    const int w = t >> 6, lane = t & 63;
    const int lr = lane & 15, hi = lane >> 4;
    __shared__ f16 Qls[64 * 64];
    __shared__ f16 Ks[64 * 64];
    __shared__ f16 vT[64 * 72];
    __shared__ f16 Ps[64 * 72];
    __shared__ float fsh[64];

    #pragma unroll
    for (int pss = 0; pss < 2; ++pss) {
        int q = pss * 256 + t;
        int r = q >> 3, cs = (q & 7) ^ (r & 7);
        GLOAD_LDS16(&qlh[(size_t)h * 4096 + r * 64 + cs * 8], &Qls[(size_t)(pss * 256 + w * 64) * 8]);
    }
    float m_reg = -1e30f, s_reg = 0.f;
    f32x4 accT[4];
    #pragma unroll
    for (int lf = 0; lf < 4; ++lf) accT[lf] = (f32x4){0.f, 0.f, 0.f, 0.f};

    const int vk8 = t & 7, vnn = t >> 3;

    for (int sub = 0; sub < 8; ++sub) {
        const int n0 = cx * 512 + sub * 64;
        __syncthreads();
        #pragma unroll
        for (int pss = 0; pss < 2; ++pss) {
            int q = pss * 256 + t;
            int r = q >> 3, cs = (q & 7) ^ (r & 7);
            GLOAD_LDS16(&qkvh[(size_t)(n0 + r) * QKVC + 512 + h * 64 + cs * 8],
                        &Ks[(size_t)(pss * 256 + w * 64) * 8]);
        }
        #pragma unroll
        for (int p2 = 0; p2 < 2; ++p2) {
            int n = vnn + 32 * p2;
            f16x8 rv = *(const f16x8*)&qkvh[(size_t)(n0 + n) * QKVC + 1024 + h * 64 + vk8 * 8];
            #pragma unroll
            for (int i = 0; i < 8; ++i) {
                int e = i ^ vk8;
                vT[(vk8 * 8 + e) * 72 + n] = rv[e];
            }
        }
        __syncthreads();
        f32x4 c[4];
        #pragma unroll
        for (int kf = 0; kf < 4; ++kf) c[kf] = (f32x4){0.f, 0.f, 0.f, 0.f};
        const int lq = w * 16 + lr;
        #pragma unroll
        for (int ks = 0; ks < 2; ++ks) {
            f16x8 bf = *(const f16x8*)&Qls[lq * 64 + (((ks * 4 + hi) ^ (lq & 7)) * 8)];
            #pragma unroll
            for (int kf = 0; kf < 4; ++kf) {
                int rn = kf * 16 + lr;
                f16x8 af = *(const f16x8*)&Ks[rn * 64 + (((ks * 4 + hi) ^ (rn & 7)) * 8)];
                c[kf] = __builtin_amdgcn_mfma_f32_16x16x32_f16(af, bf, c[kf], 0, 0, 0);
            }
        }
        float tmax = -1e30f;
        #pragma unroll
        for (int kf = 0; kf < 4; ++kf)
            #pragma unroll
            for (int j = 0; j < 4; ++j) tmax = fmaxf(tmax, c[kf][j]);
        tmax = fmaxf(tmax, __shfl_xor(tmax, 16));
        tmax = fmaxf(tmax, __shfl_xor(tmax, 32));
        float newm = fmaxf(m_reg, tmax);
        float fct = __expf(m_reg - newm);
        float psum = 0.f;
        #pragma unroll
        for (int kf = 0; kf < 4; ++kf) {
            f16x4 pk;
            #pragma unroll
            for (int j = 0; j < 4; ++j) {
                float e = __expf(c[kf][j] - newm);
                psum += e;
                pk[j] = (f16)e;
            }
            *(f16x4*)&Ps[lq * 72 + kf * 16 + hi * 4] = pk;
        }
        psum += __shfl_xor(psum, 16);
        psum += __shfl_xor(psum, 32);
        s_reg = s_reg * fct + psum;
        m_reg = newm;
        if (hi == 0) fsh[lq] = fct;
        __syncthreads();
        #pragma unroll
        for (int lf = 0; lf < 4; ++lf) {
            f32x4 fr = *(const f32x4*)&fsh[lf * 16 + hi * 4];
            accT[lf] *= fr;
        }
        #pragma unroll
        for (int ks = 0; ks < 2; ++ks) {
            f16x8 bf = *(const f16x8*)&vT[(w * 16 + lr) * 72 + ks * 32 + hi * 8];
            #pragma unroll
            for (int lf = 0; lf < 4; ++lf) {
                f16x8 af = *(const f16x8*)&Ps[(lf * 16 + lr) * 72 + ks * 32 + hi * 8];
                accT[lf] = __builtin_amdgcn_mfma_f32_16x16x32_f16(af, bf, accT[lf], 0, 0, 0);
            }
        }
    }
    int part = h * NCHUNK + cx;
    if (hi == 0) {
        pm[part * 64 + w * 16 + lr] = m_reg;
        ps[part * 64 + w * 16 + lr] = s_reg;
    }
    #pragma unroll
    for (int lf = 0; lf < 4; ++lf)
        #pragma unroll
        for (int j = 0; j < 4; ++j)
            pacc[((size_t)part * 64 + (lf * 16 + hi * 4 + j)) * 64 + (w * 16 + lr)] = accT[lf][j];
}

// ---------------- merge attn3 partials -> T[h][l][d] ----------------
__global__ void attn3_merge_k(const float* __restrict__ pm, const float* __restrict__ ps,
                              const float* __restrict__ pacc, float* __restrict__ T) {
    int l = blockIdx.x, h = blockIdx.y, d = threadIdx.x;
    float m = -1e30f;
    for (int c = 0; c < NCHUNK; ++c) m = fmaxf(m, pm[(h * NCHUNK + c) * 64 + l]);
    float s = 0.f, a = 0.f;
    for (int c = 0; c < NCHUNK; ++c) {
        float wgt = __expf(pm[(h * NCHUNK + c) * 64 + l] - m);
        s += ps[(h * NCHUNK + c) * 64 + l] * wgt;
        a += pacc[((size_t)(h * NCHUNK + c) * 64 + l) * 64 + d] * wgt;
    }
    T[(h * 64 + l) * 64 + d] = a / s;
}

// ---------------- M = z @ T per head; emit M^T split into f16 hi+lo ----------------
__global__ __launch_bounds__(256) void zmatT_k(const float* __restrict__ z_g, const float* __restrict__ T,
                                               f16* __restrict__ MthHi, f16* __restrict__ MthLo) {
    int h = blockIdx.x;
    __shared__ float zs[64][68], Ts[64][68];
    int t = threadIdx.x;
    for (int idx = t; idx < 4096; idx += 256) {
        int r = idx >> 6, c = idx & 63;
        zs[r][c] = z_g[h * 4096 + idx];
        Ts[r][c] = T[h * 4096 + idx];
    }
    __syncthreads();
    int i0 = (t >> 4) * 4, j0 = (t & 15) * 4;
    float o[4][4];
    mm_blk(zs, Ts, i0, j0, o);
    #pragma unroll
    for (int ii = 0; ii < 4; ++ii)
        #pragma unroll
        for (int jj = 0; jj < 4; ++jj) {
            float mv = o[ii][jj];
            f16 hiv = (f16)mv;
            f16 lov = (f16)(mv - (float)hiv);
            MthHi[h * 4096 + (j0 + jj) * 64 + (i0 + ii)] = hiv;
            MthLo[h * 4096 + (j0 + jj) * 64 + (i0 + ii)] = lov;
        }
}

// ---------------- depthwise conv over sorted v (streaming) -> resH (f16) ----------------
__global__ __launch_bounds__(256) void conv_k(const f16* __restrict__ qkvh,
                                              const float* __restrict__ resk, f16* __restrict__ resH) {
    int h = blockIdx.y;
    int p0 = blockIdx.x * 256;
    __shared__ f16 vt[288][72];
    int t = threadIdx.x;
    for (int id = t; id < 288 * 8; id += 256) {
        int rr = id >> 3, c = id & 7;
        int pg = p0 - 16 + rr;
        int4 v = {0, 0, 0, 0};
        if (pg >= 0 && pg < N_TOK)
            v = *(const int4*)&qkvh[(size_t)pg * QKVC + 1024 + h * 64 + c * 8];
        *(int4*)&vt[rr][c * 8] = v;
    }
    float wk[KSZ];
    #pragma unroll
    for (int k = 0; k < KSZ; ++k) wk[k] = resk[h * KSZ + k];
    __syncthreads();
    int d = t & 63, pg4 = t >> 6;
    float col[96];
    #pragma unroll
    for (int i2 = 0; i2 < 96; ++i2) col[i2] = (float)vt[pg4 * 64 + i2][d];
    #pragma unroll
    for (int pp = 0; pp < 64; ++pp) {
        float acc = 0.f;
        #pragma unroll
        for (int k = 0; k < KSZ; ++k) acc += wk[k] * col[pp + k];
        resH[(size_t)(p0 + pg4 * 64 + pp) * 512 + h * 64 + d] = (f16)acc;
    }
}

// ---------------- attn1 via MFMA: softmax(Q@kl^T) @ M + residual -> Yh ----------------
__global__ __launch_bounds__(256) void attn1_k(const f16* __restrict__ qkvh, const f16* __restrict__ klh,
                                               const f16* __restrict__ MthHi, const f16* __restrict__ MthLo,
                                               const f16* __restrict__ resH, f16* __restrict__ Yh) {
    const int h = blockIdx.y;
    const int p0 = blockIdx.x * 128;
    const int t = threadIdx.x;
    const int w = t >> 6, lane = t & 63;
    const int lr = lane & 15, hi = lane >> 4;
    __shared__ f16 Qs[128][72];
    __shared__ f16 Ks[64][72];
    __shared__ f16 Mhi[64][72];
    __shared__ f16 Mlo[64][72];
    __shared__ f16 Ps[128][72];

    #pragma unroll
    for (int i = 0; i < 4; ++i) {
        int id = i * 256 + t, row = id >> 3, c8 = id & 7;
        *(f16x8*)&Qs[row][c8 * 8] = *(const f16x8*)&qkvh[(size_t)(p0 + row) * QKVC + h * 64 + c8 * 8];
    }
    #pragma unroll
    for (int i = 0; i < 2; ++i) {
        int id = i * 256 + t, row = id >> 3, c8 = id & 7;
        *(f16x8*)&Ks[row][c8 * 8]  = *(const f16x8*)&klh[h * 4096 + id * 8];
        *(f16x8*)&Mhi[row][c8 * 8] = *(const f16x8*)&MthHi[h * 4096 + id * 8];
        *(f16x8*)&Mlo[row][c8 * 8] = *(const f16x8*)&MthLo[h * 4096 + id * 8];
    }
    __syncthreads();

    f32x4 c[4][2];
    #pragma unroll
    for (int lf = 0; lf < 4; ++lf)
        #pragma unroll
        for (int nf = 0; nf < 2; ++nf) c[lf][nf] = (f32x4){0.f, 0.f, 0.f, 0.f};
    #pragma unroll
    for (int ks = 0; ks < 2; ++ks) {
        f16x8 af[4], bf[2];
        #pragma unroll
        for (int lf = 0; lf < 4; ++lf) af[lf] = *(const f16x8*)&Ks[lf * 16 + lr][ks * 32 + hi * 8];
        #pragma unroll
        for (int nf = 0; nf < 2; ++nf) bf[nf] = *(const f16x8*)&Qs[w * 32 + nf * 16 + lr][ks * 32 + hi * 8];
        #pragma unroll
        for (int lf = 0; lf < 4; ++lf)
            #pragma unroll
            for (int nf = 0; nf < 2; ++nf)
                c[lf][nf] = __builtin_amdgcn_mfma_f32_16x16x32_f16(af[lf], bf[nf], c[lf][nf], 0, 0, 0);
    }

    #pragma unroll
    for (int nf = 0; nf < 2; ++nf) {
        float m = -1e30f;
        #pragma unroll
        for (int lf = 0; lf < 4; ++lf)
            #pragma unroll
            for (int j = 0; j < 4; ++j) m = fmaxf(m, c[lf][nf][j]);
        m = fmaxf(m, __shfl_xor(m, 16));
        m = fmaxf(m, __shfl_xor(m, 32));
        float s = 0.f;
        #pragma unroll
        for (int lf = 0; lf < 4; ++lf)
            #pragma unroll
            for (int j = 0; j < 4; ++j) { float e = __expf(c[lf][nf][j] - m); c[lf][nf][j] = e; s += e; }
        s += __shfl_xor(s, 16);
        s += __shfl_xor(s, 32);
        float inv = 1.0f / s;
        #pragma unroll
        for (int lf = 0; lf < 4; ++lf) {
            f16x4 pk;
            #pragma unroll
            for (int j = 0; j < 4; ++j) pk[j] = (f16)(c[lf][nf][j] * inv);
            *(f16x4*)&Ps[w * 32 + nf * 16 + lr][lf * 16 + hi * 4] = pk;
        }
    }

    f32x4 o[2][4];
    #pragma unroll
    for (int nf = 0; nf < 2; ++nf)
        #pragma unroll
        for (int df = 0; df < 4; ++df) o[nf][df] = (f32x4){0.f, 0.f, 0.f, 0.f};
    #pragma unroll
    for (int ks = 0; ks < 2; ++ks) {
        f16x8 pa[2], bh[4], bl[4];
        #pragma unroll
        for (int nf = 0; nf < 2; ++nf) pa[nf] = *(const f16x8*)&Ps[w * 32 + nf * 16 + lr][ks * 32 + hi * 8];
        #pragma unroll
        for (int df = 0; df < 4; ++df) {
            bh[df] = *(const f16x8*)&Mhi[df * 16 + lr][ks * 32 + hi * 8];
            bl[df] = *(const f16x8*)&Mlo[df * 16 + lr][ks * 32 + hi * 8];
        }
        #pragma unroll
        for (int nf = 0; nf < 2; ++nf)
            #pragma unroll
            for (int df = 0; df < 4; ++df) {
                o[nf][df] = __builtin_amdgcn_mfma_f32_16x16x32_f16(pa[nf], bh[df], o[nf][df], 0, 0, 0);
                o[nf][df] = __builtin_amdgcn_mfma_f32_16x16x32_f16(pa[nf], bl[df], o[nf][df], 0, 0, 0);
            }
    }

    #pragma unroll
    for (int nf = 0; nf < 2; ++nf)
        #pragma unroll
        for (int df = 0; df < 4; ++df)
            #pragma unroll
            for (int j = 0; j < 4; ++j)
                Ps[w * 32 + nf * 16 + hi * 4 + j][df * 16 + lr] = (f16)(o[nf][df][j]);
    __syncthreads();

    #pragma unroll
    for (int i = 0; i < 4; ++i) {
        int id = i * 256 + t, row = id >> 3, c8 = id & 7;
        size_t go = (size_t)(p0 + row) * 512 + h * 64 + c8 * 8;
        f16x8 yv = *(const f16x8*)&Ps[row][c8 * 8];
        f16x8 rv = *(const f16x8*)&resH[go];
        f16x8 sv;
        #pragma unroll
        for (int e = 0; e < 8; ++e) sv[e] = (f16)((float)yv[e] + (float)rv[e]);
        *(f16x8*)&Yh[go] = sv;
    }
}

// ---------------- host launch ----------------
extern "C" void kernel_launch(void* const* d_in, const int* in_sizes, int n_in,
                              void* d_out, int out_size, void* d_ws, size_t ws_size,
                              hipStream_t stream) {
    const float* x    = (const float*)d_in[0];
    const float* Wqkv = (const float*)d_in[1];
    const float* Wout = (const float*)d_in[2];
    const float* bout = (const float*)d_in[3];
    const float* resk = (const float*)d_in[4];
    const int*   labels = (const int*)d_in[5];
    float* out = (float*)d_out;

    char* w = (char*)d_ws;
    size_t off = 0;
    auto alloc = [&](size_t bytes) {
        void* p = w + off;
        off += (bytes + 255) & ~(size_t)255;
        return p;
    };
    f16* xh     = (f16*)alloc((size_t)N_TOK * DIMC * 2);       // sorted
    f16* qkvh   = (f16*)alloc((size_t)N_TOK * QKVC * 2);       // sorted
    f16* WqkvT  = (f16*)alloc((size_t)QKVC * DIMC * 2);
    f16* WoutT  = (f16*)alloc((size_t)DIMC * DIMC * 2);
    f16* Yh     = (f16*)alloc((size_t)N_TOK * DIMC * 2);       // sorted
    int* counts = (int*)alloc(NL * 4);
    int* baseA  = (int*)alloc(NL * 4);
    int* indexA = (int*)alloc((size_t)N_TOK * 4);
    float* ql   = (float*)alloc((size_t)NH * 64 * 64 * 4);
    float* kl   = (float*)alloc((size_t)NH * 64 * 64 * 4);
    f16* qlh    = (f16*)alloc((size_t)NH * 64 * 64 * 2);
    f16* klh    = (f16*)alloc((size_t)NH * 64 * 64 * 2);
    float* a2   = (float*)alloc((size_t)NH * 64 * 64 * 4);
    float* mrow = (float*)alloc(NH * 4);
    float* mcol = (float*)alloc(NH * 4);
    float* zb   = (float*)alloc((size_t)NH * 64 * 64 * 4);
    float* Tb   = (float*)alloc((size_t)NH * 64 * 64 * 4);
    f16* MthHi  = (f16*)alloc((size_t)NH * 64 * 64 * 2);
    f16* MthLo  = (f16*)alloc((size_t)NH * 64 * 64 * 2);
    float* pm   = (float*)alloc((size_t)NH * NCHUNK * 64 * 4);
    float* ps   = (float*)alloc((size_t)NH * NCHUNK * 64 * 4);
    float* pacc = (float*)alloc((size_t)NH * NCHUNK * 64 * 64 * 4);
    f16* resH = (f16*)d_out;  // reuse d_out (64MB) as f16 conv output (32MB); overwritten by final GEMM

    hipMemsetAsync(counts, 0, NL * 4, stream);

    // stable counting sort
    hist_k<<<N_TOK / 256, 256, 0, stream>>>(labels, counts);
    scan_k<<<1, 64, 0, stream>>>(counts, baseA);
    compact_k<<<NL, 256, 0, stream>>>(labels, baseA, indexA);
    // gather+convert x rows into sorted order
    gather_cvt_k<<<N_TOK / 2, 256, 0, stream>>>((const float4*)x, indexA, (f16x4*)xh);
    // weight transposes
    transpose_k<<<dim3(QKVC / 32, DIMC / 32), dim3(32, 8), 0, stream>>>(Wqkv, WqkvT, DIMC, QKVC);
    transpose_k<<<dim3(DIMC / 32, DIMC / 32), dim3(32, 8), 0, stream>>>(Wout, WoutT, DIMC, DIMC);
    // qkv = x_sorted @ Wqkv  (sorted domain)
    gemm_k512<QKVC, false, 6><<<dim3(N_TOK / 128, QKVC / 256), 512, 0, stream>>>(xh, WqkvT, qkvh, nullptr, nullptr);
    // segment pooling (vectorized)
    pool_k<<<NL, 1024, 0, stream>>>(qkvh, baseA, counts, ql, kl, qlh, klh);
    // attn2 + pinv chain (f32)
    attn2_k<<<NH, 256, 0, stream>>>(ql, kl, a2, mrow, mcol);
    pinv_k<<<NH, 256, 0, stream>>>(a2, mrow, mcol, zb);
    // T = softmax(ql@k^T) @ v  (MFMA flash-style)
    attn3_k<<<dim3(NCHUNK, NH), 256, 0, stream>>>(qkvh, qlh, pm, ps, pacc);
    attn3_merge_k<<<dim3(NL, NH), 64, 0, stream>>>(pm, ps, pacc, Tb);
    // M^T (hi+lo f16) = (z @ T)^T
    zmatT_k<<<NH, 256, 0, stream>>>(zb, Tb, MthHi, MthLo);
    // depthwise conv over sorted v (streaming)
    conv_k<<<dim3(N_TOK / 256, NH), 256, 0, stream>>>(qkvh, resk, resH);
    // attn1 (MFMA) + combine -> Yh (sorted)
    attn1_k<<<dim3(N_TOK / 128, NH), 256, 0, stream>>>(qkvh, klh, MthHi, MthLo, resH, Yh);
    // final projection + bias, scatter rows back to original order
    gemm_k512<DIMC, true, 2><<<dim3(N_TOK / 128, DIMC / 256), 512, 0, stream>>>(Yh, WoutT, out, bout, indexA);
}

// Round 9
// 379.937 us; speedup vs baseline: 2.9797x; 1.0151x over previous
//
#include <hip/hip_runtime.h>
#include <hip/hip_bf16.h>

// ---------------- problem constants ----------------
#define N_TOK 32768
#define DIMC  512
#define NH    8
#define DHD   64
#define NL    64
#define KSZ   33
#define QKVC  1536
#define NCHUNK 64   // attn3 chunks; 512 tokens per block

typedef _Float16 f16;
typedef _Float16 f16x8 __attribute__((ext_vector_type(8)));
typedef _Float16 f16x4 __attribute__((ext_vector_type(4)));
typedef float    f32x4 __attribute__((ext_vector_type(4)));

#define GLOAD_LDS16(gp, lp) \
    __builtin_amdgcn_global_load_lds((const __attribute__((address_space(1))) void*)(gp), \
                                     (__attribute__((address_space(3))) void*)(lp), 16, 0, 0)

// ---------------- transpose f32 (R x C) -> f16 (C x R) ----------------
__global__ void transpose_k(const float* __restrict__ W, f16* __restrict__ WT, int R, int C) {
    __shared__ float tile[32][33];
    int bx = blockIdx.x * 32, by = blockIdx.y * 32;
    int tx = threadIdx.x, ty = threadIdx.y;
    #pragma unroll
    for (int i = 0; i < 32; i += 8)
        tile[ty + i][tx] = W[(size_t)(by + ty + i) * C + bx + tx];
    __syncthreads();
    #pragma unroll
    for (int i = 0; i < 32; i += 8)
        WT[(size_t)(bx + ty + i) * R + by + tx] = (f16)tile[tx][ty + i];
}

// ---------------- label histogram ----------------
__global__ void hist_k(const int* __restrict__ labels, int* __restrict__ counts) {
    __shared__ int hloc[NL];
    int t = threadIdx.x;
    if (t < NL) hloc[t] = 0;
    __syncthreads();
    int i = blockIdx.x * 256 + t;
    atomicAdd(&hloc[labels[i]], 1);
    __syncthreads();
    if (t < NL) atomicAdd(&counts[t], hloc[t]);
}

// ---------------- exclusive prefix over 64 counts ----------------
__global__ void scan_k(const int* __restrict__ counts, int* __restrict__ base) {
    if (threadIdx.x == 0) {
        int s = 0;
        for (int l = 0; l < NL; ++l) { base[l] = s; s += counts[l]; }
    }
}

// ---------------- stable compaction: one block per label ----------------
__global__ __launch_bounds__(256) void compact_k(const int* __restrict__ labels,
                                                 const int* __restrict__ base,
                                                 int* __restrict__ indexArr) {
    const int l = blockIdx.x;
    __shared__ int wtot[4];
    __shared__ int s_run;
    int t = threadIdx.x, lane = t & 63, w = t >> 6;
    if (t == 0) s_run = base[l];
    __syncthreads();
    for (int c0 = 0; c0 < N_TOK; c0 += 256) {
        int ii = c0 + t;
        bool flag = (labels[ii] == l);
        unsigned long long mask = __ballot(flag);
        int before = __popcll(mask & ((1ull << lane) - 1ull));
        if (lane == 0) wtot[w] = __popcll(mask);
        __syncthreads();
        int off = 0;
        #pragma unroll
        for (int ww = 0; ww < 4; ++ww) off += (ww < w) ? wtot[ww] : 0;
        int tot = wtot[0] + wtot[1] + wtot[2] + wtot[3];
        int rb = s_run;
        if (flag) indexArr[rb + off + before] = ii;
        __syncthreads();
        if (t == 0) s_run = rb + tot;
    }
}

// ---------------- gather rows of x via index, convert to f16 (sorted domain) ----------------
__global__ __launch_bounds__(256) void gather_cvt_k(const float4* __restrict__ x4,
                                                    const int* __restrict__ indexArr,
                                                    f16x4* __restrict__ xh4) {
    int t = threadIdx.x;
    int row = blockIdx.x * 2 + (t >> 7);
    int c4 = t & 127;
    int j = indexArr[row];
    float4 v = x4[(size_t)j * 128 + c4];
    f16x4 o = { (f16)v.x, (f16)v.y, (f16)v.z, (f16)v.w };
    xh4[(size_t)row * 128 + c4] = o;
}

// ---------------- f16 MFMA GEMM: C[M x BNTOT] = A[M x 512] @ BT[BNTOT x 512]^T ----------------
// tile 128x256, BK=32, 8 waves (2M x 4N grid), each wave a SQUARE 64x64 sub-tile:
// acc 4x4 frags = 64 VGPR, af 4 + bf 4 = 8 ds_read_b128/wave/K-step (64 KB/block/K-step,
// -20% LDS traffic vs 128x32 wave strips). 3-buffer rotation: stage(kt+2) is safe after the
// single top barrier of iter kt (all waves finished compute(kt-1), the last reader of that
// buffer) -> ONE barrier per K-step. Counted vmcnt(3) retires only the oldest stage (T4).
// T2 chunk-XOR swizzle (source-side), T1 bijective XCD swizzle, swapped-operand epilogue.
template<int BNTOT, bool OUT_F32, int NY>
__global__ __launch_bounds__(512, 4) void gemm_k512(const f16* __restrict__ A, const f16* __restrict__ BT,
                                                    void* __restrict__ Cout, const float* __restrict__ bias,
                                                    const int* __restrict__ scatterIdx) {
    constexpr int K = 512;
    constexpr int NKT = K / 32;             // 16 K-tiles
    __shared__ f16 As[3][128 * 32];         // 3 x 8 KB
    __shared__ f16 Bs[3][256 * 32];         // 3 x 16 KB  (72 KB total -> 2 blocks/CU)
    const int t = threadIdx.x;
    const int orig = blockIdx.x + gridDim.x * blockIdx.y;
    constexpr int NWG = 256 * NY;           // gridDim.x == 256 (N_TOK/128)
    constexpr int CPX = NWG / 8;
    const int lin = (orig & 7) * CPX + (orig >> 3);
    const int mBase = (lin / NY) * 128;
    const int nBase = (lin % NY) * 256;
    const int w = t >> 6, lane = t & 63;
    const int wm = w >> 2, wn = w & 3;      // 2 x 4 wave grid
    const int lr = lane & 15, lk = lane >> 4;
    const int kc = (lk ^ ((lr >> 1) & 3)) * 8;   // swizzled chunk offset (halves)
    f32x4 acc[4][4];
    #pragma unroll
    for (int m = 0; m < 4; ++m)
        #pragma unroll
        for (int n = 0; n < 4; ++n) acc[m][n] = (f32x4){0.f, 0.f, 0.f, 0.f};

    auto stage = [&](int buf, int kt) {
        // A: 128 rows x 4 slots = 512 chunks of 16B; one round over 512 threads
        {
            int id = t;
            int row = id >> 2, c = id & 3;
            int cg = c ^ ((row >> 1) & 3);
            GLOAD_LDS16(&A[(size_t)(mBase + row) * K + kt * 32 + cg * 8],
                        &As[buf][(size_t)(w * 64) * 8]);
        }
        // B: 256 rows x 4 slots = 1024 chunks; two rounds
        #pragma unroll
        for (int r = 0; r < 2; ++r) {
            int id = r * 512 + t;
            int row = id >> 2, c = id & 3;
            int cg = c ^ ((row >> 1) & 3);
            GLOAD_LDS16(&BT[(size_t)(nBase + row) * K + kt * 32 + cg * 8],
                        &Bs[buf][(size_t)(r * 512 + w * 64) * 8]);
        }
    };
    auto compute = [&](int buf) {
        f16x8 af[4], bf[4];
        #pragma unroll
        for (int m = 0; m < 4; ++m)
            af[m] = *(const f16x8*)&As[buf][(wm * 64 + m * 16 + lr) * 32 + kc];
        #pragma unroll
        for (int n = 0; n < 4; ++n)
            bf[n] = *(const f16x8*)&Bs[buf][(wn * 64 + n * 16 + lr) * 32 + kc];
        // swapped operands: lane element j -> C col = nBase + wn*64 + n*16 + lk*4 + j,
        // C row = mBase + wm*64 + m*16 + lr
        #pragma unroll
        for (int m = 0; m < 4; ++m)
            #pragma unroll
            for (int n = 0; n < 4; ++n)
                acc[m][n] = __builtin_amdgcn_mfma_f32_16x16x32_f16(bf[n], af[m], acc[m][n], 0, 0, 0);
    };

    // prologue: 2-deep prefetch (6 loads/wave in flight)
    stage(0, 0);
    stage(1, 1);
    for (int kt = 0; kt < NKT; ++kt) {
        if (kt < NKT - 1) {
            asm volatile("s_waitcnt vmcnt(3)" ::: "memory");   // retire oldest stage's 3/wave
        } else {
            asm volatile("s_waitcnt vmcnt(0)" ::: "memory");
        }
        __builtin_amdgcn_s_barrier();     // tile-kt fully in LDS; all waves past compute(kt-1)
        if (kt + 2 < NKT) stage((kt + 2) % 3, kt + 2);   // overwrites buffer last read at kt-1: safe
        compute(kt % 3);
    }

    #pragma unroll
    for (int m = 0; m < 4; ++m) {
        int row = mBase + wm * 64 + m * 16 + lr;
        int srow = OUT_F32 ? scatterIdx[row] : row;
        #pragma unroll
        for (int n = 0; n < 4; ++n) {
            int col = nBase + wn * 64 + n * 16 + lk * 4;
            if constexpr (OUT_F32) {
                float4 bv = *(const float4*)&bias[col];
                float4 sv = make_float4(acc[m][n][0] + bv.x, acc[m][n][1] + bv.y,
                                        acc[m][n][2] + bv.z, acc[m][n][3] + bv.w);
                *(float4*)&((float*)Cout)[(size_t)srow * BNTOT + col] = sv;
            } else {
                f16x4 hv = { (f16)acc[m][n][0], (f16)acc[m][n][1],
                             (f16)acc[m][n][2], (f16)acc[m][n][3] };
                *(f16x4*)&((f16*)Cout)[(size_t)srow * BNTOT + col] = hv;
            }
        }
    }
}

// ---------------- segment-mean pooling (vectorized): sorted q,k -> ql,kl (f32) + qlh,klh (f16) ----------------
__global__ __launch_bounds__(1024) void pool_k(const f16* __restrict__ qkvh,
                                               const int* __restrict__ base, const int* __restrict__ counts,
                                               float* __restrict__ ql, float* __restrict__ kl,
                                               f16* __restrict__ qlh, f16* __restrict__ klh) {
    int l = blockIdx.x;
    int t = threadIdx.x;
    int c = t & 127, rg = t >> 7;
    int b0 = base[l], cnt = counts[l];
    f32x4 a0 = {0.f,0.f,0.f,0.f}, a1 = {0.f,0.f,0.f,0.f};
    for (int p = rg; p < cnt; p += 8) {
        f16x8 v = *(const f16x8*)&qkvh[(size_t)(b0 + p) * QKVC + c * 8];
        a0[0] += (float)v[0]; a0[1] += (float)v[1]; a0[2] += (float)v[2]; a0[3] += (float)v[3];
        a1[0] += (float)v[4]; a1[1] += (float)v[5]; a1[2] += (float)v[6]; a1[3] += (float)v[7];
    }
    __shared__ f32x4 red[8][128][2];
    red[rg][c][0] = a0; red[rg][c][1] = a1;
    __syncthreads();
    if (t < 128) {
        float inv = 1.0f / (float)(cnt > 0 ? cnt : 1);
        f32x4 s0 = {0.f,0.f,0.f,0.f}, s1 = {0.f,0.f,0.f,0.f};
        #pragma unroll
        for (int g = 0; g < 8; ++g) { s0 += red[g][t][0]; s1 += red[g][t][1]; }
        s0 *= inv; s1 *= inv;
        int h = (t & 63) >> 3, d0 = (t & 7) * 8;
        size_t o = ((size_t)(h * 64 + l)) * 64 + d0;
        f16x8 hv;
        #pragma unroll
        for (int e = 0; e < 4; ++e) { hv[e] = (f16)s0[e]; hv[4 + e] = (f16)s1[e]; }
        if (t < 64) {
            *(f32x4*)&ql[o] = s0; *(f32x4*)&ql[o + 4] = s1;
            *(f16x8*)&qlh[o] = hv;
        } else {
            *(f32x4*)&kl[o] = s0; *(f32x4*)&kl[o + 4] = s1;
            *(f16x8*)&klh[o] = hv;
        }
    }
}

// ---------------- attn2 = softmax(ql@kl^T) rows; per-head row/col abs-sum maxes ----------------
__global__ __launch_bounds__(256) void attn2_k(const float* __restrict__ ql, const float* __restrict__ kl,
                                               float* __restrict__ a_out, float* __restrict__ mrow,
                                               float* __restrict__ mcol) {
    int h = blockIdx.x;
    __shared__ float qs[64][65], ks[64][65], a[64][65];
    __shared__ float red[64][4];
    __shared__ float rowv[64], colv[64];
    int t = threadIdx.x;
    for (int idx = t; idx < 4096; idx += 256) {
        int r = idx >> 6, c = idx & 63;
        qs[r][c] = ql[h * 4096 + idx];
        ks[r][c] = kl[h * 4096 + idx];
    }
    __syncthreads();
    int i = t >> 2, q4 = t & 3, j0 = q4 * 16;
    float o[16];
    #pragma unroll
    for (int jj = 0; jj < 16; ++jj) o[jj] = 0.f;
    for (int d = 0; d < 64; ++d) {
        float qv = qs[i][d];
        #pragma unroll
        for (int jj = 0; jj < 16; ++jj) o[jj] += qv * ks[j0 + jj][d];
    }
    float pmx = o[0];
    #pragma unroll
    for (int jj = 1; jj < 16; ++jj) pmx = fmaxf(pmx, o[jj]);
    red[i][q4] = pmx;
    __syncthreads();
    float rm = fmaxf(fmaxf(red[i][0], red[i][1]), fmaxf(red[i][2], red[i][3]));
    float psum = 0.f;
    #pragma unroll
    for (int jj = 0; jj < 16; ++jj) { o[jj] = expf(o[jj] - rm); psum += o[jj]; }
    __syncthreads();
    red[i][q4] = psum;
    __syncthreads();
    float rs = red[i][0] + red[i][1] + red[i][2] + red[i][3];
    float inv = 1.0f / rs;
    #pragma unroll
    for (int jj = 0; jj < 16; ++jj) { o[jj] *= inv; a[i][j0 + jj] = o[jj]; }
    __syncthreads();
    for (int idx = t; idx < 4096; idx += 256) a_out[h * 4096 + idx] = a[idx >> 6][idx & 63];
    float rsum = 0.f;
    #pragma unroll
    for (int jj = 0; jj < 16; ++jj) rsum += o[jj];
    __syncthreads();
    red[i][q4] = rsum;
    __syncthreads();
    if (q4 == 0) rowv[i] = red[i][0] + red[i][1] + red[i][2] + red[i][3];
    float csum = 0.f;
    #pragma unroll
    for (int jj = 0; jj < 16; ++jj) csum += a[j0 + jj][i];
    __syncthreads();
    red[i][q4] = csum;
    __syncthreads();
    if (q4 == 0) colv[i] = red[i][0] + red[i][1] + red[i][2] + red[i][3];
    __syncthreads();
    if (t == 0) {
        float mr = rowv[0], mc = colv[0];
        for (int j = 1; j < 64; ++j) { mr = fmaxf(mr, rowv[j]); mc = fmaxf(mc, colv[j]); }
        mrow[h] = mr; mcol[h] = mc;
    }
}

// 4x4-blocked 64x64 matmul helper (operands in LDS, stride 68)
__device__ __forceinline__ void mm_blk(const float (*X)[68], const float (*Y)[68],
                                       int i0, int j0, float o[4][4]) {
    #pragma unroll
    for (int ii = 0; ii < 4; ++ii)
        #pragma unroll
        for (int jj = 0; jj < 4; ++jj) o[ii][jj] = 0.f;
    for (int k = 0; k < 64; ++k) {
        float4 yv = *(const float4*)&Y[k][j0];
        float x0 = X[i0][k], x1 = X[i0 + 1][k], x2 = X[i0 + 2][k], x3 = X[i0 + 3][k];
        o[0][0] += x0 * yv.x; o[0][1] += x0 * yv.y; o[0][2] += x0 * yv.z; o[0][3] += x0 * yv.w;
        o[1][0] += x1 * yv.x; o[1][1] += x1 * yv.y; o[1][2] += x1 * yv.z; o[1][3] += x1 * yv.w;
        o[2][0] += x2 * yv.x; o[2][1] += x2 * yv.y; o[2][2] += x2 * yv.z; o[2][3] += x2 * yv.w;
        o[3][0] += x3 * yv.x; o[3][1] += x3 * yv.y; o[3][2] += x3 * yv.z; o[3][3] += x3 * yv.w;
    }
}

// ---------------- Newton-Schulz pinv (6 iters, f32, per head) ----------------
__global__ __launch_bounds__(256) void pinv_k(const float* __restrict__ a_g, const float* __restrict__ mrow,
                                              const float* __restrict__ mcol, float* __restrict__ z_g) {
    int h = blockIdx.x;
    __shared__ float a[64][68], z[64][68], C[64][68], D[64][68], E[64][68];
    int t = threadIdx.x;
    float mr = mrow[0], mc = mcol[0];
    #pragma unroll
    for (int k = 1; k < 8; ++k) { mr = fmaxf(mr, mrow[k]); mc = fmaxf(mc, mcol[k]); }
    float inv0 = 1.0f / (mr * mc);
    for (int idx = t; idx < 4096; idx += 256) {
        int r = idx >> 6, c = idx & 63;
        float av = a_g[h * 4096 + idx];
        a[r][c] = av;
        z[c][r] = av * inv0;
    }
    __syncthreads();
    int i0 = (t >> 4) * 4, j0 = (t & 15) * 4;
    float o[4][4];
    for (int it = 0; it < 6; ++it) {
        mm_blk(a, z, i0, j0, o);
        #pragma unroll
        for (int ii = 0; ii < 4; ++ii)
            #pragma unroll
            for (int jj = 0; jj < 4; ++jj) C[i0 + ii][j0 + jj] = o[ii][jj];
        __syncthreads();
        mm_blk(C, C, i0, j0, o);
        #pragma unroll
        for (int ii = 0; ii < 4; ++ii)
            #pragma unroll
            for (int jj = 0; jj < 4; ++jj) D[i0 + ii][j0 + jj] = 7.f * C[i0 + ii][j0 + jj] - o[ii][jj];
        __syncthreads();
        mm_blk(C, D, i0, j0, o);
        #pragma unroll
        for (int ii = 0; ii < 4; ++ii)
            #pragma unroll
            for (int jj = 0; jj < 4; ++jj) E[i0 + ii][j0 + jj] = 15.f * C[i0 + ii][j0 + jj] - o[ii][jj];
        __syncthreads();
        mm_blk(z, E, i0, j0, o);
        #pragma unroll
        for (int ii = 0; ii < 4; ++ii)
            #pragma unroll
            for (int jj = 0; jj < 4; ++jj) D[i0 + ii][j0 + jj] = 0.25f * (13.f * z[i0 + ii][j0 + jj] - o[ii][jj]);
        __syncthreads();
        #pragma unroll
        for (int ii = 0; ii < 4; ++ii)
            #pragma unroll
            for (int jj = 0; jj < 4; ++jj) z[i0 + ii][j0 + jj] = D[i0 + ii][j0 + jj];
        __syncthreads();
    }
    for (int idx = t; idx < 4096; idx += 256) z_g[h * 4096 + idx] = z[idx >> 6][idx & 63];
}

// ---------------- attn3 @ v via MFMA: flash-style online softmax, per-block partials ----------------
__global__ __launch_bounds__(256) void attn3_k(const f16* __restrict__ qkvh, const f16* __restrict__ qlh,
                                               float* __restrict__ pm, float* __restrict__ ps,
                                               float* __restrict__ pacc) {
    const int cx = blockIdx.x, h = blockIdx.y;
    const int t = threadIdx.x;
    const int w = t >> 6, lane = t & 63;
    const int lr = lane & 15, hi = lane >> 4;
    __shared__ f16 Qls[64 * 64];
    __shared__ f16 Ks[64 * 64];
    __shared__ f16 vT[64 * 72];
    __shared__ f16 Ps[64 * 72];
    __shared__ float fsh[64];

    #pragma unroll
    for (int pss = 0; pss < 2; ++pss) {
        int q = pss * 256 + t;
        int r = q >> 3, cs = (q & 7) ^ (r & 7);
        GLOAD_LDS16(&qlh[(size_t)h * 4096 + r * 64 + cs * 8], &Qls[(size_t)(pss * 256 + w * 64) * 8]);
    }
    float m_reg = -1e30f, s_reg = 0.f;
    f32x4 accT[4];
    #pragma unroll
    for (int lf = 0; lf < 4; ++lf) accT[lf] = (f32x4){0.f, 0.f, 0.f, 0.f};

    const int vk8 = t & 7, vnn = t >> 3;

    for (int sub = 0; sub < 8; ++sub) {
        const int n0 = cx * 512 + sub * 64;
        __syncthreads();
        #pragma unroll
        for (int pss = 0; pss < 2; ++pss) {
            int q = pss * 256 + t;
            int r = q >> 3, cs = (q & 7) ^ (r & 7);
            GLOAD_LDS16(&qkvh[(size_t)(n0 + r) * QKVC + 512 + h * 64 + cs * 8],
                        &Ks[(size_t)(pss * 256 + w * 64) * 8]);
        }
        #pragma unroll
        for (int p2 = 0; p2 < 2; ++p2) {
            int n = vnn + 32 * p2;
            f16x8 rv = *(const f16x8*)&qkvh[(size_t)(n0 + n) * QKVC + 1024 + h * 64 + vk8 * 8];
            #pragma unroll
            for (int i = 0; i < 8; ++i) {
                int e = i ^ vk8;
                vT[(vk8 * 8 + e) * 72 + n] = rv[e];
            }
        }
        __syncthreads();
        f32x4 c[4];
        #pragma unroll
        for (int kf = 0; kf < 4; ++kf) c[kf] = (f32x4){0.f, 0.f, 0.f, 0.f};
        const int lq = w * 16 + lr;
        #pragma unroll
        for (int ks = 0; ks < 2; ++ks) {
            f16x8 bf = *(const f16x8*)&Qls[lq * 64 + (((ks * 4 + hi) ^ (lq & 7)) * 8)];
            #pragma unroll
            for (int kf = 0; kf < 4; ++kf) {
                int rn = kf * 16 + lr;
                f16x8 af = *(const f16x8*)&Ks[rn * 64 + (((ks * 4 + hi) ^ (rn & 7)) * 8)];
                c[kf] = __builtin_amdgcn_mfma_f32_16x16x32_f16(af, bf, c[kf], 0, 0, 0);
            }
        }
        float tmax = -1e30f;
        #pragma unroll
        for (int kf = 0; kf < 4; ++kf)
            #pragma unroll
            for (int j = 0; j < 4; ++j) tmax = fmaxf(tmax, c[kf][j]);
        tmax = fmaxf(tmax, __shfl_xor(tmax, 16));
        tmax = fmaxf(tmax, __shfl_xor(tmax, 32));
        float newm = fmaxf(m_reg, tmax);
        float fct = __expf(m_reg - newm);
        float psum = 0.f;
        #pragma unroll
        for (int kf = 0; kf < 4; ++kf) {
            f16x4 pk;
            #pragma unroll
            for (int j = 0; j < 4; ++j) {
                float e = __expf(c[kf][j] - newm);
                psum += e;
                pk[j] = (f16)e;
            }
            *(f16x4*)&Ps[lq * 72 + kf * 16 + hi * 4] = pk;
        }
        psum += __shfl_xor(psum, 16);
        psum += __shfl_xor(psum, 32);
        s_reg = s_reg * fct + psum;
        m_reg = newm;
        if (hi == 0) fsh[lq] = fct;
        __syncthreads();
        #pragma unroll
        for (int lf = 0; lf < 4; ++lf) {
            f32x4 fr = *(const f32x4*)&fsh[lf * 16 + hi * 4];
            accT[lf] *= fr;
        }
        #pragma unroll
        for (int ks = 0; ks < 2; ++ks) {
            f16x8 bf = *(const f16x8*)&vT[(w * 16 + lr) * 72 + ks * 32 + hi * 8];
            #pragma unroll
            for (int lf = 0; lf < 4; ++lf) {
                f16x8 af = *(const f16x8*)&Ps[(lf * 16 + lr) * 72 + ks * 32 + hi * 8];
                accT[lf] = __builtin_amdgcn_mfma_f32_16x16x32_f16(af, bf, accT[lf], 0, 0, 0);
            }
        }
    }
    int part = h * NCHUNK + cx;
    if (hi == 0) {
        pm[part * 64 + w * 16 + lr] = m_reg;
        ps[part * 64 + w * 16 + lr] = s_reg;
    }
    #pragma unroll
    for (int lf = 0; lf < 4; ++lf)
        #pragma unroll
        for (int j = 0; j < 4; ++j)
            pacc[((size_t)part * 64 + (lf * 16 + hi * 4 + j)) * 64 + (w * 16 + lr)] = accT[lf][j];
}

// ---------------- merge attn3 partials -> T[h][l][d] ----------------
__global__ void attn3_merge_k(const float* __restrict__ pm, const float* __restrict__ ps,
                              const float* __restrict__ pacc, float* __restrict__ T) {
    int l = blockIdx.x, h = blockIdx.y, d = threadIdx.x;
    float m = -1e30f;
    for (int c = 0; c < NCHUNK; ++c) m = fmaxf(m, pm[(h * NCHUNK + c) * 64 + l]);
    float s = 0.f, a = 0.f;
    for (int c = 0; c < NCHUNK; ++c) {
        float wgt = __expf(pm[(h * NCHUNK + c) * 64 + l] - m);
        s += ps[(h * NCHUNK + c) * 64 + l] * wgt;
        a += pacc[((size_t)(h * NCHUNK + c) * 64 + l) * 64 + d] * wgt;
    }
    T[(h * 64 + l) * 64 + d] = a / s;
}

// ---------------- M = z @ T per head; emit M^T split into f16 hi+lo ----------------
__global__ __launch_bounds__(256) void zmatT_k(const float* __restrict__ z_g, const float* __restrict__ T,
                                               f16* __restrict__ MthHi, f16* __restrict__ MthLo) {
    int h = blockIdx.x;
    __shared__ float zs[64][68], Ts[64][68];
    int t = threadIdx.x;
    for (int idx = t; idx < 4096; idx += 256) {
        int r = idx >> 6, c = idx & 63;
        zs[r][c] = z_g[h * 4096 + idx];
        Ts[r][c] = T[h * 4096 + idx];
    }
    __syncthreads();
    int i0 = (t >> 4) * 4, j0 = (t & 15) * 4;
    float o[4][4];
    mm_blk(zs, Ts, i0, j0, o);
    #pragma unroll
    for (int ii = 0; ii < 4; ++ii)
        #pragma unroll
        for (int jj = 0; jj < 4; ++jj) {
            float mv = o[ii][jj];
            f16 hiv = (f16)mv;
            f16 lov = (f16)(mv - (float)hiv);
            MthHi[h * 4096 + (j0 + jj) * 64 + (i0 + ii)] = hiv;
            MthLo[h * 4096 + (j0 + jj) * 64 + (i0 + ii)] = lov;
        }
}

// ---------------- depthwise conv over sorted v (streaming) -> resH (f16) ----------------
__global__ __launch_bounds__(256) void conv_k(const f16* __restrict__ qkvh,
                                              const float* __restrict__ resk, f16* __restrict__ resH) {
    int h = blockIdx.y;
    int p0 = blockIdx.x * 256;
    __shared__ f16 vt[288][72];
    int t = threadIdx.x;
    for (int id = t; id < 288 * 8; id += 256) {
        int rr = id >> 3, c = id & 7;
        int pg = p0 - 16 + rr;
        int4 v = {0, 0, 0, 0};
        if (pg >= 0 && pg < N_TOK)
            v = *(const int4*)&qkvh[(size_t)pg * QKVC + 1024 + h * 64 + c * 8];
        *(int4*)&vt[rr][c * 8] = v;
    }
    float wk[KSZ];
    #pragma unroll
    for (int k = 0; k < KSZ; ++k) wk[k] = resk[h * KSZ + k];
    __syncthreads();
    int d = t & 63, pg4 = t >> 6;
    float col[96];
    #pragma unroll
    for (int i2 = 0; i2 < 96; ++i2) col[i2] = (float)vt[pg4 * 64 + i2][d];
    #pragma unroll
    for (int pp = 0; pp < 64; ++pp) {
        float acc = 0.f;
        #pragma unroll
        for (int k = 0; k < KSZ; ++k) acc += wk[k] * col[pp + k];
        resH[(size_t)(p0 + pg4 * 64 + pp) * 512 + h * 64 + d] = (f16)acc;
    }
}

// ---------------- attn1 via MFMA: softmax(Q@kl^T) @ M + residual -> Yh ----------------
__global__ __launch_bounds__(256) void attn1_k(const f16* __restrict__ qkvh, const f16* __restrict__ klh,
                                               const f16* __restrict__ MthHi, const f16* __restrict__ MthLo,
                                               const f16* __restrict__ resH, f16* __restrict__ Yh) {
    const int h = blockIdx.y;
    const int p0 = blockIdx.x * 128;
    const int t = threadIdx.x;
    const int w = t >> 6, lane = t & 63;
    const int lr = lane & 15, hi = lane >> 4;
    __shared__ f16 Qs[128][72];
    __shared__ f16 Ks[64][72];
    __shared__ f16 Mhi[64][72];
    __shared__ f16 Mlo[64][72];
    __shared__ f16 Ps[128][72];

    #pragma unroll
    for (int i = 0; i < 4; ++i) {
        int id = i * 256 + t, row = id >> 3, c8 = id & 7;
        *(f16x8*)&Qs[row][c8 * 8] = *(const f16x8*)&qkvh[(size_t)(p0 + row) * QKVC + h * 64 + c8 * 8];
    }
    #pragma unroll
    for (int i = 0; i < 2; ++i) {
        int id = i * 256 + t, row = id >> 3, c8 = id & 7;
        *(f16x8*)&Ks[row][c8 * 8]  = *(const f16x8*)&klh[h * 4096 + id * 8];
        *(f16x8*)&Mhi[row][c8 * 8] = *(const f16x8*)&MthHi[h * 4096 + id * 8];
        *(f16x8*)&Mlo[row][c8 * 8] = *(const f16x8*)&MthLo[h * 4096 + id * 8];
    }
    __syncthreads();

    f32x4 c[4][2];
    #pragma unroll
    for (int lf = 0; lf < 4; ++lf)
        #pragma unroll
        for (int nf = 0; nf < 2; ++nf) c[lf][nf] = (f32x4){0.f, 0.f, 0.f, 0.f};
    #pragma unroll
    for (int ks = 0; ks < 2; ++ks) {
        f16x8 af[4], bf[2];
        #pragma unroll
        for (int lf = 0; lf < 4; ++lf) af[lf] = *(const f16x8*)&Ks[lf * 16 + lr][ks * 32 + hi * 8];
        #pragma unroll
        for (int nf = 0; nf < 2; ++nf) bf[nf] = *(const f16x8*)&Qs[w * 32 + nf * 16 + lr][ks * 32 + hi * 8];
        #pragma unroll
        for (int lf = 0; lf < 4; ++lf)
            #pragma unroll
            for (int nf = 0; nf < 2; ++nf)
                c[lf][nf] = __builtin_amdgcn_mfma_f32_16x16x32_f16(af[lf], bf[nf], c[lf][nf], 0, 0, 0);
    }

    #pragma unroll
    for (int nf = 0; nf < 2; ++nf) {
        float m = -1e30f;
        #pragma unroll
        for (int lf = 0; lf < 4; ++lf)
            #pragma unroll
            for (int j = 0; j < 4; ++j) m = fmaxf(m, c[lf][nf][j]);
        m = fmaxf(m, __shfl_xor(m, 16));
        m = fmaxf(m, __shfl_xor(m, 32));
        float s = 0.f;
        #pragma unroll
        for (int lf = 0; lf < 4; ++lf)
            #pragma unroll
            for (int j = 0; j < 4; ++j) { float e = __expf(c[lf][nf][j] - m); c[lf][nf][j] = e; s += e; }
        s += __shfl_xor(s, 16);
        s += __shfl_xor(s, 32);
        float inv = 1.0f / s;
        #pragma unroll
        for (int lf = 0; lf < 4; ++lf) {
            f16x4 pk;
            #pragma unroll
            for (int j = 0; j < 4; ++j) pk[j] = (f16)(c[lf][nf][j] * inv);
            *(f16x4*)&Ps[w * 32 + nf * 16 + lr][lf * 16 + hi * 4] = pk;
        }
    }

    f32x4 o[2][4];
    #pragma unroll
    for (int nf = 0; nf < 2; ++nf)
        #pragma unroll
        for (int df = 0; df < 4; ++df) o[nf][df] = (f32x4){0.f, 0.f, 0.f, 0.f};
    #pragma unroll
    for (int ks = 0; ks < 2; ++ks) {
        f16x8 pa[2], bh[4], bl[4];
        #pragma unroll
        for (int nf = 0; nf < 2; ++nf) pa[nf] = *(const f16x8*)&Ps[w * 32 + nf * 16 + lr][ks * 32 + hi * 8];
        #pragma unroll
        for (int df = 0; df < 4; ++df) {
            bh[df] = *(const f16x8*)&Mhi[df * 16 + lr][ks * 32 + hi * 8];
            bl[df] = *(const f16x8*)&Mlo[df * 16 + lr][ks * 32 + hi * 8];
        }
        #pragma unroll
        for (int nf = 0; nf < 2; ++nf)
            #pragma unroll
            for (int df = 0; df < 4; ++df) {
                o[nf][df] = __builtin_amdgcn_mfma_f32_16x16x32_f16(pa[nf], bh[df], o[nf][df], 0, 0, 0);
                o[nf][df] = __builtin_amdgcn_mfma_f32_16x16x32_f16(pa[nf], bl[df], o[nf][df], 0, 0, 0);
            }
    }

    #pragma unroll
    for (int nf = 0; nf < 2; ++nf)
        #pragma unroll
        for (int df = 0; df < 4; ++df)
            #pragma unroll
            for (int j = 0; j < 4; ++j)
                Ps[w * 32 + nf * 16 + hi * 4 + j][df * 16 + lr] = (f16)(o[nf][df][j]);
    __syncthreads();

    #pragma unroll
    for (int i = 0; i < 4; ++i) {
        int id = i * 256 + t, row = id >> 3, c8 = id & 7;
        size_t go = (size_t)(p0 + row) * 512 + h * 64 + c8 * 8;
        f16x8 yv = *(const f16x8*)&Ps[row][c8 * 8];
        f16x8 rv = *(const f16x8*)&resH[go];
        f16x8 sv;
        #pragma unroll
        for (int e = 0; e < 8; ++e) sv[e] = (f16)((float)yv[e] + (float)rv[e]);
        *(f16x8*)&Yh[go] = sv;
    }
}

// ---------------- host launch ----------------
extern "C" void kernel_launch(void* const* d_in, const int* in_sizes, int n_in,
                              void* d_out, int out_size, void* d_ws, size_t ws_size,
                              hipStream_t stream) {
    const float* x    = (const float*)d_in[0];
    const float* Wqkv = (const float*)d_in[1];
    const float* Wout = (const float*)d_in[2];
    const float* bout = (const float*)d_in[3];
    const float* resk = (const float*)d_in[4];
    const int*   labels = (const int*)d_in[5];
    float* out = (float*)d_out;

    char* w = (char*)d_ws;
    size_t off = 0;
    auto alloc = [&](size_t bytes) {
        void* p = w + off;
        off += (bytes + 255) & ~(size_t)255;
        return p;
    };
    f16* xh     = (f16*)alloc((size_t)N_TOK * DIMC * 2);       // sorted
    f16* qkvh   = (f16*)alloc((size_t)N_TOK * QKVC * 2);       // sorted
    f16* WqkvT  = (f16*)alloc((size_t)QKVC * DIMC * 2);
    f16* WoutT  = (f16*)alloc((size_t)DIMC * DIMC * 2);
    f16* Yh     = (f16*)alloc((size_t)N_TOK * DIMC * 2);       // sorted
    int* counts = (int*)alloc(NL * 4);
    int* baseA  = (int*)alloc(NL * 4);
    int* indexA = (int*)alloc((size_t)N_TOK * 4);
    float* ql   = (float*)alloc((size_t)NH * 64 * 64 * 4);
    float* kl   = (float*)alloc((size_t)NH * 64 * 64 * 4);
    f16* qlh    = (f16*)alloc((size_t)NH * 64 * 64 * 2);
    f16* klh    = (f16*)alloc((size_t)NH * 64 * 64 * 2);
    float* a2   = (float*)alloc((size_t)NH * 64 * 64 * 4);
    float* mrow = (float*)alloc(NH * 4);
    float* mcol = (float*)alloc(NH * 4);
    float* zb   = (float*)alloc((size_t)NH * 64 * 64 * 4);
    float* Tb   = (float*)alloc((size_t)NH * 64 * 64 * 4);
    f16* MthHi  = (f16*)alloc((size_t)NH * 64 * 64 * 2);
    f16* MthLo  = (f16*)alloc((size_t)NH * 64 * 64 * 2);
    float* pm   = (float*)alloc((size_t)NH * NCHUNK * 64 * 4);
    float* ps   = (float*)alloc((size_t)NH * NCHUNK * 64 * 4);
    float* pacc = (float*)alloc((size_t)NH * NCHUNK * 64 * 64 * 4);
    f16* resH = (f16*)d_out;  // reuse d_out (64MB) as f16 conv output (32MB); overwritten by final GEMM

    hipMemsetAsync(counts, 0, NL * 4, stream);

    // stable counting sort
    hist_k<<<N_TOK / 256, 256, 0, stream>>>(labels, counts);
    scan_k<<<1, 64, 0, stream>>>(counts, baseA);
    compact_k<<<NL, 256, 0, stream>>>(labels, baseA, indexA);
    // gather+convert x rows into sorted order
    gather_cvt_k<<<N_TOK / 2, 256, 0, stream>>>((const float4*)x, indexA, (f16x4*)xh);
    // weight transposes
    transpose_k<<<dim3(QKVC / 32, DIMC / 32), dim3(32, 8), 0, stream>>>(Wqkv, WqkvT, DIMC, QKVC);
    transpose_k<<<dim3(DIMC / 32, DIMC / 32), dim3(32, 8), 0, stream>>>(Wout, WoutT, DIMC, DIMC);
    // qkv = x_sorted @ Wqkv  (sorted domain)
    gemm_k512<QKVC, false, 6><<<dim3(N_TOK / 128, QKVC / 256), 512, 0, stream>>>(xh, WqkvT, qkvh, nullptr, nullptr);
    // segment pooling (vectorized)
    pool_k<<<NL, 1024, 0, stream>>>(qkvh, baseA, counts, ql, kl, qlh, klh);
    // attn2 + pinv chain (f32)
    attn2_k<<<NH, 256, 0, stream>>>(ql, kl, a2, mrow, mcol);
    pinv_k<<<NH, 256, 0, stream>>>(a2, mrow, mcol, zb);
    // T = softmax(ql@k^T) @ v  (MFMA flash-style)
    attn3_k<<<dim3(NCHUNK, NH), 256, 0, stream>>>(qkvh, qlh, pm, ps, pacc);
    attn3_merge_k<<<dim3(NL, NH), 64, 0, stream>>>(pm, ps, pacc, Tb);
    // M^T (hi+lo f16) = (z @ T)^T
    zmatT_k<<<NH, 256, 0, stream>>>(zb, Tb, MthHi, MthLo);
    // depthwise conv over sorted v (streaming)
    conv_k<<<dim3(N_TOK / 256, NH), 256, 0, stream>>>(qkvh, resk, resH);
    // attn1 (MFMA) + combine -> Yh (sorted)
    attn1_k<<<dim3(N_TOK / 128, NH), 256, 0, stream>>>(qkvh, klh, MthHi, MthLo, resH, Yh);
    // final projection + bias, scatter rows back to original order
    gemm_k512<DIMC, true, 2><<<dim3(N_TOK / 128, DIMC / 256), 512, 0, stream>>>(Yh, WoutT, out, bout, indexA);
}

// Round 10
// 375.386 us; speedup vs baseline: 3.0158x; 1.0121x over previous
//
#include <hip/hip_runtime.h>
#include <hip/hip_bf16.h>

// ---------------- problem constants ----------------
#define N_TOK 32768
#define DIMC  512
#define NH    8
#define DHD   64
#define NL    64
#define KSZ   33
#define QKVC  1536
#define NCHUNK 64   // attn3 chunks; 512 tokens per block

typedef _Float16 f16;
typedef _Float16 f16x8 __attribute__((ext_vector_type(8)));
typedef _Float16 f16x4 __attribute__((ext_vector_type(4)));
typedef float    f32x4 __attribute__((ext_vector_type(4)));

#define GLOAD_LDS16(gp, lp) \
    __builtin_amdgcn_global_load_lds((const __attribute__((address_space(1))) void*)(gp), \
                                     (__attribute__((address_space(3))) void*)(lp), 16, 0, 0)

// ---------------- transpose f32 (R x C) -> f16 (C x R) ----------------
__global__ void transpose_k(const float* __restrict__ W, f16* __restrict__ WT, int R, int C) {
    __shared__ float tile[32][33];
    int bx = blockIdx.x * 32, by = blockIdx.y * 32;
    int tx = threadIdx.x, ty = threadIdx.y;
    #pragma unroll
    for (int i = 0; i < 32; i += 8)
        tile[ty + i][tx] = W[(size_t)(by + ty + i) * C + bx + tx];
    __syncthreads();
    #pragma unroll
    for (int i = 0; i < 32; i += 8)
        WT[(size_t)(bx + ty + i) * R + by + tx] = (f16)tile[tx][ty + i];
}

// ---------------- label histogram ----------------
__global__ void hist_k(const int* __restrict__ labels, int* __restrict__ counts) {
    __shared__ int hloc[NL];
    int t = threadIdx.x;
    if (t < NL) hloc[t] = 0;
    __syncthreads();
    int i = blockIdx.x * 256 + t;
    atomicAdd(&hloc[labels[i]], 1);
    __syncthreads();
    if (t < NL) atomicAdd(&counts[t], hloc[t]);
}

// ---------------- exclusive prefix over 64 counts ----------------
__global__ void scan_k(const int* __restrict__ counts, int* __restrict__ base) {
    if (threadIdx.x == 0) {
        int s = 0;
        for (int l = 0; l < NL; ++l) { base[l] = s; s += counts[l]; }
    }
}

// ---------------- stable compaction: one block per label ----------------
__global__ __launch_bounds__(256) void compact_k(const int* __restrict__ labels,
                                                 const int* __restrict__ base,
                                                 int* __restrict__ indexArr) {
    const int l = blockIdx.x;
    __shared__ int wtot[4];
    __shared__ int s_run;
    int t = threadIdx.x, lane = t & 63, w = t >> 6;
    if (t == 0) s_run = base[l];
    __syncthreads();
    for (int c0 = 0; c0 < N_TOK; c0 += 256) {
        int ii = c0 + t;
        bool flag = (labels[ii] == l);
        unsigned long long mask = __ballot(flag);
        int before = __popcll(mask & ((1ull << lane) - 1ull));
        if (lane == 0) wtot[w] = __popcll(mask);
        __syncthreads();
        int off = 0;
        #pragma unroll
        for (int ww = 0; ww < 4; ++ww) off += (ww < w) ? wtot[ww] : 0;
        int tot = wtot[0] + wtot[1] + wtot[2] + wtot[3];
        int rb = s_run;
        if (flag) indexArr[rb + off + before] = ii;
        __syncthreads();
        if (t == 0) s_run = rb + tot;
    }
}

// ---------------- gather rows of x via index, convert to f16 (sorted domain) ----------------
__global__ __launch_bounds__(256) void gather_cvt_k(const float4* __restrict__ x4,
                                                    const int* __restrict__ indexArr,
                                                    f16x4* __restrict__ xh4) {
    int t = threadIdx.x;
    int row = blockIdx.x * 2 + (t >> 7);
    int c4 = t & 127;
    int j = indexArr[row];
    float4 v = x4[(size_t)j * 128 + c4];
    f16x4 o = { (f16)v.x, (f16)v.y, (f16)v.z, (f16)v.w };
    xh4[(size_t)row * 128 + c4] = o;
}

// ---------------- f16 MFMA GEMM: C[M x BNTOT] = A[M x 512] @ BT[BNTOT x 512]^T ----------------
// tile 128x256, BK=32, 8 waves (2M x 4N grid), each wave a square 64x64 sub-tile.
// 3-buffer rotation, one barrier per K-step, counted vmcnt(3) (T4), T2 source-side swizzle,
// T1 bijective XCD swizzle, swapped-operand vector epilogue. VGPR 64 -> 4 waves/SIMD.
template<int BNTOT, bool OUT_F32, int NY>
__global__ __launch_bounds__(512, 4) void gemm_k512(const f16* __restrict__ A, const f16* __restrict__ BT,
                                                    void* __restrict__ Cout, const float* __restrict__ bias,
                                                    const int* __restrict__ scatterIdx) {
    constexpr int K = 512;
    constexpr int NKT = K / 32;             // 16 K-tiles
    __shared__ f16 As[3][128 * 32];         // 3 x 8 KB
    __shared__ f16 Bs[3][256 * 32];         // 3 x 16 KB  (72 KB total -> 2 blocks/CU)
    const int t = threadIdx.x;
    const int orig = blockIdx.x + gridDim.x * blockIdx.y;
    constexpr int NWG = 256 * NY;           // gridDim.x == 256 (N_TOK/128)
    constexpr int CPX = NWG / 8;
    const int lin = (orig & 7) * CPX + (orig >> 3);
    const int mBase = (lin / NY) * 128;
    const int nBase = (lin % NY) * 256;
    const int w = t >> 6, lane = t & 63;
    const int wm = w >> 2, wn = w & 3;      // 2 x 4 wave grid
    const int lr = lane & 15, lk = lane >> 4;
    const int kc = (lk ^ ((lr >> 1) & 3)) * 8;   // swizzled chunk offset (halves)
    f32x4 acc[4][4];
    #pragma unroll
    for (int m = 0; m < 4; ++m)
        #pragma unroll
        for (int n = 0; n < 4; ++n) acc[m][n] = (f32x4){0.f, 0.f, 0.f, 0.f};

    auto stage = [&](int buf, int kt) {
        {
            int id = t;
            int row = id >> 2, c = id & 3;
            int cg = c ^ ((row >> 1) & 3);
            GLOAD_LDS16(&A[(size_t)(mBase + row) * K + kt * 32 + cg * 8],
                        &As[buf][(size_t)(w * 64) * 8]);
        }
        #pragma unroll
        for (int r = 0; r < 2; ++r) {
            int id = r * 512 + t;
            int row = id >> 2, c = id & 3;
            int cg = c ^ ((row >> 1) & 3);
            GLOAD_LDS16(&BT[(size_t)(nBase + row) * K + kt * 32 + cg * 8],
                        &Bs[buf][(size_t)(r * 512 + w * 64) * 8]);
        }
    };
    auto compute = [&](int buf) {
        f16x8 af[4], bf[4];
        #pragma unroll
        for (int m = 0; m < 4; ++m)
            af[m] = *(const f16x8*)&As[buf][(wm * 64 + m * 16 + lr) * 32 + kc];
        #pragma unroll
        for (int n = 0; n < 4; ++n)
            bf[n] = *(const f16x8*)&Bs[buf][(wn * 64 + n * 16 + lr) * 32 + kc];
        #pragma unroll
        for (int m = 0; m < 4; ++m)
            #pragma unroll
            for (int n = 0; n < 4; ++n)
                acc[m][n] = __builtin_amdgcn_mfma_f32_16x16x32_f16(bf[n], af[m], acc[m][n], 0, 0, 0);
    };

    stage(0, 0);
    stage(1, 1);
    for (int kt = 0; kt < NKT; ++kt) {
        if (kt < NKT - 1) {
            asm volatile("s_waitcnt vmcnt(3)" ::: "memory");
        } else {
            asm volatile("s_waitcnt vmcnt(0)" ::: "memory");
        }
        __builtin_amdgcn_s_barrier();
        if (kt + 2 < NKT) stage((kt + 2) % 3, kt + 2);
        compute(kt % 3);
    }

    #pragma unroll
    for (int m = 0; m < 4; ++m) {
        int row = mBase + wm * 64 + m * 16 + lr;
        int srow = OUT_F32 ? scatterIdx[row] : row;
        #pragma unroll
        for (int n = 0; n < 4; ++n) {
            int col = nBase + wn * 64 + n * 16 + lk * 4;
            if constexpr (OUT_F32) {
                float4 bv = *(const float4*)&bias[col];
                float4 sv = make_float4(acc[m][n][0] + bv.x, acc[m][n][1] + bv.y,
                                        acc[m][n][2] + bv.z, acc[m][n][3] + bv.w);
                *(float4*)&((float*)Cout)[(size_t)srow * BNTOT + col] = sv;
            } else {
                f16x4 hv = { (f16)acc[m][n][0], (f16)acc[m][n][1],
                             (f16)acc[m][n][2], (f16)acc[m][n][3] };
                *(f16x4*)&((f16*)Cout)[(size_t)srow * BNTOT + col] = hv;
            }
        }
    }
}

// ---------------- segment-mean pooling (vectorized): sorted q,k -> ql,kl (f32) + qlh,klh (f16) ----------------
__global__ __launch_bounds__(1024) void pool_k(const f16* __restrict__ qkvh,
                                               const int* __restrict__ base, const int* __restrict__ counts,
                                               float* __restrict__ ql, float* __restrict__ kl,
                                               f16* __restrict__ qlh, f16* __restrict__ klh) {
    int l = blockIdx.x;
    int t = threadIdx.x;
    int c = t & 127, rg = t >> 7;
    int b0 = base[l], cnt = counts[l];
    f32x4 a0 = {0.f,0.f,0.f,0.f}, a1 = {0.f,0.f,0.f,0.f};
    for (int p = rg; p < cnt; p += 8) {
        f16x8 v = *(const f16x8*)&qkvh[(size_t)(b0 + p) * QKVC + c * 8];
        a0[0] += (float)v[0]; a0[1] += (float)v[1]; a0[2] += (float)v[2]; a0[3] += (float)v[3];
        a1[0] += (float)v[4]; a1[1] += (float)v[5]; a1[2] += (float)v[6]; a1[3] += (float)v[7];
    }
    __shared__ f32x4 red[8][128][2];
    red[rg][c][0] = a0; red[rg][c][1] = a1;
    __syncthreads();
    if (t < 128) {
        float inv = 1.0f / (float)(cnt > 0 ? cnt : 1);
        f32x4 s0 = {0.f,0.f,0.f,0.f}, s1 = {0.f,0.f,0.f,0.f};
        #pragma unroll
        for (int g = 0; g < 8; ++g) { s0 += red[g][t][0]; s1 += red[g][t][1]; }
        s0 *= inv; s1 *= inv;
        int h = (t & 63) >> 3, d0 = (t & 7) * 8;
        size_t o = ((size_t)(h * 64 + l)) * 64 + d0;
        f16x8 hv;
        #pragma unroll
        for (int e = 0; e < 4; ++e) { hv[e] = (f16)s0[e]; hv[4 + e] = (f16)s1[e]; }
        if (t < 64) {
            *(f32x4*)&ql[o] = s0; *(f32x4*)&ql[o + 4] = s1;
            *(f16x8*)&qlh[o] = hv;
        } else {
            *(f32x4*)&kl[o] = s0; *(f32x4*)&kl[o + 4] = s1;
            *(f16x8*)&klh[o] = hv;
        }
    }
}

// ---------------- attn2 = softmax(ql@kl^T) rows; per-head row/col abs-sum maxes ----------------
__global__ __launch_bounds__(256) void attn2_k(const float* __restrict__ ql, const float* __restrict__ kl,
                                               float* __restrict__ a_out, float* __restrict__ mrow,
                                               float* __restrict__ mcol) {
    int h = blockIdx.x;
    __shared__ float qs[64][65], ks[64][65], a[64][65];
    __shared__ float red[64][4];
    __shared__ float rowv[64], colv[64];
    int t = threadIdx.x;
    for (int idx = t; idx < 4096; idx += 256) {
        int r = idx >> 6, c = idx & 63;
        qs[r][c] = ql[h * 4096 + idx];
        ks[r][c] = kl[h * 4096 + idx];
    }
    __syncthreads();
    int i = t >> 2, q4 = t & 3, j0 = q4 * 16;
    float o[16];
    #pragma unroll
    for (int jj = 0; jj < 16; ++jj) o[jj] = 0.f;
    for (int d = 0; d < 64; ++d) {
        float qv = qs[i][d];
        #pragma unroll
        for (int jj = 0; jj < 16; ++jj) o[jj] += qv * ks[j0 + jj][d];
    }
    float pmx = o[0];
    #pragma unroll
    for (int jj = 1; jj < 16; ++jj) pmx = fmaxf(pmx, o[jj]);
    red[i][q4] = pmx;
    __syncthreads();
    float rm = fmaxf(fmaxf(red[i][0], red[i][1]), fmaxf(red[i][2], red[i][3]));
    float psum = 0.f;
    #pragma unroll
    for (int jj = 0; jj < 16; ++jj) { o[jj] = expf(o[jj] - rm); psum += o[jj]; }
    __syncthreads();
    red[i][q4] = psum;
    __syncthreads();
    float rs = red[i][0] + red[i][1] + red[i][2] + red[i][3];
    float inv = 1.0f / rs;
    #pragma unroll
    for (int jj = 0; jj < 16; ++jj) { o[jj] *= inv; a[i][j0 + jj] = o[jj]; }
    __syncthreads();
    for (int idx = t; idx < 4096; idx += 256) a_out[h * 4096 + idx] = a[idx >> 6][idx & 63];
    float rsum = 0.f;
    #pragma unroll
    for (int jj = 0; jj < 16; ++jj) rsum += o[jj];
    __syncthreads();
    red[i][q4] = rsum;
    __syncthreads();
    if (q4 == 0) rowv[i] = red[i][0] + red[i][1] + red[i][2] + red[i][3];
    float csum = 0.f;
    #pragma unroll
    for (int jj = 0; jj < 16; ++jj) csum += a[j0 + jj][i];
    __syncthreads();
    red[i][q4] = csum;
    __syncthreads();
    if (q4 == 0) colv[i] = red[i][0] + red[i][1] + red[i][2] + red[i][3];
    __syncthreads();
    if (t == 0) {
        float mr = rowv[0], mc = colv[0];
        for (int j = 1; j < 64; ++j) { mr = fmaxf(mr, rowv[j]); mc = fmaxf(mc, colv[j]); }
        mrow[h] = mr; mcol[h] = mc;
    }
}

// 4x4-blocked 64x64 matmul helper (operands in LDS, stride 68)
__device__ __forceinline__ void mm_blk(const float (*X)[68], const float (*Y)[68],
                                       int i0, int j0, float o[4][4]) {
    #pragma unroll
    for (int ii = 0; ii < 4; ++ii)
        #pragma unroll
        for (int jj = 0; jj < 4; ++jj) o[ii][jj] = 0.f;
    for (int k = 0; k < 64; ++k) {
        float4 yv = *(const float4*)&Y[k][j0];
        float x0 = X[i0][k], x1 = X[i0 + 1][k], x2 = X[i0 + 2][k], x3 = X[i0 + 3][k];
        o[0][0] += x0 * yv.x; o[0][1] += x0 * yv.y; o[0][2] += x0 * yv.z; o[0][3] += x0 * yv.w;
        o[1][0] += x1 * yv.x; o[1][1] += x1 * yv.y; o[1][2] += x1 * yv.z; o[1][3] += x1 * yv.w;
        o[2][0] += x2 * yv.x; o[2][1] += x2 * yv.y; o[2][2] += x2 * yv.z; o[2][3] += x2 * yv.w;
        o[3][0] += x3 * yv.x; o[3][1] += x3 * yv.y; o[3][2] += x3 * yv.z; o[3][3] += x3 * yv.w;
    }
}

// ---------------- Newton-Schulz pinv (6 iters, f32, per head) ----------------
__global__ __launch_bounds__(256) void pinv_k(const float* __restrict__ a_g, const float* __restrict__ mrow,
                                              const float* __restrict__ mcol, float* __restrict__ z_g) {
    int h = blockIdx.x;
    __shared__ float a[64][68], z[64][68], C[64][68], D[64][68], E[64][68];
    int t = threadIdx.x;
    float mr = mrow[0], mc = mcol[0];
    #pragma unroll
    for (int k = 1; k < 8; ++k) { mr = fmaxf(mr, mrow[k]); mc = fmaxf(mc, mcol[k]); }
    float inv0 = 1.0f / (mr * mc);
    for (int idx = t; idx < 4096; idx += 256) {
        int r = idx >> 6, c = idx & 63;
        float av = a_g[h * 4096 + idx];
        a[r][c] = av;
        z[c][r] = av * inv0;
    }
    __syncthreads();
    int i0 = (t >> 4) * 4, j0 = (t & 15) * 4;
    float o[4][4];
    for (int it = 0; it < 6; ++it) {
        mm_blk(a, z, i0, j0, o);
        #pragma unroll
        for (int ii = 0; ii < 4; ++ii)
            #pragma unroll
            for (int jj = 0; jj < 4; ++jj) C[i0 + ii][j0 + jj] = o[ii][jj];
        __syncthreads();
        mm_blk(C, C, i0, j0, o);
        #pragma unroll
        for (int ii = 0; ii < 4; ++ii)
            #pragma unroll
            for (int jj = 0; jj < 4; ++jj) D[i0 + ii][j0 + jj] = 7.f * C[i0 + ii][j0 + jj] - o[ii][jj];
        __syncthreads();
        mm_blk(C, D, i0, j0, o);
        #pragma unroll
        for (int ii = 0; ii < 4; ++ii)
            #pragma unroll
            for (int jj = 0; jj < 4; ++jj) E[i0 + ii][j0 + jj] = 15.f * C[i0 + ii][j0 + jj] - o[ii][jj];
        __syncthreads();
        mm_blk(z, E, i0, j0, o);
        #pragma unroll
        for (int ii = 0; ii < 4; ++ii)
            #pragma unroll
            for (int jj = 0; jj < 4; ++jj) D[i0 + ii][j0 + jj] = 0.25f * (13.f * z[i0 + ii][j0 + jj] - o[ii][jj]);
        __syncthreads();
        #pragma unroll
        for (int ii = 0; ii < 4; ++ii)
            #pragma unroll
            for (int jj = 0; jj < 4; ++jj) z[i0 + ii][j0 + jj] = D[i0 + ii][j0 + jj];
        __syncthreads();
    }
    for (int idx = t; idx < 4096; idx += 256) z_g[h * 4096 + idx] = z[idx >> 6][idx & 63];
}

// ---------------- attn3 @ v via MFMA: flash-style online softmax, per-block partials ----------------
__global__ __launch_bounds__(256) void attn3_k(const f16* __restrict__ qkvh, const f16* __restrict__ qlh,
                                               float* __restrict__ pm, float* __restrict__ ps,
                                               float* __restrict__ pacc) {
    const int cx = blockIdx.x, h = blockIdx.y;
    const int t = threadIdx.x;
    const int w = t >> 6, lane = t & 63;
    const int lr = lane & 15, hi = lane >> 4;
    __shared__ f16 Qls[64 * 64];
    __shared__ f16 Ks[64 * 64];
    __shared__ f16 vT[64 * 72];
    __shared__ f16 Ps[64 * 72];
    __shared__ float fsh[64];

    #pragma unroll
    for (int pss = 0; pss < 2; ++pss) {
        int q = pss * 256 + t;
        int r = q >> 3, cs = (q & 7) ^ (r & 7);
        GLOAD_LDS16(&qlh[(size_t)h * 4096 + r * 64 + cs * 8], &Qls[(size_t)(pss * 256 + w * 64) * 8]);
    }
    float m_reg = -1e30f, s_reg = 0.f;
    f32x4 accT[4];
    #pragma unroll
    for (int lf = 0; lf < 4; ++lf) accT[lf] = (f32x4){0.f, 0.f, 0.f, 0.f};

    const int vk8 = t & 7, vnn = t >> 3;

    for (int sub = 0; sub < 8; ++sub) {
        const int n0 = cx * 512 + sub * 64;
        __syncthreads();
        #pragma unroll
        for (int pss = 0; pss < 2; ++pss) {
            int q = pss * 256 + t;
            int r = q >> 3, cs = (q & 7) ^ (r & 7);
            GLOAD_LDS16(&qkvh[(size_t)(n0 + r) * QKVC + 512 + h * 64 + cs * 8],
                        &Ks[(size_t)(pss * 256 + w * 64) * 8]);
        }
        #pragma unroll
        for (int p2 = 0; p2 < 2; ++p2) {
            int n = vnn + 32 * p2;
            f16x8 rv = *(const f16x8*)&qkvh[(size_t)(n0 + n) * QKVC + 1024 + h * 64 + vk8 * 8];
            #pragma unroll
            for (int i = 0; i < 8; ++i) {
                int e = i ^ vk8;
                vT[(vk8 * 8 + e) * 72 + n] = rv[e];
            }
        }
        __syncthreads();
        f32x4 c[4];
        #pragma unroll
        for (int kf = 0; kf < 4; ++kf) c[kf] = (f32x4){0.f, 0.f, 0.f, 0.f};
        const int lq = w * 16 + lr;
        #pragma unroll
        for (int ks = 0; ks < 2; ++ks) {
            f16x8 bf = *(const f16x8*)&Qls[lq * 64 + (((ks * 4 + hi) ^ (lq & 7)) * 8)];
            #pragma unroll
            for (int kf = 0; kf < 4; ++kf) {
                int rn = kf * 16 + lr;
                f16x8 af = *(const f16x8*)&Ks[rn * 64 + (((ks * 4 + hi) ^ (rn & 7)) * 8)];
                c[kf] = __builtin_amdgcn_mfma_f32_16x16x32_f16(af, bf, c[kf], 0, 0, 0);
            }
        }
        float tmax = -1e30f;
        #pragma unroll
        for (int kf = 0; kf < 4; ++kf)
            #pragma unroll
            for (int j = 0; j < 4; ++j) tmax = fmaxf(tmax, c[kf][j]);
        tmax = fmaxf(tmax, __shfl_xor(tmax, 16));
        tmax = fmaxf(tmax, __shfl_xor(tmax, 32));
        float newm = fmaxf(m_reg, tmax);
        float fct = __expf(m_reg - newm);
        float psum = 0.f;
        #pragma unroll
        for (int kf = 0; kf < 4; ++kf) {
            f16x4 pk;
            #pragma unroll
            for (int j = 0; j < 4; ++j) {
                float e = __expf(c[kf][j] - newm);
                psum += e;
                pk[j] = (f16)e;
            }
            *(f16x4*)&Ps[lq * 72 + kf * 16 + hi * 4] = pk;
        }
        psum += __shfl_xor(psum, 16);
        psum += __shfl_xor(psum, 32);
        s_reg = s_reg * fct + psum;
        m_reg = newm;
        if (hi == 0) fsh[lq] = fct;
        __syncthreads();
        #pragma unroll
        for (int lf = 0; lf < 4; ++lf) {
            f32x4 fr = *(const f32x4*)&fsh[lf * 16 + hi * 4];
            accT[lf] *= fr;
        }
        #pragma unroll
        for (int ks = 0; ks < 2; ++ks) {
            f16x8 bf = *(const f16x8*)&vT[(w * 16 + lr) * 72 + ks * 32 + hi * 8];
            #pragma unroll
            for (int lf = 0; lf < 4; ++lf) {
                f16x8 af = *(const f16x8*)&Ps[(lf * 16 + lr) * 72 + ks * 32 + hi * 8];
                accT[lf] = __builtin_amdgcn_mfma_f32_16x16x32_f16(af, bf, accT[lf], 0, 0, 0);
            }
        }
    }
    int part = h * NCHUNK + cx;
    if (hi == 0) {
        pm[part * 64 + w * 16 + lr] = m_reg;
        ps[part * 64 + w * 16 + lr] = s_reg;
    }
    #pragma unroll
    for (int lf = 0; lf < 4; ++lf)
        #pragma unroll
        for (int j = 0; j < 4; ++j)
            pacc[((size_t)part * 64 + (lf * 16 + hi * 4 + j)) * 64 + (w * 16 + lr)] = accT[lf][j];
}

// ---------------- merge attn3 partials -> T[h][l][d] ----------------
__global__ void attn3_merge_k(const float* __restrict__ pm, const float* __restrict__ ps,
                              const float* __restrict__ pacc, float* __restrict__ T) {
    int l = blockIdx.x, h = blockIdx.y, d = threadIdx.x;
    float m = -1e30f;
    for (int c = 0; c < NCHUNK; ++c) m = fmaxf(m, pm[(h * NCHUNK + c) * 64 + l]);
    float s = 0.f, a = 0.f;
    for (int c = 0; c < NCHUNK; ++c) {
        float wgt = __expf(pm[(h * NCHUNK + c) * 64 + l] - m);
        s += ps[(h * NCHUNK + c) * 64 + l] * wgt;
        a += pacc[((size_t)(h * NCHUNK + c) * 64 + l) * 64 + d] * wgt;
    }
    T[(h * 64 + l) * 64 + d] = a / s;
}

// ---------------- M = z @ T per head; emit M^T split into f16 hi+lo ----------------
__global__ __launch_bounds__(256) void zmatT_k(const float* __restrict__ z_g, const float* __restrict__ T,
                                               f16* __restrict__ MthHi, f16* __restrict__ MthLo) {
    int h = blockIdx.x;
    __shared__ float zs[64][68], Ts[64][68];
    int t = threadIdx.x;
    for (int idx = t; idx < 4096; idx += 256) {
        int r = idx >> 6, c = idx & 63;
        zs[r][c] = z_g[h * 4096 + idx];
        Ts[r][c] = T[h * 4096 + idx];
    }
    __syncthreads();
    int i0 = (t >> 4) * 4, j0 = (t & 15) * 4;
    float o[4][4];
    mm_blk(zs, Ts, i0, j0, o);
    #pragma unroll
    for (int ii = 0; ii < 4; ++ii)
        #pragma unroll
        for (int jj = 0; jj < 4; ++jj) {
            float mv = o[ii][jj];
            f16 hiv = (f16)mv;
            f16 lov = (f16)(mv - (float)hiv);
            MthHi[h * 4096 + (j0 + jj) * 64 + (i0 + ii)] = hiv;
            MthLo[h * 4096 + (j0 + jj) * 64 + (i0 + ii)] = lov;
        }
}

// ---------------- fused attn1 + depthwise conv: softmax(Q@kl^T)@M + conv(v) -> Yh ----------------
// P/O tile aliases the Q tile (wave-private rows: each wave reads only its own 32 Q rows
// before overwriting them with P, then O). v staged with +-16 halo for the 33-tap conv.
__global__ __launch_bounds__(256) void attn1_k(const f16* __restrict__ qkvh, const f16* __restrict__ klh,
                                               const f16* __restrict__ MthHi, const f16* __restrict__ MthLo,
                                               const float* __restrict__ resk, f16* __restrict__ Yh) {
    const int h = blockIdx.y;
    const int p0 = blockIdx.x * 128;
    const int t = threadIdx.x;
    const int w = t >> 6, lane = t & 63;
    const int lr = lane & 15, hi = lane >> 4;
    __shared__ f16 QPs[128][72];     // Q tile -> P tile -> O tile (wave-private rows)
    __shared__ f16 Ks[64][72];
    __shared__ f16 Mhi[64][72];
    __shared__ f16 Mlo[64][72];
    __shared__ f16 vt[160][72];      // v rows [p0-16, p0+144)

    // stage Q (128x64)
    #pragma unroll
    for (int i = 0; i < 4; ++i) {
        int id = i * 256 + t, row = id >> 3, c8 = id & 7;
        *(f16x8*)&QPs[row][c8 * 8] = *(const f16x8*)&qkvh[(size_t)(p0 + row) * QKVC + h * 64 + c8 * 8];
    }
    // stage kl / Mhi / Mlo (64x64 each)
    #pragma unroll
    for (int i = 0; i < 2; ++i) {
        int id = i * 256 + t, row = id >> 3, c8 = id & 7;
        *(f16x8*)&Ks[row][c8 * 8]  = *(const f16x8*)&klh[h * 4096 + id * 8];
        *(f16x8*)&Mhi[row][c8 * 8] = *(const f16x8*)&MthHi[h * 4096 + id * 8];
        *(f16x8*)&Mlo[row][c8 * 8] = *(const f16x8*)&MthLo[h * 4096 + id * 8];
    }
    // stage v with halo (160 rows x 64)
    for (int id = t; id < 160 * 8; id += 256) {
        int rr = id >> 3, c8 = id & 7;
        int pg = p0 - 16 + rr;
        int4 v = {0, 0, 0, 0};
        if (pg >= 0 && pg < N_TOK)
            v = *(const int4*)&qkvh[(size_t)pg * QKVC + 1024 + h * 64 + c8 * 8];
        *(int4*)&vt[rr][c8 * 8] = v;
    }
    float wk[KSZ];
    #pragma unroll
    for (int k = 0; k < KSZ; ++k) wk[k] = resk[h * KSZ + k];
    __syncthreads();

    // S^T = kl @ Q^T : wave w covers n in [w*32, w*32+32)
    f32x4 c[4][2];
    #pragma unroll
    for (int lf = 0; lf < 4; ++lf)
        #pragma unroll
        for (int nf = 0; nf < 2; ++nf) c[lf][nf] = (f32x4){0.f, 0.f, 0.f, 0.f};
    #pragma unroll
    for (int ks = 0; ks < 2; ++ks) {
        f16x8 af[4], bf[2];
        #pragma unroll
        for (int lf = 0; lf < 4; ++lf) af[lf] = *(const f16x8*)&Ks[lf * 16 + lr][ks * 32 + hi * 8];
        #pragma unroll
        for (int nf = 0; nf < 2; ++nf) bf[nf] = *(const f16x8*)&QPs[w * 32 + nf * 16 + lr][ks * 32 + hi * 8];
        #pragma unroll
        for (int lf = 0; lf < 4; ++lf)
            #pragma unroll
            for (int nf = 0; nf < 2; ++nf)
                c[lf][nf] = __builtin_amdgcn_mfma_f32_16x16x32_f16(af[lf], bf[nf], c[lf][nf], 0, 0, 0);
    }

    // softmax over l (per n column), P overwrites own-wave Q rows
    #pragma unroll
    for (int nf = 0; nf < 2; ++nf) {
        float m = -1e30f;
        #pragma unroll
        for (int lf = 0; lf < 4; ++lf)
            #pragma unroll
            for (int j = 0; j < 4; ++j) m = fmaxf(m, c[lf][nf][j]);
        m = fmaxf(m, __shfl_xor(m, 16));
        m = fmaxf(m, __shfl_xor(m, 32));
        float s = 0.f;
        #pragma unroll
        for (int lf = 0; lf < 4; ++lf)
            #pragma unroll
            for (int j = 0; j < 4; ++j) { float e = __expf(c[lf][nf][j] - m); c[lf][nf][j] = e; s += e; }
        s += __shfl_xor(s, 16);
        s += __shfl_xor(s, 32);
        float inv = 1.0f / s;
        #pragma unroll
        for (int lf = 0; lf < 4; ++lf) {
            f16x4 pk;
            #pragma unroll
            for (int j = 0; j < 4; ++j) pk[j] = (f16)(c[lf][nf][j] * inv);
            *(f16x4*)&QPs[w * 32 + nf * 16 + lr][lf * 16 + hi * 4] = pk;
        }
    }

    // O = P @ (Mhi + Mlo)
    f32x4 o[2][4];
    #pragma unroll
    for (int nf = 0; nf < 2; ++nf)
        #pragma unroll
        for (int df = 0; df < 4; ++df) o[nf][df] = (f32x4){0.f, 0.f, 0.f, 0.f};
    #pragma unroll
    for (int ks = 0; ks < 2; ++ks) {
        f16x8 pa[2], bh[4], bl[4];
        #pragma unroll
        for (int nf = 0; nf < 2; ++nf) pa[nf] = *(const f16x8*)&QPs[w * 32 + nf * 16 + lr][ks * 32 + hi * 8];
        #pragma unroll
        for (int df = 0; df < 4; ++df) {
            bh[df] = *(const f16x8*)&Mhi[df * 16 + lr][ks * 32 + hi * 8];
            bl[df] = *(const f16x8*)&Mlo[df * 16 + lr][ks * 32 + hi * 8];
        }
        #pragma unroll
        for (int nf = 0; nf < 2; ++nf)
            #pragma unroll
            for (int df = 0; df < 4; ++df) {
                o[nf][df] = __builtin_amdgcn_mfma_f32_16x16x32_f16(pa[nf], bh[df], o[nf][df], 0, 0, 0);
                o[nf][df] = __builtin_amdgcn_mfma_f32_16x16x32_f16(pa[nf], bl[df], o[nf][df], 0, 0, 0);
            }
    }

    // write O into own-wave QPs rows
    #pragma unroll
    for (int nf = 0; nf < 2; ++nf)
        #pragma unroll
        for (int df = 0; df < 4; ++df)
            #pragma unroll
            for (int j = 0; j < 4; ++j)
                QPs[w * 32 + nf * 16 + hi * 4 + j][df * 16 + lr] = (f16)(o[nf][df][j]);
    __syncthreads();

    // fused conv + combine: thread (rg = t>>6, d = t&63) handles 32 output rows
    const int d = t & 63, rg = t >> 6;
    #pragma unroll
    for (int hh = 0; hh < 2; ++hh) {
        const int r0 = rg * 32 + hh * 16;
        float col[48];
        #pragma unroll
        for (int j = 0; j < 48; ++j) col[j] = (float)vt[r0 + j][d];
        #pragma unroll
        for (int pp = 0; pp < 16; ++pp) {
            float acc = 0.f;
            #pragma unroll
            for (int k = 0; k < KSZ; ++k) acc += wk[k] * col[pp + k];
            int row = r0 + pp;
            Yh[(size_t)(p0 + row) * 512 + h * 64 + d] = (f16)(acc + (float)QPs[row][d]);
        }
    }
}

// ---------------- host launch ----------------
extern "C" void kernel_launch(void* const* d_in, const int* in_sizes, int n_in,
                              void* d_out, int out_size, void* d_ws, size_t ws_size,
                              hipStream_t stream) {
    const float* x    = (const float*)d_in[0];
    const float* Wqkv = (const float*)d_in[1];
    const float* Wout = (const float*)d_in[2];
    const float* bout = (const float*)d_in[3];
    const float* resk = (const float*)d_in[4];
    const int*   labels = (const int*)d_in[5];
    float* out = (float*)d_out;

    char* w = (char*)d_ws;
    size_t off = 0;
    auto alloc = [&](size_t bytes) {
        void* p = w + off;
        off += (bytes + 255) & ~(size_t)255;
        return p;
    };
    f16* xh     = (f16*)alloc((size_t)N_TOK * DIMC * 2);       // sorted
    f16* qkvh   = (f16*)alloc((size_t)N_TOK * QKVC * 2);       // sorted
    f16* WqkvT  = (f16*)alloc((size_t)QKVC * DIMC * 2);
    f16* WoutT  = (f16*)alloc((size_t)DIMC * DIMC * 2);
    f16* Yh     = (f16*)alloc((size_t)N_TOK * DIMC * 2);       // sorted
    int* counts = (int*)alloc(NL * 4);
    int* baseA  = (int*)alloc(NL * 4);
    int* indexA = (int*)alloc((size_t)N_TOK * 4);
    float* ql   = (float*)alloc((size_t)NH * 64 * 64 * 4);
    float* kl   = (float*)alloc((size_t)NH * 64 * 64 * 4);
    f16* qlh    = (f16*)alloc((size_t)NH * 64 * 64 * 2);
    f16* klh    = (f16*)alloc((size_t)NH * 64 * 64 * 2);
    float* a2   = (float*)alloc((size_t)NH * 64 * 64 * 4);
    float* mrow = (float*)alloc(NH * 4);
    float* mcol = (float*)alloc(NH * 4);
    float* zb   = (float*)alloc((size_t)NH * 64 * 64 * 4);
    float* Tb   = (float*)alloc((size_t)NH * 64 * 64 * 4);
    f16* MthHi  = (f16*)alloc((size_t)NH * 64 * 64 * 2);
    f16* MthLo  = (f16*)alloc((size_t)NH * 64 * 64 * 2);
    float* pm   = (float*)alloc((size_t)NH * NCHUNK * 64 * 4);
    float* ps   = (float*)alloc((size_t)NH * NCHUNK * 64 * 4);
    float* pacc = (float*)alloc((size_t)NH * NCHUNK * 64 * 64 * 4);

    hipMemsetAsync(counts, 0, NL * 4, stream);

    // stable counting sort
    hist_k<<<N_TOK / 256, 256, 0, stream>>>(labels, counts);
    scan_k<<<1, 64, 0, stream>>>(counts, baseA);
    compact_k<<<NL, 256, 0, stream>>>(labels, baseA, indexA);
    // gather+convert x rows into sorted order
    gather_cvt_k<<<N_TOK / 2, 256, 0, stream>>>((const float4*)x, indexA, (f16x4*)xh);
    // weight transposes
    transpose_k<<<dim3(QKVC / 32, DIMC / 32), dim3(32, 8), 0, stream>>>(Wqkv, WqkvT, DIMC, QKVC);
    transpose_k<<<dim3(DIMC / 32, DIMC / 32), dim3(32, 8), 0, stream>>>(Wout, WoutT, DIMC, DIMC);
    // qkv = x_sorted @ Wqkv  (sorted domain)
    gemm_k512<QKVC, false, 6><<<dim3(N_TOK / 128, QKVC / 256), 512, 0, stream>>>(xh, WqkvT, qkvh, nullptr, nullptr);
    // segment pooling (vectorized)
    pool_k<<<NL, 1024, 0, stream>>>(qkvh, baseA, counts, ql, kl, qlh, klh);
    // attn2 + pinv chain (f32)
    attn2_k<<<NH, 256, 0, stream>>>(ql, kl, a2, mrow, mcol);
    pinv_k<<<NH, 256, 0, stream>>>(a2, mrow, mcol, zb);
    // T = softmax(ql@k^T) @ v  (MFMA flash-style)
    attn3_k<<<dim3(NCHUNK, NH), 256, 0, stream>>>(qkvh, qlh, pm, ps, pacc);
    attn3_merge_k<<<dim3(NL, NH), 64, 0, stream>>>(pm, ps, pacc, Tb);
    // M^T (hi+lo f16) = (z @ T)^T
    zmatT_k<<<NH, 256, 0, stream>>>(zb, Tb, MthHi, MthLo);
    // fused attn1 + depthwise conv -> Yh (sorted)
    attn1_k<<<dim3(N_TOK / 128, NH), 256, 0, stream>>>(qkvh, klh, MthHi, MthLo, resk, Yh);
    // final projection + bias, scatter rows back to original order
    gemm_k512<DIMC, true, 2><<<dim3(N_TOK / 128, DIMC / 256), 512, 0, stream>>>(Yh, WoutT, out, bout, indexA);
}